// Round 1
// baseline (10034.397 us; speedup 1.0000x reference)
//
#include <hip/hip_runtime.h>
#include <math.h>

#define NN 50000     // nodes
#define NE 800000    // edges
#define DIN 128      // input feat
#define DH 256       // hidden
#define DED 32       // edge dim
#define NG 500       // graphs
#define DOUT 16      // classes
#define EPW 16       // edges per wave in edge kernels

// ---------------- utility kernels ----------------

__global__ void fill_f32(float* __restrict__ p, float v, int n) {
  int i = blockIdx.x * 256 + threadIdx.x;
  if (i < n) p[i] = v;
}

__global__ void ew_add(const float* __restrict__ a, const float* __restrict__ b,
                       float* __restrict__ o, int n) {
  int i = blockIdx.x * 256 + threadIdx.x;
  if (i < n) o[i] = a[i] + b[i];
}

// monotonic float atomic max (init must be -inf)
__device__ inline void atomicMaxFloat(float* addr, float val) {
  if (val >= 0.f) atomicMax((int*)addr, __float_as_int(val));
  else            atomicMin((unsigned int*)addr, __float_as_uint(val));
}

// ---------------- generic tiled GEMM: C = A[MxK] @ W[KxN] (+bias, act) ----------------
// wtrans: W is stored [N x K] and used transposed (for QE = q @ We^T)
__global__ __launch_bounds__(256) void gemm_bias_act(
    const float* __restrict__ A, const float* __restrict__ Wm,
    const float* __restrict__ bias, float* __restrict__ C,
    int M, int K, int Ncol, int act, int wtrans)
{
  __shared__ __align__(16) float As[16][68];
  __shared__ __align__(16) float Bs[16][68];
  int tid = threadIdx.x;
  int tx = tid & 15, ty = tid >> 4;
  int row0 = blockIdx.y * 64 + ty * 4;
  int col0 = blockIdx.x * 64 + tx * 4;
  float acc[4][4] = {{0.f}};
  for (int k0 = 0; k0 < K; k0 += 16) {
#pragma unroll
    for (int l = 0; l < 4; ++l) {
      int e = tid + l * 256;
      int r = e >> 4, kk = e & 15;
      int gr = blockIdx.y * 64 + r;
      As[kk][r] = (gr < M) ? A[(size_t)gr * K + k0 + kk] : 0.f;
    }
#pragma unroll
    for (int l = 0; l < 4; ++l) {
      int e = tid + l * 256;
      int kk = e >> 6, c = e & 63;
      int gc = blockIdx.x * 64 + c;
      float w = 0.f;
      if (gc < Ncol)
        w = wtrans ? Wm[(size_t)gc * K + k0 + kk] : Wm[(size_t)(k0 + kk) * Ncol + gc];
      Bs[kk][c] = w;
    }
    __syncthreads();
#pragma unroll
    for (int kk = 0; kk < 16; ++kk) {
      float4 a4 = *(const float4*)&As[kk][ty * 4];
      float4 b4 = *(const float4*)&Bs[kk][tx * 4];
      float a[4] = {a4.x, a4.y, a4.z, a4.w};
      float b[4] = {b4.x, b4.y, b4.z, b4.w};
#pragma unroll
      for (int i = 0; i < 4; ++i)
#pragma unroll
        for (int j = 0; j < 4; ++j)
          acc[i][j] = fmaf(a[i], b[j], acc[i][j]);
    }
    __syncthreads();
  }
#pragma unroll
  for (int i = 0; i < 4; ++i) {
    int r = row0 + i;
    if (r >= M) continue;
#pragma unroll
    for (int j = 0; j < 4; ++j) {
      int c = col0 + j;
      if (c >= Ncol) continue;
      float val = acc[i][j];
      if (bias) val += bias[c];
      if (act == 1) val = fmaxf(val, 0.f);
      C[(size_t)r * Ncol + c] = val;
    }
  }
}

// ---------------- transformer-conv edge kernels ----------------
// score_e = ( q[dst] . k[src]  +  QE[dst] . ea[e] ) / 16 ;  m[dst] = max
__global__ __launch_bounds__(256) void edge_score_k(
    const int* __restrict__ src, const int* __restrict__ dst,
    const float* __restrict__ ea, const float* __restrict__ q,
    const float* __restrict__ kmat, const float* __restrict__ QE,
    float* __restrict__ score, float* __restrict__ m)
{
  int wv = threadIdx.x >> 6, lane = threadIdx.x & 63;
  long e0 = ((long)blockIdx.x * 4 + wv) * EPW;
  for (int t = 0; t < EPW; ++t) {
    long e = e0 + t;
    if (e >= NE) return;
    int sN = src[e], dN = dst[e];
    const float* qd = q + (size_t)dN * DH;
    const float* ks = kmat + (size_t)sN * DH;
    float partial = 0.f;
#pragma unroll
    for (int j = 0; j < 4; ++j) {
      int h = lane + j * 64;
      partial += qd[h] * ks[h];
    }
    if (lane < DED)
      partial += QE[(size_t)dN * DED + lane] * ea[(size_t)e * DED + lane];
#pragma unroll
    for (int off = 32; off > 0; off >>= 1) partial += __shfl_xor(partial, off, 64);
    if (lane == 0) {
      float sc = partial * 0.0625f;  // 1/sqrt(256)
      score[e] = sc;
      atomicMaxFloat(&m[dN], sc);
    }
  }
}

// ex = exp(score - m[dst]); denom[dst]+=ex; EA[dst]+=ex*ea; AGG[dst]+=ex*v[src]
__global__ __launch_bounds__(256) void edge_aggregate_k(
    const int* __restrict__ src, const int* __restrict__ dst,
    const float* __restrict__ ea, const float* __restrict__ v,
    const float* __restrict__ score, const float* __restrict__ m,
    float* __restrict__ denom, float* __restrict__ EA, float* __restrict__ AGG)
{
  int wv = threadIdx.x >> 6, lane = threadIdx.x & 63;
  long e0 = ((long)blockIdx.x * 4 + wv) * EPW;
  for (int t = 0; t < EPW; ++t) {
    long e = e0 + t;
    if (e >= NE) return;
    int sN = src[e], dN = dst[e];
    float ex = __expf(score[e] - m[dN]);
    if (lane == 0) atomicAdd(&denom[dN], ex);
    if (lane < DED) atomicAdd(&EA[(size_t)dN * DED + lane], ex * ea[(size_t)e * DED + lane]);
#pragma unroll
    for (int j = 0; j < 4; ++j) {
      int h = lane + j * 64;
      atomicAdd(&AGG[(size_t)dN * DH + h], ex * v[(size_t)sN * DH + h]);
    }
  }
}

// out = LN( leaky_relu( (AGG+E2N)/(denom+1e-16) + S ) ) * g + b
__global__ __launch_bounds__(256) void conv_epilogue(
    const float* __restrict__ AGG, const float* __restrict__ E2N,
    const float* __restrict__ denom, const float* __restrict__ S,
    const float* __restrict__ g, const float* __restrict__ b,
    float* __restrict__ out)
{
  __shared__ float red[256];
  __shared__ float smu, srstd;
  int n = blockIdx.x, c = threadIdx.x;
  size_t idx = (size_t)n * DH + c;
  float val = (AGG[idx] + E2N[idx]) / (denom[n] + 1e-16f) + S[idx];
  val = (val > 0.f) ? val : 0.01f * val;  // leaky_relu slope 0.01
  red[c] = val; __syncthreads();
  for (int off = 128; off > 0; off >>= 1) { if (c < off) red[c] += red[c + off]; __syncthreads(); }
  if (c == 0) smu = red[0] * (1.f / DH);
  __syncthreads();
  float d = val - smu;
  red[c] = d * d; __syncthreads();
  for (int off = 128; off > 0; off >>= 1) { if (c < off) red[c] += red[c + off]; __syncthreads(); }
  if (c == 0) srstd = rsqrtf(red[0] * (1.f / DH) + 1e-5f);
  __syncthreads();
  out[idx] = d * srstd * g[c] + b[c];
}

// ---------------- GIN ----------------
__global__ void gin_agg_k(const int* __restrict__ src, const int* __restrict__ dst,
                          const float* __restrict__ h, float* __restrict__ agg) {
  long t = (long)blockIdx.x * 256 + threadIdx.x;
  if (t >= (long)NE * 64) return;
  int e = (int)(t >> 6);
  int c = ((int)t & 63) * 4;
  int sN = src[e], dN = dst[e];
  const float4 hv = *(const float4*)&h[(size_t)sN * DH + c];
  float* p = &agg[(size_t)dN * DH + c];
  atomicAdd(p + 0, hv.x); atomicAdd(p + 1, hv.y);
  atomicAdd(p + 2, hv.z); atomicAdd(p + 3, hv.w);
}

__global__ void bn_partial(const float* __restrict__ y, float* __restrict__ sum,
                           float* __restrict__ sq, int M) {
  int c = threadIdx.x;
  int rpb = (M + gridDim.x - 1) / gridDim.x;
  int r0 = blockIdx.x * rpb;
  int r1 = min(M, r0 + rpb);
  float s = 0.f, ss = 0.f;
  for (int r = r0; r < r1; ++r) {
    float v = y[(size_t)r * DH + c];
    s += v; ss += v * v;
  }
  atomicAdd(&sum[c], s); atomicAdd(&sq[c], ss);
}

__global__ void bn_final(const float* __restrict__ sum, const float* __restrict__ sq,
                         const float* __restrict__ bng, const float* __restrict__ bnb,
                         float* __restrict__ scale, float* __restrict__ shift) {
  int c = threadIdx.x;
  float mu = sum[c] * (1.f / NN);
  float var = sq[c] * (1.f / NN) - mu * mu;
  float rstd = rsqrtf(var + 1e-5f);
  float sc = bng[c] * rstd;
  scale[c] = sc;
  shift[c] = bnb[c] - mu * sc;
}

__global__ void bn_apply_relu(const float* __restrict__ y, const float* __restrict__ scale,
                              const float* __restrict__ shift, float* __restrict__ o, int n) {
  int i = blockIdx.x * 256 + threadIdx.x;
  if (i < n) {
    int c = i & (DH - 1);
    o[i] = fmaxf(y[i] * scale[c] + shift[c], 0.f);
  }
}

// ---------------- pooling ----------------
__global__ void pool_k(const int* __restrict__ batch, const float* __restrict__ h,
                       float* __restrict__ pooled) {
  int t = blockIdx.x * 256 + threadIdx.x;
  if (t >= NN * 64) return;
  int n = t >> 6;
  int c = (t & 63) * 4;
  int gph = batch[n];
  const float4 hv = *(const float4*)&h[(size_t)n * DH + c];
  float* p = &pooled[(size_t)gph * DH + c];
  atomicAdd(p + 0, hv.x); atomicAdd(p + 1, hv.y);
  atomicAdd(p + 2, hv.z); atomicAdd(p + 3, hv.w);
}

// ---------------- host orchestration ----------------

static inline void launch_fill(hipStream_t st, float* p, float v, long n) {
  fill_f32<<<dim3((unsigned)((n + 255) / 256)), dim3(256), 0, st>>>(p, v, (int)n);
}

static void run_gemm(hipStream_t st, const float* A, const float* W, const float* bias,
                     float* C, int M, int K, int Ncol, int act, int wtrans) {
  dim3 grid((Ncol + 63) / 64, (M + 63) / 64);
  gemm_bias_act<<<grid, dim3(256), 0, st>>>(A, W, bias, C, M, K, Ncol, act, wtrans);
}

extern "C" void kernel_launch(void* const* d_in, const int* in_sizes, int n_in,
                              void* d_out, int out_size, void* d_ws, size_t ws_size,
                              hipStream_t stream) {
  const float* x  = (const float*)d_in[0];
  const int* ei   = (const int*)d_in[1];
  const float* ea = (const float*)d_in[2];
  const int* batch = (const int*)d_in[3];
  const int* src = ei;
  const int* dst = ei + NE;

  // conv params: Wq,bq,Wk,bk,Wv,bv,We,Ws,bs
  const float* c1[9]; for (int i = 0; i < 9; ++i) c1[i] = (const float*)d_in[4 + i];
  const float* ln1g = (const float*)d_in[13]; const float* ln1b = (const float*)d_in[14];
  const float* c2[9]; for (int i = 0; i < 9; ++i) c2[i] = (const float*)d_in[15 + i];
  const float* ln2g = (const float*)d_in[24]; const float* ln2b = (const float*)d_in[25];
  const float* g1[6]; for (int i = 0; i < 6; ++i) g1[i] = (const float*)d_in[26 + i];
  const float* g2[6]; for (int i = 0; i < 6; ++i) g2[i] = (const float*)d_in[32 + i];
  const float* linW = (const float*)d_in[38]; const float* linb = (const float*)d_in[39];
  const float* clfW = (const float*)d_in[40]; const float* clfb = (const float*)d_in[41];
  float* out = (float*)d_out;

  // workspace layout (floats)
  float* W = (float*)d_ws;
  const size_t NB = (size_t)NN * DH;  // 12.8M
  float* B0 = W + 0 * NB;
  float* B1 = W + 1 * NB;
  float* B2 = W + 2 * NB;
  float* B3 = W + 3 * NB;
  float* B4 = W + 4 * NB;
  float* B5 = W + 5 * NB;
  float* scoreB = W + 6 * NB;           // NE
  float* mB     = scoreB + NE;          // NN
  float* denomB = mB + NN;              // NN
  float* QEb    = denomB + NN;          // NN*32
  float* EAb    = QEb + (size_t)NN * DED;   // NN*32
  float* bnsum  = EAb + (size_t)NN * DED;   // 256
  float* bnsq   = bnsum + DH;
  float* bnscale = bnsq + DH;
  float* bnshift = bnscale + DH;
  float* pooled = bnshift + DH;         // NG*DH
  float* zbuf   = pooled + (size_t)NG * DH; // NG*DH
  size_t need = (size_t)(zbuf + (size_t)NG * DH - W) * sizeof(float);
  if (ws_size < need) return;  // insufficient workspace -> loud failure

  const float NEG_INF = -__builtin_huge_valf();

  // ---------- conv layer runner ----------
  auto conv = [&](const float* xin, int din, const float* const* P,
                  const float* lng, const float* lnb, float* outbuf) {
    run_gemm(stream, xin, P[0], P[1], B0, NN, din, DH, 0, 0);  // q
    run_gemm(stream, xin, P[2], P[3], B1, NN, din, DH, 0, 0);  // k
    run_gemm(stream, xin, P[4], P[5], B2, NN, din, DH, 0, 0);  // v
    run_gemm(stream, xin, P[7], P[8], B3, NN, din, DH, 0, 0);  // s (root)
    run_gemm(stream, B0, P[6], nullptr, QEb, NN, DH, DED, 0, 1);  // QE = q @ We^T
    launch_fill(stream, mB, NEG_INF, NN);
    launch_fill(stream, denomB, 0.f, NN);
    launch_fill(stream, B4, 0.f, (long)NB);
    launch_fill(stream, EAb, 0.f, (long)NN * DED);
    edge_score_k<<<dim3(NE / (4 * EPW)), dim3(256), 0, stream>>>(
        src, dst, ea, B0, B1, QEb, scoreB, mB);
    edge_aggregate_k<<<dim3(NE / (4 * EPW)), dim3(256), 0, stream>>>(
        src, dst, ea, B2, scoreB, mB, denomB, EAb, B4);
    run_gemm(stream, EAb, P[6], nullptr, B1, NN, DED, DH, 0, 0);  // E2N = EA @ We
    conv_epilogue<<<dim3(NN), dim3(256), 0, stream>>>(B4, B1, denomB, B3, lng, lnb, outbuf);
  };

  // ---------- GIN runner ----------
  auto gin = [&](const float* hin, const float* const* P, int relu_out, float* outbuf) {
    launch_fill(stream, B4, 0.f, (long)NB);
    gin_agg_k<<<dim3((unsigned)(((long)NE * 64 + 255) / 256)), dim3(256), 0, stream>>>(
        src, dst, hin, B4);
    ew_add<<<dim3((NN * DH + 255) / 256), dim3(256), 0, stream>>>(hin, B4, B0, NN * DH);
    run_gemm(stream, B0, P[0], P[1], B1, NN, DH, DH, 0, 0);
    launch_fill(stream, bnsum, 0.f, DH);
    launch_fill(stream, bnsq, 0.f, DH);
    bn_partial<<<dim3(256), dim3(256), 0, stream>>>(B1, bnsum, bnsq, NN);
    bn_final<<<dim3(1), dim3(256), 0, stream>>>(bnsum, bnsq, P[2], P[3], bnscale, bnshift);
    bn_apply_relu<<<dim3((NN * DH + 255) / 256), dim3(256), 0, stream>>>(
        B1, bnscale, bnshift, B0, NN * DH);
    run_gemm(stream, B0, P[4], P[5], outbuf, NN, DH, DH, relu_out, 0);
  };

  // conv1 (input x [N,128]) -> B5
  conv(x, DIN, c1, ln1g, ln1b, B5);
  // conv2 (input B5) -> B5
  conv(B5, DH, c2, ln2g, ln2b, B5);
  // gin1 -> B5 (with trailing relu), gin2 -> B5
  gin(B5, g1, 1, B5);
  gin(B5, g2, 0, B5);

  // pool + head
  launch_fill(stream, pooled, 0.f, (long)NG * DH);
  pool_k<<<dim3((NN * 64 + 255) / 256), dim3(256), 0, stream>>>(batch, B5, pooled);
  run_gemm(stream, pooled, linW, linb, zbuf, NG, DH, DH, 1, 0);
  run_gemm(stream, zbuf, clfW, clfb, out, NG, DH, DOUT, 0, 0);
}

// Round 2
// 3701.701 us; speedup vs baseline: 2.7108x; 2.7108x over previous
//
#include <hip/hip_runtime.h>
#include <math.h>

#define NN 50000     // nodes
#define NE 800000    // edges
#define DIN 128      // input feat
#define DH 256       // hidden
#define DED 32       // edge dim
#define NG 500       // graphs
#define DOUT 16      // classes
#define EPW 16       // edges per wave in edge-score kernel
#define SCAN_T 256

// ---------------- utility kernels ----------------

__global__ void fill_f32(float* __restrict__ p, float v, int n) {
  int i = blockIdx.x * 256 + threadIdx.x;
  if (i < n) p[i] = v;
}

__global__ void fill_i32(int* __restrict__ p, int v, int n) {
  int i = blockIdx.x * 256 + threadIdx.x;
  if (i < n) p[i] = v;
}

// ---------------- CSR build (by dst) ----------------

__global__ void count_k(const int* __restrict__ dst, int* __restrict__ deg) {
  int e = blockIdx.x * 256 + threadIdx.x;
  if (e < NE) atomicAdd(&deg[dst[e]], 1);
}

__global__ void scan1(const int* __restrict__ deg, int* __restrict__ rowptr,
                      int* __restrict__ bsum, int n) {
  __shared__ int s[SCAN_T];
  int t = threadIdx.x, i = blockIdx.x * SCAN_T + t;
  int v = (i < n) ? deg[i] : 0;
  s[t] = v; __syncthreads();
  for (int off = 1; off < SCAN_T; off <<= 1) {
    int add = (t >= off) ? s[t - off] : 0;
    __syncthreads();
    s[t] += add;
    __syncthreads();
  }
  if (i < n) rowptr[i + 1] = s[t];
  if (t == SCAN_T - 1) bsum[blockIdx.x] = s[t];
}

__global__ void scan2(const int* __restrict__ bsum, int* __restrict__ boff, int nb) {
  __shared__ int s[SCAN_T];
  int t = threadIdx.x;
  int v = (t < nb) ? bsum[t] : 0;
  s[t] = v; __syncthreads();
  for (int off = 1; off < SCAN_T; off <<= 1) {
    int add = (t >= off) ? s[t - off] : 0;
    __syncthreads();
    s[t] += add;
    __syncthreads();
  }
  boff[t] = s[t] - v;  // exclusive
}

__global__ void scan3(int* __restrict__ rowptr, const int* __restrict__ boff, int n) {
  int i = blockIdx.x * 256 + threadIdx.x;
  if (i < n) rowptr[i + 1] += boff[i >> 8];
  if (i == 0) rowptr[0] = 0;
}

__global__ void scatter_k(const int* __restrict__ dst, const int* __restrict__ rowptr,
                          int* __restrict__ cursor, int* __restrict__ eord) {
  int e = blockIdx.x * 256 + threadIdx.x;
  if (e < NE) {
    int d = dst[e];
    int pos = rowptr[d] + atomicAdd(&cursor[d], 1);
    eord[pos] = e;
  }
}

// ---------------- generic tiled GEMM: C = A[MxK] @ W[KxN] (+bias, act) ----------------
__global__ __launch_bounds__(256) void gemm_bias_act(
    const float* __restrict__ A, const float* __restrict__ Wm,
    const float* __restrict__ bias, float* __restrict__ C,
    int M, int K, int Ncol, int act, int wtrans)
{
  __shared__ __align__(16) float As[16][68];
  __shared__ __align__(16) float Bs[16][68];
  int tid = threadIdx.x;
  int tx = tid & 15, ty = tid >> 4;
  int row0 = blockIdx.y * 64 + ty * 4;
  int col0 = blockIdx.x * 64 + tx * 4;
  float acc[4][4] = {{0.f}};
  for (int k0 = 0; k0 < K; k0 += 16) {
#pragma unroll
    for (int l = 0; l < 4; ++l) {
      int e = tid + l * 256;
      int r = e >> 4, kk = e & 15;
      int gr = blockIdx.y * 64 + r;
      As[kk][r] = (gr < M) ? A[(size_t)gr * K + k0 + kk] : 0.f;
    }
#pragma unroll
    for (int l = 0; l < 4; ++l) {
      int e = tid + l * 256;
      int kk = e >> 6, c = e & 63;
      int gc = blockIdx.x * 64 + c;
      float w = 0.f;
      if (gc < Ncol)
        w = wtrans ? Wm[(size_t)gc * K + k0 + kk] : Wm[(size_t)(k0 + kk) * Ncol + gc];
      Bs[kk][c] = w;
    }
    __syncthreads();
#pragma unroll
    for (int kk = 0; kk < 16; ++kk) {
      float4 a4 = *(const float4*)&As[kk][ty * 4];
      float4 b4 = *(const float4*)&Bs[kk][tx * 4];
      float a[4] = {a4.x, a4.y, a4.z, a4.w};
      float b[4] = {b4.x, b4.y, b4.z, b4.w};
#pragma unroll
      for (int i = 0; i < 4; ++i)
#pragma unroll
        for (int j = 0; j < 4; ++j)
          acc[i][j] = fmaf(a[i], b[j], acc[i][j]);
    }
    __syncthreads();
  }
#pragma unroll
  for (int i = 0; i < 4; ++i) {
    int r = row0 + i;
    if (r >= M) continue;
#pragma unroll
    for (int j = 0; j < 4; ++j) {
      int c = col0 + j;
      if (c >= Ncol) continue;
      float val = acc[i][j];
      if (bias) val += bias[c];
      if (act == 1) val = fmaxf(val, 0.f);
      C[(size_t)r * Ncol + c] = val;
    }
  }
}

// ---------------- transformer-conv edge kernels ----------------
// score_e = ( q[dst] . k[src]  +  QE[dst] . ea[e] ) / 16
__global__ __launch_bounds__(256) void edge_score_k(
    const int* __restrict__ src, const int* __restrict__ dst,
    const float* __restrict__ ea, const float* __restrict__ q,
    const float* __restrict__ kmat, const float* __restrict__ QE,
    float* __restrict__ score)
{
  int wv = threadIdx.x >> 6, lane = threadIdx.x & 63;
  long e0 = ((long)blockIdx.x * 4 + wv) * EPW;
  for (int t = 0; t < EPW; ++t) {
    long e = e0 + t;
    if (e >= NE) return;
    int sN = src[e], dN = dst[e];
    const float* qd = q + (size_t)dN * DH;
    const float* ks = kmat + (size_t)sN * DH;
    float partial = 0.f;
#pragma unroll
    for (int j = 0; j < 4; ++j) {
      int h = lane + j * 64;
      partial += qd[h] * ks[h];
    }
    if (lane < DED)
      partial += QE[(size_t)dN * DED + lane] * ea[(size_t)e * DED + lane];
#pragma unroll
    for (int off = 32; off > 0; off >>= 1) partial += __shfl_xor(partial, off, 64);
    if (lane == 0) score[e] = partial * 0.0625f;  // 1/sqrt(256)
  }
}

// CSR softmax-aggregate: per node, max -> exp -> accumulate AGG/EA/denom. No atomics.
__global__ __launch_bounds__(256) void conv_agg_csr(
    const int* __restrict__ rowptr, const int* __restrict__ eord,
    const int* __restrict__ src, const float* __restrict__ score,
    const float* __restrict__ ea, const float* __restrict__ v,
    float* __restrict__ AGG, float* __restrict__ EA, float* __restrict__ denom)
{
  int wv = threadIdx.x >> 6, lane = threadIdx.x & 63;
  int n = blockIdx.x * 4 + wv;
  if (n >= NN) return;
  int i0 = rowptr[n], i1 = rowptr[n + 1];
  float mx = -__builtin_huge_valf();
  for (int i = i0; i < i1; ++i) mx = fmaxf(mx, score[eord[i]]);
  float4 acc = {0.f, 0.f, 0.f, 0.f};
  float sum_ex = 0.f, eacc = 0.f;
  int c = lane * 4;
  for (int i = i0; i < i1; ++i) {
    int e = eord[i];
    int s = src[e];
    float ex = __expf(score[e] - mx);
    sum_ex += ex;
    if (lane < DED) eacc += ex * ea[(size_t)e * DED + lane];
    float4 vv = *(const float4*)&v[(size_t)s * DH + c];
    acc.x = fmaf(ex, vv.x, acc.x);
    acc.y = fmaf(ex, vv.y, acc.y);
    acc.z = fmaf(ex, vv.z, acc.z);
    acc.w = fmaf(ex, vv.w, acc.w);
  }
  *(float4*)&AGG[(size_t)n * DH + c] = acc;
  if (lane == 0) denom[n] = sum_ex;
  if (lane < DED) EA[(size_t)n * DED + lane] = eacc;
}

// out = LN( leaky_relu( (AGG+E2N)/(denom+1e-16) + S ) ) * g + b
__global__ __launch_bounds__(256) void conv_epilogue(
    const float* __restrict__ AGG, const float* __restrict__ E2N,
    const float* __restrict__ denom, const float* __restrict__ S,
    const float* __restrict__ g, const float* __restrict__ b,
    float* __restrict__ out)
{
  __shared__ float red[256];
  __shared__ float smu, srstd;
  int n = blockIdx.x, c = threadIdx.x;
  size_t idx = (size_t)n * DH + c;
  float val = (AGG[idx] + E2N[idx]) / (denom[n] + 1e-16f) + S[idx];
  val = (val > 0.f) ? val : 0.01f * val;  // leaky_relu slope 0.01
  red[c] = val; __syncthreads();
  for (int off = 128; off > 0; off >>= 1) { if (c < off) red[c] += red[c + off]; __syncthreads(); }
  if (c == 0) smu = red[0] * (1.f / DH);
  __syncthreads();
  float d = val - smu;
  red[c] = d * d; __syncthreads();
  for (int off = 128; off > 0; off >>= 1) { if (c < off) red[c] += red[c + off]; __syncthreads(); }
  if (c == 0) srstd = rsqrtf(red[0] * (1.f / DH) + 1e-5f);
  __syncthreads();
  out[idx] = d * srstd * g[c] + b[c];
}

// ---------------- GIN: CSR gather fused with self term ----------------
__global__ __launch_bounds__(256) void gin_gather(
    const int* __restrict__ rowptr, const int* __restrict__ eord,
    const int* __restrict__ src, const float* __restrict__ h,
    float* __restrict__ out)
{
  int wv = threadIdx.x >> 6, lane = threadIdx.x & 63;
  int n = blockIdx.x * 4 + wv;
  if (n >= NN) return;
  int c = lane * 4;
  float4 acc = *(const float4*)&h[(size_t)n * DH + c];  // self (eps=0)
  int i0 = rowptr[n], i1 = rowptr[n + 1];
  for (int i = i0; i < i1; ++i) {
    int s = src[eord[i]];
    float4 hv = *(const float4*)&h[(size_t)s * DH + c];
    acc.x += hv.x; acc.y += hv.y; acc.z += hv.z; acc.w += hv.w;
  }
  *(float4*)&out[(size_t)n * DH + c] = acc;
}

__global__ void bn_partial(const float* __restrict__ y, float* __restrict__ sum,
                           float* __restrict__ sq, int M) {
  int c = threadIdx.x;
  int rpb = (M + gridDim.x - 1) / gridDim.x;
  int r0 = blockIdx.x * rpb;
  int r1 = min(M, r0 + rpb);
  float s = 0.f, ss = 0.f;
  for (int r = r0; r < r1; ++r) {
    float v = y[(size_t)r * DH + c];
    s += v; ss += v * v;
  }
  atomicAdd(&sum[c], s); atomicAdd(&sq[c], ss);
}

__global__ void bn_final(const float* __restrict__ sum, const float* __restrict__ sq,
                         const float* __restrict__ bng, const float* __restrict__ bnb,
                         float* __restrict__ scale, float* __restrict__ shift) {
  int c = threadIdx.x;
  float mu = sum[c] * (1.f / NN);
  float var = sq[c] * (1.f / NN) - mu * mu;
  float rstd = rsqrtf(var + 1e-5f);
  float sc = bng[c] * rstd;
  scale[c] = sc;
  shift[c] = bnb[c] - mu * sc;
}

__global__ void bn_apply_relu(const float* __restrict__ y, const float* __restrict__ scale,
                              const float* __restrict__ shift, float* __restrict__ o, int n) {
  int i = blockIdx.x * 256 + threadIdx.x;
  if (i < n) {
    int c = i & (DH - 1);
    o[i] = fmaxf(y[i] * scale[c] + shift[c], 0.f);
  }
}

// ---------------- pooling over sorted batch ----------------
__global__ __launch_bounds__(256) void pool_sorted(
    const int* __restrict__ batch, const float* __restrict__ h,
    float* __restrict__ pooled)
{
  __shared__ int s0, s1;
  int g = blockIdx.x;
  if (threadIdx.x == 0) {
    int lo = 0, hi = NN;
    while (lo < hi) { int mid = (lo + hi) >> 1; if (batch[mid] < g) lo = mid + 1; else hi = mid; }
    s0 = lo;
  }
  if (threadIdx.x == 1) {
    int lo = 0, hi = NN;
    while (lo < hi) { int mid = (lo + hi) >> 1; if (batch[mid] < g + 1) lo = mid + 1; else hi = mid; }
    s1 = lo;
  }
  __syncthreads();
  int c = threadIdx.x;
  float acc = 0.f;
  for (int r = s0; r < s1; ++r) acc += h[(size_t)r * DH + c];
  pooled[(size_t)g * DH + c] = acc;
}

// ---------------- host orchestration ----------------

static inline void launch_fillf(hipStream_t st, float* p, float v, long n) {
  fill_f32<<<dim3((unsigned)((n + 255) / 256)), dim3(256), 0, st>>>(p, v, (int)n);
}
static inline void launch_filli(hipStream_t st, int* p, int v, long n) {
  fill_i32<<<dim3((unsigned)((n + 255) / 256)), dim3(256), 0, st>>>(p, v, (int)n);
}

static void run_gemm(hipStream_t st, const float* A, const float* W, const float* bias,
                     float* C, int M, int K, int Ncol, int act, int wtrans) {
  dim3 grid((Ncol + 63) / 64, (M + 63) / 64);
  gemm_bias_act<<<grid, dim3(256), 0, st>>>(A, W, bias, C, M, K, Ncol, act, wtrans);
}

extern "C" void kernel_launch(void* const* d_in, const int* in_sizes, int n_in,
                              void* d_out, int out_size, void* d_ws, size_t ws_size,
                              hipStream_t stream) {
  const float* x  = (const float*)d_in[0];
  const int* ei   = (const int*)d_in[1];
  const float* ea = (const float*)d_in[2];
  const int* batch = (const int*)d_in[3];
  const int* src = ei;
  const int* dst = ei + NE;

  const float* c1[9]; for (int i = 0; i < 9; ++i) c1[i] = (const float*)d_in[4 + i];
  const float* ln1g = (const float*)d_in[13]; const float* ln1b = (const float*)d_in[14];
  const float* c2[9]; for (int i = 0; i < 9; ++i) c2[i] = (const float*)d_in[15 + i];
  const float* ln2g = (const float*)d_in[24]; const float* ln2b = (const float*)d_in[25];
  const float* g1[6]; for (int i = 0; i < 6; ++i) g1[i] = (const float*)d_in[26 + i];
  const float* g2[6]; for (int i = 0; i < 6; ++i) g2[i] = (const float*)d_in[32 + i];
  const float* linW = (const float*)d_in[38]; const float* linb = (const float*)d_in[39];
  const float* clfW = (const float*)d_in[40]; const float* clfb = (const float*)d_in[41];
  float* out = (float*)d_out;

  // workspace layout
  float* W = (float*)d_ws;
  const size_t NB = (size_t)NN * DH;  // 12.8M floats
  float* B0 = W + 0 * NB;
  float* B1 = W + 1 * NB;
  float* B2 = W + 2 * NB;
  float* B3 = W + 3 * NB;
  float* B4 = W + 4 * NB;
  float* B5 = W + 5 * NB;
  float* scoreB = W + 6 * NB;               // NE
  float* denomB = scoreB + NE;              // NN
  float* QEb    = denomB + NN;              // NN*32
  float* EAb    = QEb + (size_t)NN * DED;   // NN*32
  float* bnsum  = EAb + (size_t)NN * DED;   // 256
  float* bnsq   = bnsum + DH;
  float* bnscale = bnsq + DH;
  float* bnshift = bnscale + DH;
  float* pooled = bnshift + DH;             // NG*DH
  float* zbuf   = pooled + (size_t)NG * DH; // NG*DH
  // int region for CSR
  int* ibase = (int*)(zbuf + (size_t)NG * DH);
  int* deg    = ibase;                 // NN
  int* cursor = deg + NN;              // NN
  int* rowptr = cursor + NN;           // NN+1
  int* eord   = rowptr + NN + 1;       // NE
  int* bsum   = eord + NE;             // 256
  int* boff   = bsum + 256;            // 256
  size_t need = (size_t)((char*)(boff + 256) - (char*)d_ws);
  if (ws_size < need) return;

  // ---------- CSR build (once; shared by both convs and both GINs) ----------
  const int nb1 = (NN + SCAN_T - 1) / SCAN_T;  // 196
  launch_filli(stream, deg, 0, NN);
  launch_filli(stream, cursor, 0, NN);
  count_k<<<dim3((NE + 255) / 256), dim3(256), 0, stream>>>(dst, deg);
  scan1<<<dim3(nb1), dim3(SCAN_T), 0, stream>>>(deg, rowptr, bsum, NN);
  scan2<<<dim3(1), dim3(SCAN_T), 0, stream>>>(bsum, boff, nb1);
  scan3<<<dim3(nb1), dim3(SCAN_T), 0, stream>>>(rowptr, boff, NN);
  scatter_k<<<dim3((NE + 255) / 256), dim3(256), 0, stream>>>(dst, rowptr, cursor, eord);

  // ---------- conv layer runner ----------
  auto conv = [&](const float* xin, int din, const float* const* P,
                  const float* lng, const float* lnb, float* outbuf) {
    run_gemm(stream, xin, P[0], P[1], B0, NN, din, DH, 0, 0);  // q
    run_gemm(stream, xin, P[2], P[3], B1, NN, din, DH, 0, 0);  // k
    run_gemm(stream, xin, P[4], P[5], B2, NN, din, DH, 0, 0);  // v
    run_gemm(stream, xin, P[7], P[8], B3, NN, din, DH, 0, 0);  // s (root)
    run_gemm(stream, B0, P[6], nullptr, QEb, NN, DH, DED, 0, 1);  // QE = q @ We^T
    edge_score_k<<<dim3(NE / (4 * EPW)), dim3(256), 0, stream>>>(
        src, dst, ea, B0, B1, QEb, scoreB);
    conv_agg_csr<<<dim3((NN + 3) / 4), dim3(256), 0, stream>>>(
        rowptr, eord, src, scoreB, ea, B2, B4, EAb, denomB);
    run_gemm(stream, EAb, P[6], nullptr, B1, NN, DED, DH, 0, 0);  // E2N = EA @ We
    conv_epilogue<<<dim3(NN), dim3(256), 0, stream>>>(B4, B1, denomB, B3, lng, lnb, outbuf);
  };

  // ---------- GIN runner ----------
  auto gin = [&](const float* hin, const float* const* P, int relu_out, float* outbuf) {
    gin_gather<<<dim3((NN + 3) / 4), dim3(256), 0, stream>>>(rowptr, eord, src, hin, B0);
    run_gemm(stream, B0, P[0], P[1], B1, NN, DH, DH, 0, 0);
    launch_fillf(stream, bnsum, 0.f, DH);
    launch_fillf(stream, bnsq, 0.f, DH);
    bn_partial<<<dim3(256), dim3(256), 0, stream>>>(B1, bnsum, bnsq, NN);
    bn_final<<<dim3(1), dim3(256), 0, stream>>>(bnsum, bnsq, P[2], P[3], bnscale, bnshift);
    bn_apply_relu<<<dim3((NN * DH + 255) / 256), dim3(256), 0, stream>>>(
        B1, bnscale, bnshift, B0, NN * DH);
    run_gemm(stream, B0, P[4], P[5], outbuf, NN, DH, DH, relu_out, 0);
  };

  // conv1 (input x [N,128]) -> B5 ; conv2 -> B5 ; gin1 -> B5 ; gin2 -> B5
  conv(x, DIN, c1, ln1g, ln1b, B5);
  conv(B5, DH, c2, ln2g, ln2b, B5);
  gin(B5, g1, 1, B5);
  gin(B5, g2, 0, B5);

  // pool + head
  pool_sorted<<<dim3(NG), dim3(256), 0, stream>>>(batch, B5, pooled);
  run_gemm(stream, pooled, linW, linb, zbuf, NG, DH, DH, 1, 0);
  run_gemm(stream, zbuf, clfW, clfb, out, NG, DH, DOUT, 0, 0);
}

// Round 3
// 2417.482 us; speedup vs baseline: 4.1508x; 1.5312x over previous
//
#include <hip/hip_runtime.h>
#include <math.h>

#define NN 50000
#define NE 800000
#define DIN 128
#define DH 256
#define DED 32
#define NG 500
#define DOUT 16
#define SCAN_T 256

typedef __bf16 bf16_t;
typedef __bf16 bf16x4 __attribute__((ext_vector_type(4)));
typedef __bf16 bf16x8 __attribute__((ext_vector_type(8)));
typedef float f32x4 __attribute__((ext_vector_type(4)));

// ---------------- utility ----------------
__global__ void fill_f32(float* __restrict__ p, float v, int n) {
  int i = blockIdx.x * 256 + threadIdx.x;
  if (i < n) p[i] = v;
}
__global__ void fill_i32(int* __restrict__ p, int v, int n) {
  int i = blockIdx.x * 256 + threadIdx.x;
  if (i < n) p[i] = v;
}
__global__ void cast_bf16_k(const float* __restrict__ in, bf16_t* __restrict__ o, long n) {
  long i = (long)blockIdx.x * 256 + threadIdx.x;
  if (i < n) o[i] = (bf16_t)in[i];
}

// ---------------- CSR build (by dst) ----------------
__global__ void count_k(const int* __restrict__ dst, int* __restrict__ deg) {
  int e = blockIdx.x * 256 + threadIdx.x;
  if (e < NE) atomicAdd(&deg[dst[e]], 1);
}
__global__ void scan1(const int* __restrict__ deg, int* __restrict__ rowptr,
                      int* __restrict__ bsum, int n) {
  __shared__ int s[SCAN_T];
  int t = threadIdx.x, i = blockIdx.x * SCAN_T + t;
  int v = (i < n) ? deg[i] : 0;
  s[t] = v; __syncthreads();
  for (int off = 1; off < SCAN_T; off <<= 1) {
    int add = (t >= off) ? s[t - off] : 0;
    __syncthreads(); s[t] += add; __syncthreads();
  }
  if (i < n) rowptr[i + 1] = s[t];
  if (t == SCAN_T - 1) bsum[blockIdx.x] = s[t];
}
__global__ void scan2(const int* __restrict__ bsum, int* __restrict__ boff, int nb) {
  __shared__ int s[SCAN_T];
  int t = threadIdx.x;
  int v = (t < nb) ? bsum[t] : 0;
  s[t] = v; __syncthreads();
  for (int off = 1; off < SCAN_T; off <<= 1) {
    int add = (t >= off) ? s[t - off] : 0;
    __syncthreads(); s[t] += add; __syncthreads();
  }
  boff[t] = s[t] - v;
}
__global__ void scan3(int* __restrict__ rowptr, const int* __restrict__ boff, int n) {
  int i = blockIdx.x * 256 + threadIdx.x;
  if (i < n) rowptr[i + 1] += boff[i >> 8];
  if (i == 0) rowptr[0] = 0;
}
__global__ void scatter_k(const int* __restrict__ dst, const int* __restrict__ rowptr,
                          int* __restrict__ cursor, int* __restrict__ eord) {
  int e = blockIdx.x * 256 + threadIdx.x;
  if (e < NE) {
    int d = dst[e];
    int pos = rowptr[d] + atomicAdd(&cursor[d], 1);
    eord[pos] = e;
  }
}

// ---------------- weight fragment packing ----------------
// frag f=(ks,t): element lane*8+j = W[ks*32+(lane>>4)*8+j][t*16+(lane&15)]
__global__ void pack_w(const float* __restrict__ Wsrc, bf16_t* __restrict__ Wp,
                       int K, int Ncols) {
  int i = blockIdx.x * 256 + threadIdx.x;
  if (i >= K * Ncols) return;
  int e = i & 511, f = i >> 9;
  int ntiles = Ncols >> 4;
  int ks = f / ntiles, t = f - ks * ntiles;
  int lane = e >> 3, j = e & 7;
  int k = ks * 32 + (lane >> 4) * 8 + j;
  int n = t * 16 + (lane & 15);
  Wp[i] = (bf16_t)Wsrc[(size_t)k * Ncols + n];
}

// Wqe[d][j] = sum_h Wq[d][h]*We[j][h]; bqe[j] = sum_h bq[h]*We[j][h]
__global__ void wqe_k(const float* __restrict__ Wq, const float* __restrict__ We,
                      const float* __restrict__ bq, float* __restrict__ Wqe,
                      float* __restrict__ bqe, int din) {
  int idx = blockIdx.x * 256 + threadIdx.x;
  if (idx < din * 32) {
    int d = idx >> 5, j = idx & 31;
    float s = 0.f;
    for (int h = 0; h < DH; ++h) s += Wq[(size_t)d * DH + h] * We[(size_t)j * DH + h];
    Wqe[idx] = s;
  }
  if (idx < 32) {
    float s = 0.f;
    for (int h = 0; h < DH; ++h) s += bq[h] * We[(size_t)idx * DH + h];
    bqe[idx] = s;
  }
}

// ---------------- MFMA GEMM: C = A[MxK](bf16) @ Wp(packed bf16) + bias ----------------
// block: 4 waves x 32 rows = 128 rows; each wave: 2 row-tiles x NT col-tiles
template<int NT>
__global__ __launch_bounds__(256) void gemm_mfma(
    const bf16_t* __restrict__ Ab, const bf16_t* __restrict__ Wp,
    const float* __restrict__ bias, float* __restrict__ Cf, bf16_t* __restrict__ Cb,
    int M, int K, int relu)
{
  const int Ncols = NT * 16;
  int lane = threadIdx.x & 63, wv = threadIdx.x >> 6;
  int base = blockIdx.x * 128 + wv * 32;
  int rA0 = base + (lane & 15);
  int rA1 = rA0 + 16;
  int kq = (lane >> 4) * 8;
  f32x4 acc[2][NT];
#pragma unroll
  for (int rt = 0; rt < 2; ++rt)
#pragma unroll
    for (int t = 0; t < NT; ++t) acc[rt][t] = (f32x4){0.f, 0.f, 0.f, 0.f};
  bf16x8 az;
#pragma unroll
  for (int j = 0; j < 8; ++j) az[j] = (bf16_t)0.f;
  int nk = K >> 5;
  for (int ks = 0; ks < nk; ++ks) {
    bf16x8 a0 = (rA0 < M) ? *(const bf16x8*)&Ab[(size_t)rA0 * K + ks * 32 + kq] : az;
    bf16x8 a1 = (rA1 < M) ? *(const bf16x8*)&Ab[(size_t)rA1 * K + ks * 32 + kq] : az;
    const bf16_t* wb = Wp + ((size_t)ks * NT) * 512 + lane * 8;
#pragma unroll
    for (int t = 0; t < NT; ++t) {
      bf16x8 b = *(const bf16x8*)(wb + t * 512);
      acc[0][t] = __builtin_amdgcn_mfma_f32_16x16x32_bf16(a0, b, acc[0][t], 0, 0, 0);
      acc[1][t] = __builtin_amdgcn_mfma_f32_16x16x32_bf16(a1, b, acc[1][t], 0, 0, 0);
    }
  }
  int col_l = lane & 15;
#pragma unroll
  for (int rt = 0; rt < 2; ++rt) {
    int rbase = base + rt * 16 + (lane >> 4) * 4;
#pragma unroll
    for (int t = 0; t < NT; ++t) {
      int col = t * 16 + col_l;
      float bv = bias ? bias[col] : 0.f;
#pragma unroll
      for (int r = 0; r < 4; ++r) {
        int row = rbase + r;
        if (row >= M) continue;
        float vv = acc[rt][t][r] + bv;
        if (relu) vv = fmaxf(vv, 0.f);
        if (Cf) Cf[(size_t)row * Ncols + col] = vv;
        if (Cb) Cb[(size_t)row * Ncols + col] = (bf16_t)vv;
      }
    }
  }
}

// ---------------- fused edge softmax-aggregate (CSR, online) ----------------
__global__ __launch_bounds__(256) void conv_edge_fused(
    const int* __restrict__ rowptr, const int* __restrict__ eord, const int* __restrict__ src,
    const bf16_t* __restrict__ qb, const bf16_t* __restrict__ kb, const bf16_t* __restrict__ vb,
    const bf16_t* __restrict__ eab, const float* __restrict__ QEf,
    float* __restrict__ AGG, bf16_t* __restrict__ EAb, float* __restrict__ denom)
{
  int wv = threadIdx.x >> 6, lane = threadIdx.x & 63;
  int n = blockIdx.x * 4 + wv;
  if (n >= NN) return;
  float q0, q1, q2, q3;
  {
    bf16x4 t = *(const bf16x4*)&qb[(size_t)n * DH + lane * 4];
    q0 = (float)t[0]; q1 = (float)t[1]; q2 = (float)t[2]; q3 = (float)t[3];
  }
  float qe = (lane < DED) ? QEf[(size_t)n * DED + lane] : 0.f;
  float m = -__builtin_huge_valf(), s = 0.f, eacc = 0.f;
  float a0 = 0.f, a1 = 0.f, a2 = 0.f, a3 = 0.f;
  int i0 = rowptr[n], i1 = rowptr[n + 1];
  for (int i = i0; i < i1; ++i) {
    int e = eord[i];
    int sN = src[e];
    bf16x4 kt = *(const bf16x4*)&kb[(size_t)sN * DH + lane * 4];
    bf16x4 vt = *(const bf16x4*)&vb[(size_t)sN * DH + lane * 4];
    float eav = (lane < DED) ? (float)eab[(size_t)e * DED + lane] : 0.f;
    float partial = q0 * (float)kt[0] + q1 * (float)kt[1] +
                    q2 * (float)kt[2] + q3 * (float)kt[3] + qe * eav;
#pragma unroll
    for (int off = 32; off > 0; off >>= 1) partial += __shfl_xor(partial, off, 64);
    float sc = partial * 0.0625f;  // 1/sqrt(256)
    float nm = fmaxf(m, sc);
    float sca = __expf(m - nm);    // first iter: exp(-inf)=0
    float ex = __expf(sc - nm);
    s = s * sca + ex;
    a0 = a0 * sca + ex * (float)vt[0];
    a1 = a1 * sca + ex * (float)vt[1];
    a2 = a2 * sca + ex * (float)vt[2];
    a3 = a3 * sca + ex * (float)vt[3];
    eacc = eacc * sca + ex * eav;
    m = nm;
  }
  float4 o; o.x = a0; o.y = a1; o.z = a2; o.w = a3;
  *(float4*)&AGG[(size_t)n * DH + lane * 4] = o;
  if (lane == 0) denom[n] = s;
  if (lane < DED) EAb[(size_t)n * DED + lane] = (bf16_t)eacc;
}

// out_bf16 = LN( leaky_relu( (AGG+E2N)/(denom+1e-16) + S ) ) * g + b
__global__ __launch_bounds__(256) void conv_epilogue(
    const float* __restrict__ AGG, const bf16_t* __restrict__ E2N,
    const float* __restrict__ denom, const bf16_t* __restrict__ S,
    const float* __restrict__ g, const float* __restrict__ b,
    bf16_t* __restrict__ out)
{
  __shared__ float red[256];
  __shared__ float smu, srstd;
  int n = blockIdx.x, c = threadIdx.x;
  size_t idx = (size_t)n * DH + c;
  float val = (AGG[idx] + (float)E2N[idx]) / (denom[n] + 1e-16f) + (float)S[idx];
  val = (val > 0.f) ? val : 0.01f * val;
  red[c] = val; __syncthreads();
  for (int off = 128; off > 0; off >>= 1) { if (c < off) red[c] += red[c + off]; __syncthreads(); }
  if (c == 0) smu = red[0] * (1.f / DH);
  __syncthreads();
  float d = val - smu;
  red[c] = d * d; __syncthreads();
  for (int off = 128; off > 0; off >>= 1) { if (c < off) red[c] += red[c + off]; __syncthreads(); }
  if (c == 0) srstd = rsqrtf(red[0] * (1.f / DH) + 1e-5f);
  __syncthreads();
  out[idx] = (bf16_t)(d * srstd * g[c] + b[c]);
}

// ---------------- GIN gather (bf16 in/out, fp32 accumulate) ----------------
__global__ __launch_bounds__(256) void gin_gather(
    const int* __restrict__ rowptr, const int* __restrict__ eord,
    const int* __restrict__ src, const bf16_t* __restrict__ h,
    bf16_t* __restrict__ out)
{
  int wv = threadIdx.x >> 6, lane = threadIdx.x & 63;
  int n = blockIdx.x * 4 + wv;
  if (n >= NN) return;
  int c = lane * 4;
  bf16x4 hv = *(const bf16x4*)&h[(size_t)n * DH + c];
  float a0 = (float)hv[0], a1 = (float)hv[1], a2 = (float)hv[2], a3 = (float)hv[3];
  int i0 = rowptr[n], i1 = rowptr[n + 1];
  for (int i = i0; i < i1; ++i) {
    int s = src[eord[i]];
    bf16x4 t = *(const bf16x4*)&h[(size_t)s * DH + c];
    a0 += (float)t[0]; a1 += (float)t[1]; a2 += (float)t[2]; a3 += (float)t[3];
  }
  bf16x4 o; o[0] = (bf16_t)a0; o[1] = (bf16_t)a1; o[2] = (bf16_t)a2; o[3] = (bf16_t)a3;
  *(bf16x4*)&out[(size_t)n * DH + c] = o;
}

// ---------------- BN ----------------
__global__ void bn_partial(const float* __restrict__ y, float* __restrict__ sum,
                           float* __restrict__ sq, int M) {
  int c = threadIdx.x;
  int rpb = (M + gridDim.x - 1) / gridDim.x;
  int r0 = blockIdx.x * rpb;
  int r1 = min(M, r0 + rpb);
  float s = 0.f, ss = 0.f;
  for (int r = r0; r < r1; ++r) {
    float v = y[(size_t)r * DH + c];
    s += v; ss += v * v;
  }
  atomicAdd(&sum[c], s); atomicAdd(&sq[c], ss);
}
__global__ void bn_final(const float* __restrict__ sum, const float* __restrict__ sq,
                         const float* __restrict__ bng, const float* __restrict__ bnb,
                         float* __restrict__ scale, float* __restrict__ shift) {
  int c = threadIdx.x;
  float mu = sum[c] * (1.f / NN);
  float var = sq[c] * (1.f / NN) - mu * mu;
  float rstd = rsqrtf(var + 1e-5f);
  float sc = bng[c] * rstd;
  scale[c] = sc;
  shift[c] = bnb[c] - mu * sc;
}
__global__ void bn_apply_relu(const float* __restrict__ y, const float* __restrict__ scale,
                              const float* __restrict__ shift, bf16_t* __restrict__ o, int n) {
  int i = blockIdx.x * 256 + threadIdx.x;
  if (i < n) {
    int c = i & (DH - 1);
    o[i] = (bf16_t)fmaxf(y[i] * scale[c] + shift[c], 0.f);
  }
}

// ---------------- pooling over sorted batch ----------------
__global__ __launch_bounds__(256) void pool_sorted(
    const int* __restrict__ batch, const float* __restrict__ h, float* __restrict__ pooled)
{
  __shared__ int s0, s1;
  int g = blockIdx.x;
  if (threadIdx.x == 0) {
    int lo = 0, hi = NN;
    while (lo < hi) { int mid = (lo + hi) >> 1; if (batch[mid] < g) lo = mid + 1; else hi = mid; }
    s0 = lo;
  }
  if (threadIdx.x == 1) {
    int lo = 0, hi = NN;
    while (lo < hi) { int mid = (lo + hi) >> 1; if (batch[mid] < g + 1) lo = mid + 1; else hi = mid; }
    s1 = lo;
  }
  __syncthreads();
  int c = threadIdx.x;
  float acc = 0.f;
  for (int r = s0; r < s1; ++r) acc += h[(size_t)r * DH + c];
  pooled[(size_t)g * DH + c] = acc;
}

// ---------------- small fp32 GEMM (head only) ----------------
__global__ __launch_bounds__(256) void gemm_bias_act(
    const float* __restrict__ A, const float* __restrict__ Wm,
    const float* __restrict__ bias, float* __restrict__ C,
    int M, int K, int Ncol, int act)
{
  __shared__ __align__(16) float As[16][68];
  __shared__ __align__(16) float Bs[16][68];
  int tid = threadIdx.x;
  int tx = tid & 15, ty = tid >> 4;
  int row0 = blockIdx.y * 64 + ty * 4;
  int col0 = blockIdx.x * 64 + tx * 4;
  float acc[4][4] = {{0.f}};
  for (int k0 = 0; k0 < K; k0 += 16) {
#pragma unroll
    for (int l = 0; l < 4; ++l) {
      int e = tid + l * 256;
      int r = e >> 4, kk = e & 15;
      int gr = blockIdx.y * 64 + r;
      As[kk][r] = (gr < M) ? A[(size_t)gr * K + k0 + kk] : 0.f;
    }
#pragma unroll
    for (int l = 0; l < 4; ++l) {
      int e = tid + l * 256;
      int kk = e >> 6, c = e & 63;
      int gc = blockIdx.x * 64 + c;
      Bs[kk][c] = (gc < Ncol) ? Wm[(size_t)(k0 + kk) * Ncol + gc] : 0.f;
    }
    __syncthreads();
#pragma unroll
    for (int kk = 0; kk < 16; ++kk) {
      float4 a4 = *(const float4*)&As[kk][ty * 4];
      float4 b4 = *(const float4*)&Bs[kk][tx * 4];
      float a[4] = {a4.x, a4.y, a4.z, a4.w};
      float b[4] = {b4.x, b4.y, b4.z, b4.w};
#pragma unroll
      for (int i = 0; i < 4; ++i)
#pragma unroll
        for (int j = 0; j < 4; ++j)
          acc[i][j] = fmaf(a[i], b[j], acc[i][j]);
    }
    __syncthreads();
  }
#pragma unroll
  for (int i = 0; i < 4; ++i) {
    int r = row0 + i;
    if (r >= M) continue;
#pragma unroll
    for (int j = 0; j < 4; ++j) {
      int c = col0 + j;
      if (c >= Ncol) continue;
      float val = acc[i][j];
      if (bias) val += bias[c];
      if (act == 1) val = fmaxf(val, 0.f);
      C[(size_t)r * Ncol + c] = val;
    }
  }
}

// ---------------- host ----------------
static inline void launch_fillf(hipStream_t st, float* p, float v, long n) {
  fill_f32<<<dim3((unsigned)((n + 255) / 256)), dim3(256), 0, st>>>(p, v, (int)n);
}
static inline void launch_filli(hipStream_t st, int* p, int v, long n) {
  fill_i32<<<dim3((unsigned)((n + 255) / 256)), dim3(256), 0, st>>>(p, v, (int)n);
}
static inline void launch_cast(hipStream_t st, const float* in, bf16_t* o, long n) {
  cast_bf16_k<<<dim3((unsigned)((n + 255) / 256)), dim3(256), 0, st>>>(in, o, n);
}
static inline void launch_pack(hipStream_t st, const float* Wsrc, bf16_t* Wp, int K, int Ncol) {
  pack_w<<<dim3((K * Ncol + 255) / 256), dim3(256), 0, st>>>(Wsrc, Wp, K, Ncol);
}

extern "C" void kernel_launch(void* const* d_in, const int* in_sizes, int n_in,
                              void* d_out, int out_size, void* d_ws, size_t ws_size,
                              hipStream_t stream) {
  const float* x  = (const float*)d_in[0];
  const int* ei   = (const int*)d_in[1];
  const float* ea = (const float*)d_in[2];
  const int* batch = (const int*)d_in[3];
  const int* src = ei;
  const int* dst = ei + NE;

  const float* c1[9]; for (int i = 0; i < 9; ++i) c1[i] = (const float*)d_in[4 + i];
  const float* ln1g = (const float*)d_in[13]; const float* ln1b = (const float*)d_in[14];
  const float* c2[9]; for (int i = 0; i < 9; ++i) c2[i] = (const float*)d_in[15 + i];
  const float* ln2g = (const float*)d_in[24]; const float* ln2b = (const float*)d_in[25];
  const float* g1[6]; for (int i = 0; i < 6; ++i) g1[i] = (const float*)d_in[26 + i];
  const float* g2[6]; for (int i = 0; i < 6; ++i) g2[i] = (const float*)d_in[32 + i];
  const float* linW = (const float*)d_in[38]; const float* linb = (const float*)d_in[39];
  const float* clfW = (const float*)d_in[40]; const float* clfb = (const float*)d_in[41];
  float* out = (float*)d_out;

  // ---- bump allocator over d_ws (256B aligned) ----
  size_t off = 0;
  auto alloc = [&](size_t bytes) -> void* {
    void* r = (char*)d_ws + off;
    off += (bytes + 255) & ~(size_t)255;
    return r;
  };
  // ints
  int* deg    = (int*)alloc(NN * 4);
  int* cursor = (int*)alloc(NN * 4);
  int* rowptr = (int*)alloc((NN + 1) * 4);
  int* eord   = (int*)alloc((size_t)NE * 4);
  int* bsum   = (int*)alloc(1024);
  int* boff   = (int*)alloc(1024);
  // fp32
  float* QEf   = (float*)alloc((size_t)NN * DED * 4);
  float* denom = (float*)alloc((size_t)NN * 4);
  float* AGG   = (float*)alloc((size_t)NN * DH * 4);   // also Y for GIN
  float* pooled = (float*)alloc((size_t)NG * DH * 4);
  float* zbuf   = (float*)alloc((size_t)NG * DH * 4);
  float* bnsum = (float*)alloc(DH * 4);
  float* bnsq  = (float*)alloc(DH * 4);
  float* bnscale = (float*)alloc(DH * 4);
  float* bnshift = (float*)alloc(DH * 4);
  float* wqe_tmp = (float*)alloc((size_t)DH * DED * 4);
  float* bqe1 = (float*)alloc(DED * 4);
  float* bqe2 = (float*)alloc(DED * 4);
  // bf16 activations (qb and kb MUST be adjacent: Hout aliases them)
  bf16_t* qb = (bf16_t*)alloc((size_t)NN * DH * 2);
  bf16_t* kb = (bf16_t*)alloc((size_t)NN * DH * 2);
  bf16_t* vb = (bf16_t*)alloc((size_t)NN * DH * 2);
  bf16_t* sb = (bf16_t*)alloc((size_t)NN * DH * 2);
  bf16_t* h_b = (bf16_t*)alloc((size_t)NN * DH * 2);
  bf16_t* g_b = (bf16_t*)alloc((size_t)NN * DH * 2);
  bf16_t* E2Nb = (bf16_t*)alloc((size_t)NN * DH * 2);
  bf16_t* EAb = (bf16_t*)alloc((size_t)NN * DED * 2);
  bf16_t* xb  = (bf16_t*)alloc((size_t)NN * DIN * 2);
  bf16_t* eab = (bf16_t*)alloc((size_t)NE * DED * 2);
  float* Hout = (float*)qb;  // 50000*256*4 = qb+kb region, free during GIN phase
  // packed weights
  bf16_t* pk1q = (bf16_t*)alloc(DIN * DH * 2);
  bf16_t* pk1k = (bf16_t*)alloc(DIN * DH * 2);
  bf16_t* pk1v = (bf16_t*)alloc(DIN * DH * 2);
  bf16_t* pk1s = (bf16_t*)alloc(DIN * DH * 2);
  bf16_t* pk1qe = (bf16_t*)alloc(DIN * DED * 2);
  bf16_t* pk1we = (bf16_t*)alloc(DED * DH * 2);
  bf16_t* pk2q = (bf16_t*)alloc(DH * DH * 2);
  bf16_t* pk2k = (bf16_t*)alloc(DH * DH * 2);
  bf16_t* pk2v = (bf16_t*)alloc(DH * DH * 2);
  bf16_t* pk2s = (bf16_t*)alloc(DH * DH * 2);
  bf16_t* pk2qe = (bf16_t*)alloc(DH * DED * 2);
  bf16_t* pk2we = (bf16_t*)alloc(DED * DH * 2);
  bf16_t* pkg1a = (bf16_t*)alloc(DH * DH * 2);
  bf16_t* pkg1b = (bf16_t*)alloc(DH * DH * 2);
  bf16_t* pkg2a = (bf16_t*)alloc(DH * DH * 2);
  bf16_t* pkg2b = (bf16_t*)alloc(DH * DH * 2);
  if (ws_size < off) return;

  const int GRID_M = (NN + 127) / 128;  // gemm_mfma grid

  // ---- casts & weight packing ----
  launch_cast(stream, x, xb, (long)NN * DIN);
  launch_cast(stream, ea, eab, (long)NE * DED);
  launch_pack(stream, c1[0], pk1q, DIN, DH);
  launch_pack(stream, c1[2], pk1k, DIN, DH);
  launch_pack(stream, c1[4], pk1v, DIN, DH);
  launch_pack(stream, c1[7], pk1s, DIN, DH);
  launch_pack(stream, c1[6], pk1we, DED, DH);
  wqe_k<<<dim3((DIN * 32 + 255) / 256), dim3(256), 0, stream>>>(c1[0], c1[6], c1[1], wqe_tmp, bqe1, DIN);
  launch_pack(stream, wqe_tmp, pk1qe, DIN, DED);
  launch_pack(stream, c2[0], pk2q, DH, DH);
  launch_pack(stream, c2[2], pk2k, DH, DH);
  launch_pack(stream, c2[4], pk2v, DH, DH);
  launch_pack(stream, c2[7], pk2s, DH, DH);
  launch_pack(stream, c2[6], pk2we, DED, DH);
  wqe_k<<<dim3((DH * 32 + 255) / 256), dim3(256), 0, stream>>>(c2[0], c2[6], c2[1], wqe_tmp, bqe2, DH);
  launch_pack(stream, wqe_tmp, pk2qe, DH, DED);
  launch_pack(stream, g1[0], pkg1a, DH, DH);
  launch_pack(stream, g1[4], pkg1b, DH, DH);
  launch_pack(stream, g2[0], pkg2a, DH, DH);
  launch_pack(stream, g2[4], pkg2b, DH, DH);

  // ---- CSR build ----
  const int nb1 = (NN + SCAN_T - 1) / SCAN_T;
  launch_filli(stream, deg, 0, NN);
  launch_filli(stream, cursor, 0, NN);
  count_k<<<dim3((NE + 255) / 256), dim3(256), 0, stream>>>(dst, deg);
  scan1<<<dim3(nb1), dim3(SCAN_T), 0, stream>>>(deg, rowptr, bsum, NN);
  scan2<<<dim3(1), dim3(SCAN_T), 0, stream>>>(bsum, boff, nb1);
  scan3<<<dim3(nb1), dim3(SCAN_T), 0, stream>>>(rowptr, boff, NN);
  scatter_k<<<dim3((NE + 255) / 256), dim3(256), 0, stream>>>(dst, rowptr, cursor, eord);

  // ---- conv layer ----
  auto conv = [&](const bf16_t* Ain, int K,
                  const bf16_t* pq, const bf16_t* pk, const bf16_t* pv, const bf16_t* ps,
                  const bf16_t* pqe, const bf16_t* pwe,
                  const float* const* P, const float* bqe,
                  const float* lng, const float* lnb, bf16_t* outb) {
    gemm_mfma<16><<<dim3(GRID_M), dim3(256), 0, stream>>>(Ain, pq, P[1], nullptr, qb, NN, K, 0);
    gemm_mfma<16><<<dim3(GRID_M), dim3(256), 0, stream>>>(Ain, pk, P[3], nullptr, kb, NN, K, 0);
    gemm_mfma<16><<<dim3(GRID_M), dim3(256), 0, stream>>>(Ain, pv, P[5], nullptr, vb, NN, K, 0);
    gemm_mfma<16><<<dim3(GRID_M), dim3(256), 0, stream>>>(Ain, ps, P[8], nullptr, sb, NN, K, 0);
    gemm_mfma<2><<<dim3(GRID_M), dim3(256), 0, stream>>>(Ain, pqe, bqe, QEf, nullptr, NN, K, 0);
    conv_edge_fused<<<dim3((NN + 3) / 4), dim3(256), 0, stream>>>(
        rowptr, eord, src, qb, kb, vb, eab, QEf, AGG, EAb, denom);
    gemm_mfma<16><<<dim3(GRID_M), dim3(256), 0, stream>>>(EAb, pwe, nullptr, nullptr, E2Nb, NN, DED, 0);
    conv_epilogue<<<dim3(NN), dim3(256), 0, stream>>>(AGG, E2Nb, denom, sb, lng, lnb, outb);
  };

  // ---- GIN layer ----
  auto gin = [&](const bf16_t* hin, const bf16_t* pw1, const bf16_t* pw2,
                 const float* const* P, int relu_out, float* Cf, bf16_t* Cb) {
    gin_gather<<<dim3((NN + 3) / 4), dim3(256), 0, stream>>>(rowptr, eord, src, hin, g_b);
    gemm_mfma<16><<<dim3(GRID_M), dim3(256), 0, stream>>>(g_b, pw1, P[1], AGG, nullptr, NN, DH, 0);
    launch_fillf(stream, bnsum, 0.f, DH);
    launch_fillf(stream, bnsq, 0.f, DH);
    bn_partial<<<dim3(256), dim3(256), 0, stream>>>(AGG, bnsum, bnsq, NN);
    bn_final<<<dim3(1), dim3(256), 0, stream>>>(bnsum, bnsq, P[2], P[3], bnscale, bnshift);
    bn_apply_relu<<<dim3((NN * DH + 255) / 256), dim3(256), 0, stream>>>(
        AGG, bnscale, bnshift, g_b, NN * DH);
    gemm_mfma<16><<<dim3(GRID_M), dim3(256), 0, stream>>>(g_b, pw2, P[5], Cf, Cb, NN, DH, relu_out);
  };

  conv(xb, DIN, pk1q, pk1k, pk1v, pk1s, pk1qe, pk1we, c1, bqe1, ln1g, ln1b, h_b);
  conv(h_b, DH, pk2q, pk2k, pk2v, pk2s, pk2qe, pk2we, c2, bqe2, ln2g, ln2b, h_b);
  gin(h_b, pkg1a, pkg1b, g1, 1, nullptr, h_b);   // gin1: bf16 out + relu
  gin(h_b, pkg2a, pkg2b, g2, 0, Hout, nullptr);  // gin2: fp32 out (qb/kb region now free)

  // ---- pool + head (fp32) ----
  pool_sorted<<<dim3(NG), dim3(256), 0, stream>>>(batch, Hout, pooled);
  gemm_bias_act<<<dim3(4, 8), dim3(256), 0, stream>>>(pooled, linW, linb, zbuf, NG, DH, DH, 1);
  gemm_bias_act<<<dim3(1, 8), dim3(256), 0, stream>>>(zbuf, clfW, clfb, out, NG, DH, DOUT, 0);
}

// Round 4
// 2015.908 us; speedup vs baseline: 4.9776x; 1.1992x over previous
//
#include <hip/hip_runtime.h>
#include <math.h>

#define NN 50000
#define NE 800000
#define DIN 128
#define DH 256
#define DED 32
#define NG 500
#define DOUT 16
#define SCAN_T 256

typedef __bf16 bf16_t;
typedef __bf16 bf16x4 __attribute__((ext_vector_type(4)));
typedef __bf16 bf16x8 __attribute__((ext_vector_type(8)));
typedef float f32x4 __attribute__((ext_vector_type(4)));

// ---------------- utility ----------------
__global__ void fill_i32(int* __restrict__ p, int v, int n) {
  int i = blockIdx.x * 256 + threadIdx.x;
  if (i < n) p[i] = v;
}
__global__ void cast_bf16_k(const float* __restrict__ in, bf16_t* __restrict__ o, long n) {
  long i = (long)blockIdx.x * 256 + threadIdx.x;
  if (i < n) o[i] = (bf16_t)in[i];
}

// ---------------- CSR build (by dst) ----------------
__global__ void count_k(const int* __restrict__ dst, int* __restrict__ deg) {
  int e = blockIdx.x * 256 + threadIdx.x;
  if (e < NE) atomicAdd(&deg[dst[e]], 1);
}
__global__ void scan1(const int* __restrict__ deg, int* __restrict__ rowptr,
                      int* __restrict__ bsum, int n) {
  __shared__ int s[SCAN_T];
  int t = threadIdx.x, i = blockIdx.x * SCAN_T + t;
  int v = (i < n) ? deg[i] : 0;
  s[t] = v; __syncthreads();
  for (int off = 1; off < SCAN_T; off <<= 1) {
    int add = (t >= off) ? s[t - off] : 0;
    __syncthreads(); s[t] += add; __syncthreads();
  }
  if (i < n) rowptr[i + 1] = s[t];
  if (t == SCAN_T - 1) bsum[blockIdx.x] = s[t];
}
__global__ void scan2(const int* __restrict__ bsum, int* __restrict__ boff, int nb) {
  __shared__ int s[SCAN_T];
  int t = threadIdx.x;
  int v = (t < nb) ? bsum[t] : 0;
  s[t] = v; __syncthreads();
  for (int off = 1; off < SCAN_T; off <<= 1) {
    int add = (t >= off) ? s[t - off] : 0;
    __syncthreads(); s[t] += add; __syncthreads();
  }
  boff[t] = s[t] - v;
}
__global__ void scan3(int* __restrict__ rowptr, const int* __restrict__ boff, int n) {
  int i = blockIdx.x * 256 + threadIdx.x;
  if (i < n) rowptr[i + 1] += boff[i >> 8];
  if (i == 0) rowptr[0] = 0;
}
// stores src and edge-id in CSR order: kills the dependent src[eord[i]] lookup
__global__ void scatter_k(const int* __restrict__ dst, const int* __restrict__ src,
                          const int* __restrict__ rowptr, int* __restrict__ cursor,
                          int* __restrict__ esrc, int* __restrict__ eidx) {
  int e = blockIdx.x * 256 + threadIdx.x;
  if (e < NE) {
    int d = dst[e];
    int pos = rowptr[d] + atomicAdd(&cursor[d], 1);
    esrc[pos] = src[e];
    eidx[pos] = e;
  }
}

// ---------------- weight fragment packing (all weights, one dispatch) ----------------
struct PackEnt { const float* src; bf16_t* dst; int K; int N; };
struct PackArgs { PackEnt e[16]; };
__global__ void pack_all(PackArgs pa) {
  PackEnt en = pa.e[blockIdx.y];
  int i = blockIdx.x * 256 + threadIdx.x;
  if (i >= en.K * en.N) return;
  int el = i & 511, f = i >> 9;
  int ntiles = en.N >> 4;
  int ks = f / ntiles, t = f - ks * ntiles;
  int lane = el >> 3, j = el & 7;
  int k = ks * 32 + (lane >> 4) * 8 + j;
  int n = t * 16 + (lane & 15);
  en.dst[i] = (bf16_t)en.src[(size_t)k * en.N + n];
}

// Wqe[d][j] = sum_h Wq[d][h]*We[j][h]; bqe[j] = sum_h bq[h]*We[j][h]
__global__ void wqe_k(const float* __restrict__ Wq, const float* __restrict__ We,
                      const float* __restrict__ bq, float* __restrict__ Wqe,
                      float* __restrict__ bqe, int din) {
  int idx = blockIdx.x * 256 + threadIdx.x;
  if (idx < din * 32) {
    int d = idx >> 5, j = idx & 31;
    float s = 0.f;
    for (int h = 0; h < DH; ++h) s += Wq[(size_t)d * DH + h] * We[(size_t)j * DH + h];
    Wqe[idx] = s;
  }
  if (idx < 32) {
    float s = 0.f;
    for (int h = 0; h < DH; ++h) s += bq[h] * We[(size_t)idx * DH + h];
    bqe[idx] = s;
  }
}

// ---------------- MFMA GEMM body ----------------
template<int NT>
__device__ __forceinline__ void gemm_body(
    const bf16_t* __restrict__ Ab, const bf16_t* __restrict__ Wp,
    const float* __restrict__ bias, float* __restrict__ Cf, bf16_t* __restrict__ Cb,
    int M, int K, int relu, int bx)
{
  const int Ncols = NT * 16;
  int lane = threadIdx.x & 63, wv = threadIdx.x >> 6;
  int base = bx * 128 + wv * 32;
  int rA0 = base + (lane & 15);
  int rA1 = rA0 + 16;
  int kq = (lane >> 4) * 8;
  f32x4 acc[2][NT];
#pragma unroll
  for (int rt = 0; rt < 2; ++rt)
#pragma unroll
    for (int t = 0; t < NT; ++t) acc[rt][t] = (f32x4){0.f, 0.f, 0.f, 0.f};
  bf16x8 az;
#pragma unroll
  for (int j = 0; j < 8; ++j) az[j] = (bf16_t)0.f;
  int nk = K >> 5;
  for (int ks = 0; ks < nk; ++ks) {
    bf16x8 a0 = (rA0 < M) ? *(const bf16x8*)&Ab[(size_t)rA0 * K + ks * 32 + kq] : az;
    bf16x8 a1 = (rA1 < M) ? *(const bf16x8*)&Ab[(size_t)rA1 * K + ks * 32 + kq] : az;
    const bf16_t* wb = Wp + ((size_t)ks * NT) * 512 + lane * 8;
#pragma unroll
    for (int t = 0; t < NT; ++t) {
      bf16x8 b = *(const bf16x8*)(wb + t * 512);
      acc[0][t] = __builtin_amdgcn_mfma_f32_16x16x32_bf16(a0, b, acc[0][t], 0, 0, 0);
      acc[1][t] = __builtin_amdgcn_mfma_f32_16x16x32_bf16(a1, b, acc[1][t], 0, 0, 0);
    }
  }
  int col_l = lane & 15;
#pragma unroll
  for (int rt = 0; rt < 2; ++rt) {
    int rbase = base + rt * 16 + (lane >> 4) * 4;
#pragma unroll
    for (int t = 0; t < NT; ++t) {
      int col = t * 16 + col_l;
      float bv = bias ? bias[col] : 0.f;
#pragma unroll
      for (int r = 0; r < 4; ++r) {
        int row = rbase + r;
        if (row >= M) continue;
        float vv = acc[rt][t][r] + bv;
        if (relu) vv = fmaxf(vv, 0.f);
        if (Cf) Cf[(size_t)row * Ncols + col] = vv;
        if (Cb) Cb[(size_t)row * Ncols + col] = (bf16_t)vv;
      }
    }
  }
}

template<int NT>
__global__ __launch_bounds__(256) void gemm_mfma(
    const bf16_t* __restrict__ Ab, const bf16_t* __restrict__ Wp,
    const float* __restrict__ bias, float* __restrict__ Cf, bf16_t* __restrict__ Cb,
    int M, int K, int relu)
{
  gemm_body<NT>(Ab, Wp, bias, Cf, Cb, M, K, relu, blockIdx.x);
}

// 4 GEMMs sharing A (q,k,v,s) in one dispatch: grid.y selects the weight set
struct QkvsArgs { const bf16_t* w[4]; const float* bias[4]; bf16_t* outp[4]; };
__global__ __launch_bounds__(256) void gemm_qkvs(
    const bf16_t* __restrict__ Ab, QkvsArgs qa, int M, int K)
{
  int which = blockIdx.y;
  gemm_body<16>(Ab, qa.w[which], qa.bias[which], nullptr, qa.outp[which], M, K, 0, blockIdx.x);
}

// ---------------- fused edge softmax-aggregate: half-wave per node, pipelined ----------------
__global__ __launch_bounds__(256) void conv_edge_fused(
    const int* __restrict__ rowptr, const int* __restrict__ esrc, const int* __restrict__ eidx,
    const bf16_t* __restrict__ qb, const bf16_t* __restrict__ kb, const bf16_t* __restrict__ vb,
    const bf16_t* __restrict__ eab, const float* __restrict__ QEf,
    bf16_t* __restrict__ AGGn, bf16_t* __restrict__ EAn)
{
  int half = threadIdx.x >> 5, l = threadIdx.x & 31;
  int n = blockIdx.x * 8 + half;
  if (n >= NN) return;
  size_t co = (size_t)n * DH + l * 8;
  float q[8];
  {
    bf16x8 t = *(const bf16x8*)&qb[co];
#pragma unroll
    for (int j = 0; j < 8; ++j) q[j] = (float)t[j];
  }
  float qe[8];
#pragma unroll
  for (int j = 0; j < 8; ++j) qe[j] = 0.f;
  if (l < 4) {
    const float* p = &QEf[(size_t)n * DED + l * 8];
#pragma unroll
    for (int j = 0; j < 8; ++j) qe[j] = p[j];
  }
  float m = -__builtin_huge_valf(), s = 0.f;
  float acc[8], eacc[8];
#pragma unroll
  for (int j = 0; j < 8; ++j) { acc[j] = 0.f; eacc[j] = 0.f; }
  int i0 = rowptr[n], i1 = rowptr[n + 1];
  int i = i0;
  bf16x8 kt, vt; float eav[8];
#pragma unroll
  for (int j = 0; j < 8; ++j) eav[j] = 0.f;
  if (i < i1) {
    int sN = esrc[i];
    kt = *(const bf16x8*)&kb[(size_t)sN * DH + l * 8];
    vt = *(const bf16x8*)&vb[(size_t)sN * DH + l * 8];
    if (l < 4) {
      int e = eidx[i];
      bf16x8 t = *(const bf16x8*)&eab[(size_t)e * DED + l * 8];
#pragma unroll
      for (int j = 0; j < 8; ++j) eav[j] = (float)t[j];
    }
  }
  while (i < i1) {
    bf16x8 kt2, vt2; float eav2[8];
#pragma unroll
    for (int j = 0; j < 8; ++j) eav2[j] = 0.f;
    if (i + 1 < i1) {                       // prefetch next edge before reducing current
      int sN = esrc[i + 1];
      kt2 = *(const bf16x8*)&kb[(size_t)sN * DH + l * 8];
      vt2 = *(const bf16x8*)&vb[(size_t)sN * DH + l * 8];
      if (l < 4) {
        int e = eidx[i + 1];
        bf16x8 t = *(const bf16x8*)&eab[(size_t)e * DED + l * 8];
#pragma unroll
        for (int j = 0; j < 8; ++j) eav2[j] = (float)t[j];
      }
    } else {
      kt2 = kt; vt2 = vt;
    }
    float partial = 0.f;
#pragma unroll
    for (int j = 0; j < 8; ++j) partial = fmaf(q[j], (float)kt[j], partial);
#pragma unroll
    for (int j = 0; j < 8; ++j) partial = fmaf(qe[j], eav[j], partial);  // 0 for l>=4
#pragma unroll
    for (int off = 16; off > 0; off >>= 1) partial += __shfl_xor(partial, off, 64);
    float sc = partial * 0.0625f;  // 1/sqrt(256)
    float nm = fmaxf(m, sc);
    float sca = __expf(m - nm);    // first iter: exp(-inf)=0
    float ex = __expf(sc - nm);
    s = s * sca + ex;
#pragma unroll
    for (int j = 0; j < 8; ++j) acc[j] = acc[j] * sca + ex * (float)vt[j];
#pragma unroll
    for (int j = 0; j < 8; ++j) eacc[j] = eacc[j] * sca + ex * eav[j];
    m = nm;
    kt = kt2; vt = vt2;
#pragma unroll
    for (int j = 0; j < 8; ++j) eav[j] = eav2[j];
    ++i;
  }
  float inv = 1.f / (s + 1e-16f);
  bf16x8 o;
#pragma unroll
  for (int j = 0; j < 8; ++j) o[j] = (bf16_t)(acc[j] * inv);
  *(bf16x8*)&AGGn[co] = o;
  if (l < 4) {
    bf16x8 eo;
#pragma unroll
    for (int j = 0; j < 8; ++j) eo[j] = (bf16_t)(eacc[j] * inv);
    *(bf16x8*)&EAn[(size_t)n * DED + l * 8] = eo;
  }
}

// out = LN( leaky_relu( AGGn + E2N + S ) ) * g + b  — one wave per node, shfl reductions
__global__ __launch_bounds__(256) void conv_epilogue(
    const bf16_t* __restrict__ AGGn, const bf16_t* __restrict__ E2N,
    const bf16_t* __restrict__ S, const float* __restrict__ g,
    const float* __restrict__ b, bf16_t* __restrict__ out)
{
  int wv = threadIdx.x >> 6, lane = threadIdx.x & 63;
  int n = blockIdx.x * 4 + wv;
  if (n >= NN) return;
  size_t base = (size_t)n * DH + lane * 4;
  bf16x4 a = *(const bf16x4*)&AGGn[base];
  bf16x4 e2 = *(const bf16x4*)&E2N[base];
  bf16x4 sv = *(const bf16x4*)&S[base];
  float v[4];
#pragma unroll
  for (int j = 0; j < 4; ++j) {
    float t = (float)a[j] + (float)e2[j] + (float)sv[j];
    v[j] = (t > 0.f) ? t : 0.01f * t;
  }
  float sum = v[0] + v[1] + v[2] + v[3];
  float sq = v[0]*v[0] + v[1]*v[1] + v[2]*v[2] + v[3]*v[3];
#pragma unroll
  for (int off = 32; off > 0; off >>= 1) {
    sum += __shfl_xor(sum, off, 64);
    sq  += __shfl_xor(sq, off, 64);
  }
  float mu = sum * (1.f / DH);
  float var = sq * (1.f / DH) - mu * mu;
  float rstd = rsqrtf(var + 1e-5f);
  bf16x4 o;
#pragma unroll
  for (int j = 0; j < 4; ++j)
    o[j] = (bf16_t)((v[j] - mu) * rstd * g[lane * 4 + j] + b[lane * 4 + j]);
  *(bf16x4*)&out[base] = o;
}

// ---------------- GIN gather: half-wave per node, pipelined ----------------
__global__ __launch_bounds__(256) void gin_gather(
    const int* __restrict__ rowptr, const int* __restrict__ esrc,
    const bf16_t* __restrict__ h, bf16_t* __restrict__ out)
{
  int half = threadIdx.x >> 5, l = threadIdx.x & 31;
  int n = blockIdx.x * 8 + half;
  if (n >= NN) return;
  size_t co = (size_t)n * DH + l * 8;
  float acc[8];
  {
    bf16x8 hv = *(const bf16x8*)&h[co];
#pragma unroll
    for (int j = 0; j < 8; ++j) acc[j] = (float)hv[j];  // self (eps=0)
  }
  int i0 = rowptr[n], i1 = rowptr[n + 1];
  int i = i0;
  bf16x8 cur;
  if (i < i1) cur = *(const bf16x8*)&h[(size_t)esrc[i] * DH + l * 8];
  while (i < i1) {
    bf16x8 nxt = cur;
    if (i + 1 < i1) nxt = *(const bf16x8*)&h[(size_t)esrc[i + 1] * DH + l * 8];
#pragma unroll
    for (int j = 0; j < 8; ++j) acc[j] += (float)cur[j];
    cur = nxt;
    ++i;
  }
  bf16x8 o;
#pragma unroll
  for (int j = 0; j < 8; ++j) o[j] = (bf16_t)acc[j];
  *(bf16x8*)&out[co] = o;
}

// ---------------- BN (no atomics, no fills) ----------------
__global__ __launch_bounds__(256) void bn_partial_na(
    const float* __restrict__ y, float* __restrict__ psum, float* __restrict__ psq)
{
  int c = threadIdx.x, b = blockIdx.x;
  float s = 0.f, ss = 0.f;
  for (int r = b; r < NN; r += 256) {
    float v = y[(size_t)r * DH + c];
    s += v; ss += v * v;
  }
  psum[b * DH + c] = s; psq[b * DH + c] = ss;
}
__global__ void bn_final_na(const float* __restrict__ psum, const float* __restrict__ psq,
                            const float* __restrict__ bng, const float* __restrict__ bnb,
                            float* __restrict__ scale, float* __restrict__ shift) {
  int c = threadIdx.x;
  float s = 0.f, ss = 0.f;
  for (int b = 0; b < 256; ++b) { s += psum[b * DH + c]; ss += psq[b * DH + c]; }
  float mu = s * (1.f / NN);
  float var = ss * (1.f / NN) - mu * mu;
  float rstd = rsqrtf(var + 1e-5f);
  float sc = bng[c] * rstd;
  scale[c] = sc;
  shift[c] = bnb[c] - mu * sc;
}
__global__ void bn_apply_relu(const float* __restrict__ y, const float* __restrict__ scale,
                              const float* __restrict__ shift, bf16_t* __restrict__ o, int n) {
  int i = blockIdx.x * 256 + threadIdx.x;
  if (i < n) {
    int c = i & (DH - 1);
    o[i] = (bf16_t)fmaxf(y[i] * scale[c] + shift[c], 0.f);
  }
}

// ---------------- pooling over sorted batch ----------------
__global__ __launch_bounds__(256) void pool_sorted(
    const int* __restrict__ batch, const float* __restrict__ h, float* __restrict__ pooled)
{
  __shared__ int s0, s1;
  int g = blockIdx.x;
  if (threadIdx.x == 0) {
    int lo = 0, hi = NN;
    while (lo < hi) { int mid = (lo + hi) >> 1; if (batch[mid] < g) lo = mid + 1; else hi = mid; }
    s0 = lo;
  }
  if (threadIdx.x == 1) {
    int lo = 0, hi = NN;
    while (lo < hi) { int mid = (lo + hi) >> 1; if (batch[mid] < g + 1) lo = mid + 1; else hi = mid; }
    s1 = lo;
  }
  __syncthreads();
  int c = threadIdx.x;
  float acc = 0.f;
  for (int r = s0; r < s1; ++r) acc += h[(size_t)r * DH + c];
  pooled[(size_t)g * DH + c] = acc;
}

// ---------------- small fp32 GEMM (head only) ----------------
__global__ __launch_bounds__(256) void gemm_bias_act(
    const float* __restrict__ A, const float* __restrict__ Wm,
    const float* __restrict__ bias, float* __restrict__ C,
    int M, int K, int Ncol, int act)
{
  __shared__ __align__(16) float As[16][68];
  __shared__ __align__(16) float Bs[16][68];
  int tid = threadIdx.x;
  int tx = tid & 15, ty = tid >> 4;
  int row0 = blockIdx.y * 64 + ty * 4;
  int col0 = blockIdx.x * 64 + tx * 4;
  float acc[4][4] = {{0.f}};
  for (int k0 = 0; k0 < K; k0 += 16) {
#pragma unroll
    for (int l = 0; l < 4; ++l) {
      int e = tid + l * 256;
      int r = e >> 4, kk = e & 15;
      int gr = blockIdx.y * 64 + r;
      As[kk][r] = (gr < M) ? A[(size_t)gr * K + k0 + kk] : 0.f;
    }
#pragma unroll
    for (int l = 0; l < 4; ++l) {
      int e = tid + l * 256;
      int kk = e >> 6, c = e & 63;
      int gc = blockIdx.x * 64 + c;
      Bs[kk][c] = (gc < Ncol) ? Wm[(size_t)(k0 + kk) * Ncol + gc] : 0.f;
    }
    __syncthreads();
#pragma unroll
    for (int kk = 0; kk < 16; ++kk) {
      float4 a4 = *(const float4*)&As[kk][ty * 4];
      float4 b4 = *(const float4*)&Bs[kk][tx * 4];
      float a[4] = {a4.x, a4.y, a4.z, a4.w};
      float b[4] = {b4.x, b4.y, b4.z, b4.w};
#pragma unroll
      for (int i = 0; i < 4; ++i)
#pragma unroll
        for (int j = 0; j < 4; ++j)
          acc[i][j] = fmaf(a[i], b[j], acc[i][j]);
    }
    __syncthreads();
  }
#pragma unroll
  for (int i = 0; i < 4; ++i) {
    int r = row0 + i;
    if (r >= M) continue;
#pragma unroll
    for (int j = 0; j < 4; ++j) {
      int c = col0 + j;
      if (c >= Ncol) continue;
      float val = acc[i][j];
      if (bias) val += bias[c];
      if (act == 1) val = fmaxf(val, 0.f);
      C[(size_t)r * Ncol + c] = val;
    }
  }
}

// ---------------- host ----------------
static inline void launch_filli(hipStream_t st, int* p, int v, long n) {
  fill_i32<<<dim3((unsigned)((n + 255) / 256)), dim3(256), 0, st>>>(p, v, (int)n);
}
static inline void launch_cast(hipStream_t st, const float* in, bf16_t* o, long n) {
  cast_bf16_k<<<dim3((unsigned)((n + 255) / 256)), dim3(256), 0, st>>>(in, o, n);
}

extern "C" void kernel_launch(void* const* d_in, const int* in_sizes, int n_in,
                              void* d_out, int out_size, void* d_ws, size_t ws_size,
                              hipStream_t stream) {
  const float* x  = (const float*)d_in[0];
  const int* ei   = (const int*)d_in[1];
  const float* ea = (const float*)d_in[2];
  const int* batch = (const int*)d_in[3];
  const int* src = ei;
  const int* dst = ei + NE;

  const float* c1[9]; for (int i = 0; i < 9; ++i) c1[i] = (const float*)d_in[4 + i];
  const float* ln1g = (const float*)d_in[13]; const float* ln1b = (const float*)d_in[14];
  const float* c2[9]; for (int i = 0; i < 9; ++i) c2[i] = (const float*)d_in[15 + i];
  const float* ln2g = (const float*)d_in[24]; const float* ln2b = (const float*)d_in[25];
  const float* g1[6]; for (int i = 0; i < 6; ++i) g1[i] = (const float*)d_in[26 + i];
  const float* g2[6]; for (int i = 0; i < 6; ++i) g2[i] = (const float*)d_in[32 + i];
  const float* linW = (const float*)d_in[38]; const float* linb = (const float*)d_in[39];
  const float* clfW = (const float*)d_in[40]; const float* clfb = (const float*)d_in[41];
  float* out = (float*)d_out;

  // ---- bump allocator over d_ws (256B aligned) ----
  size_t off = 0;
  auto alloc = [&](size_t bytes) -> void* {
    void* r = (char*)d_ws + off;
    off += (bytes + 255) & ~(size_t)255;
    return r;
  };
  // ints
  int* deg    = (int*)alloc(NN * 4);
  int* cursor = (int*)alloc(NN * 4);
  int* rowptr = (int*)alloc((NN + 1) * 4);
  int* esrc   = (int*)alloc((size_t)NE * 4);
  int* eidx   = (int*)alloc((size_t)NE * 4);
  int* bsum   = (int*)alloc(1024);
  int* boff   = (int*)alloc(1024);
  // fp32
  float* QEf   = (float*)alloc((size_t)NN * DED * 4);
  float* Yf    = (float*)alloc((size_t)NN * DH * 4);   // GIN pre-BN activations
  float* pooled = (float*)alloc((size_t)NG * DH * 4);
  float* zbuf   = (float*)alloc((size_t)NG * DH * 4);
  float* psum  = (float*)alloc(256 * DH * 4);
  float* psq   = (float*)alloc(256 * DH * 4);
  float* bnscale = (float*)alloc(DH * 4);
  float* bnshift = (float*)alloc(DH * 4);
  float* wqe_tmp1 = (float*)alloc((size_t)DIN * DED * 4);
  float* wqe_tmp2 = (float*)alloc((size_t)DH * DED * 4);
  float* bqe1 = (float*)alloc(DED * 4);
  float* bqe2 = (float*)alloc(DED * 4);
  // bf16 activations (qb and kb MUST be adjacent: Hout aliases them)
  bf16_t* qb = (bf16_t*)alloc((size_t)NN * DH * 2);
  bf16_t* kb = (bf16_t*)alloc((size_t)NN * DH * 2);
  bf16_t* vb = (bf16_t*)alloc((size_t)NN * DH * 2);
  bf16_t* sb = (bf16_t*)alloc((size_t)NN * DH * 2);
  bf16_t* h_b = (bf16_t*)alloc((size_t)NN * DH * 2);
  bf16_t* g_b = (bf16_t*)alloc((size_t)NN * DH * 2);
  bf16_t* E2Nb = (bf16_t*)alloc((size_t)NN * DH * 2);
  bf16_t* AGGb = (bf16_t*)alloc((size_t)NN * DH * 2);
  bf16_t* EAn = (bf16_t*)alloc((size_t)NN * DED * 2);
  bf16_t* xb  = (bf16_t*)alloc((size_t)NN * DIN * 2);
  bf16_t* eab = (bf16_t*)alloc((size_t)NE * DED * 2);
  float* Hout = (float*)qb;  // qb+kb region (fp32 [N,DH]) free during GIN phase
  // packed weights
  bf16_t* pk1q = (bf16_t*)alloc(DIN * DH * 2);
  bf16_t* pk1k = (bf16_t*)alloc(DIN * DH * 2);
  bf16_t* pk1v = (bf16_t*)alloc(DIN * DH * 2);
  bf16_t* pk1s = (bf16_t*)alloc(DIN * DH * 2);
  bf16_t* pk1qe = (bf16_t*)alloc(DIN * DED * 2);
  bf16_t* pk1we = (bf16_t*)alloc(DED * DH * 2);
  bf16_t* pk2q = (bf16_t*)alloc(DH * DH * 2);
  bf16_t* pk2k = (bf16_t*)alloc(DH * DH * 2);
  bf16_t* pk2v = (bf16_t*)alloc(DH * DH * 2);
  bf16_t* pk2s = (bf16_t*)alloc(DH * DH * 2);
  bf16_t* pk2qe = (bf16_t*)alloc(DH * DED * 2);
  bf16_t* pk2we = (bf16_t*)alloc(DED * DH * 2);
  bf16_t* pkg1a = (bf16_t*)alloc(DH * DH * 2);
  bf16_t* pkg1b = (bf16_t*)alloc(DH * DH * 2);
  bf16_t* pkg2a = (bf16_t*)alloc(DH * DH * 2);
  bf16_t* pkg2b = (bf16_t*)alloc(DH * DH * 2);
  if (ws_size < off) return;

  const int GRID_M = (NN + 127) / 128;

  // ---- casts, Wqe folds, one packed-weights dispatch ----
  launch_cast(stream, x, xb, (long)NN * DIN);
  launch_cast(stream, ea, eab, (long)NE * DED);
  wqe_k<<<dim3((DIN * 32 + 255) / 256), dim3(256), 0, stream>>>(c1[0], c1[6], c1[1], wqe_tmp1, bqe1, DIN);
  wqe_k<<<dim3((DH * 32 + 255) / 256), dim3(256), 0, stream>>>(c2[0], c2[6], c2[1], wqe_tmp2, bqe2, DH);
  PackArgs pa;
  pa.e[0]  = {c1[0], pk1q, DIN, DH};
  pa.e[1]  = {c1[2], pk1k, DIN, DH};
  pa.e[2]  = {c1[4], pk1v, DIN, DH};
  pa.e[3]  = {c1[7], pk1s, DIN, DH};
  pa.e[4]  = {c1[6], pk1we, DED, DH};
  pa.e[5]  = {wqe_tmp1, pk1qe, DIN, DED};
  pa.e[6]  = {c2[0], pk2q, DH, DH};
  pa.e[7]  = {c2[2], pk2k, DH, DH};
  pa.e[8]  = {c2[4], pk2v, DH, DH};
  pa.e[9]  = {c2[7], pk2s, DH, DH};
  pa.e[10] = {c2[6], pk2we, DED, DH};
  pa.e[11] = {wqe_tmp2, pk2qe, DH, DED};
  pa.e[12] = {g1[0], pkg1a, DH, DH};
  pa.e[13] = {g1[4], pkg1b, DH, DH};
  pa.e[14] = {g2[0], pkg2a, DH, DH};
  pa.e[15] = {g2[4], pkg2b, DH, DH};
  pack_all<<<dim3(256, 16), dim3(256), 0, stream>>>(pa);

  // ---- CSR build ----
  const int nb1 = (NN + SCAN_T - 1) / SCAN_T;
  launch_filli(stream, deg, 0, NN);
  launch_filli(stream, cursor, 0, NN);
  count_k<<<dim3((NE + 255) / 256), dim3(256), 0, stream>>>(dst, deg);
  scan1<<<dim3(nb1), dim3(SCAN_T), 0, stream>>>(deg, rowptr, bsum, NN);
  scan2<<<dim3(1), dim3(SCAN_T), 0, stream>>>(bsum, boff, nb1);
  scan3<<<dim3(nb1), dim3(SCAN_T), 0, stream>>>(rowptr, boff, NN);
  scatter_k<<<dim3((NE + 255) / 256), dim3(256), 0, stream>>>(dst, src, rowptr, cursor, esrc, eidx);

  // ---- conv layer ----
  auto conv = [&](const bf16_t* Ain, int K,
                  const bf16_t* pq, const bf16_t* pk, const bf16_t* pv, const bf16_t* ps,
                  const bf16_t* pqe, const bf16_t* pwe,
                  const float* const* P, const float* bqe,
                  const float* lng, const float* lnb, bf16_t* outb) {
    QkvsArgs qa;
    qa.w[0] = pq; qa.w[1] = pk; qa.w[2] = pv; qa.w[3] = ps;
    qa.bias[0] = P[1]; qa.bias[1] = P[3]; qa.bias[2] = P[5]; qa.bias[3] = P[8];
    qa.outp[0] = qb; qa.outp[1] = kb; qa.outp[2] = vb; qa.outp[3] = sb;
    gemm_qkvs<<<dim3(GRID_M, 4), dim3(256), 0, stream>>>(Ain, qa, NN, K);
    gemm_mfma<2><<<dim3(GRID_M), dim3(256), 0, stream>>>(Ain, pqe, bqe, QEf, nullptr, NN, K, 0);
    conv_edge_fused<<<dim3((NN + 7) / 8), dim3(256), 0, stream>>>(
        rowptr, esrc, eidx, qb, kb, vb, eab, QEf, AGGb, EAn);
    gemm_mfma<16><<<dim3(GRID_M), dim3(256), 0, stream>>>(EAn, pwe, nullptr, nullptr, E2Nb, NN, DED, 0);
    conv_epilogue<<<dim3((NN + 3) / 4), dim3(256), 0, stream>>>(AGGb, E2Nb, sb, lng, lnb, outb);
  };

  // ---- GIN layer ----
  auto gin = [&](const bf16_t* hin, const bf16_t* pw1, const bf16_t* pw2,
                 const float* const* P, int relu_out, float* Cf, bf16_t* Cb) {
    gin_gather<<<dim3((NN + 7) / 8), dim3(256), 0, stream>>>(rowptr, esrc, hin, g_b);
    gemm_mfma<16><<<dim3(GRID_M), dim3(256), 0, stream>>>(g_b, pw1, P[1], Yf, nullptr, NN, DH, 0);
    bn_partial_na<<<dim3(256), dim3(256), 0, stream>>>(Yf, psum, psq);
    bn_final_na<<<dim3(1), dim3(256), 0, stream>>>(psum, psq, P[2], P[3], bnscale, bnshift);
    bn_apply_relu<<<dim3((NN * DH + 255) / 256), dim3(256), 0, stream>>>(
        Yf, bnscale, bnshift, g_b, NN * DH);
    gemm_mfma<16><<<dim3(GRID_M), dim3(256), 0, stream>>>(g_b, pw2, P[5], Cf, Cb, NN, DH, relu_out);
  };

  conv(xb, DIN, pk1q, pk1k, pk1v, pk1s, pk1qe, pk1we, c1, bqe1, ln1g, ln1b, h_b);
  conv(h_b, DH, pk2q, pk2k, pk2v, pk2s, pk2qe, pk2we, c2, bqe2, ln2g, ln2b, h_b);
  gin(h_b, pkg1a, pkg1b, g1, 1, nullptr, h_b);   // gin1: bf16 out + relu
  gin(h_b, pkg2a, pkg2b, g2, 0, Hout, nullptr);  // gin2: fp32 out into qb/kb region

  // ---- pool + head (fp32) ----
  pool_sorted<<<dim3(NG), dim3(256), 0, stream>>>(batch, Hout, pooled);
  gemm_bias_act<<<dim3(4, 8), dim3(256), 0, stream>>>(pooled, linW, linb, zbuf, NG, DH, DH, 1);
  gemm_bias_act<<<dim3(1, 8), dim3(256), 0, stream>>>(zbuf, clfW, clfb, out, NG, DH, DOUT, 0);
}

// Round 5
// 1693.222 us; speedup vs baseline: 5.9262x; 1.1906x over previous
//
#include <hip/hip_runtime.h>
#include <math.h>

#define NN 50000
#define NE 800000
#define DIN 128
#define DH 256
#define DED 32
#define NG 500
#define DOUT 16
#define SCAN_T 256

typedef __bf16 bf16_t;
typedef __bf16 bf16x4 __attribute__((ext_vector_type(4)));
typedef __bf16 bf16x8 __attribute__((ext_vector_type(8)));
typedef float f32x4 __attribute__((ext_vector_type(4)));

// async global->LDS, 16B per lane (global_load_lds_dwordx4)
__device__ __forceinline__ void async_copy16(const bf16_t* g, bf16_t* l) {
  __builtin_amdgcn_global_load_lds(
      (const __attribute__((address_space(1))) void*)g,
      (__attribute__((address_space(3))) void*)l, 16, 0, 0);
}

// ---------------- utility ----------------
__global__ void fill_i32(int* __restrict__ p, int v, int n) {
  int i = blockIdx.x * 256 + threadIdx.x;
  if (i < n) p[i] = v;
}
__global__ void cast_bf16_k(const float* __restrict__ in, bf16_t* __restrict__ o, long n) {
  long i = (long)blockIdx.x * 256 + threadIdx.x;
  if (i < n) o[i] = (bf16_t)in[i];
}

// ---------------- CSR build (by dst) ----------------
__global__ void count_k(const int* __restrict__ dst, int* __restrict__ deg) {
  int e = blockIdx.x * 256 + threadIdx.x;
  if (e < NE) atomicAdd(&deg[dst[e]], 1);
}
__global__ void scan1(const int* __restrict__ deg, int* __restrict__ rowptr,
                      int* __restrict__ bsum, int n) {
  __shared__ int s[SCAN_T];
  int t = threadIdx.x, i = blockIdx.x * SCAN_T + t;
  int v = (i < n) ? deg[i] : 0;
  s[t] = v; __syncthreads();
  for (int off = 1; off < SCAN_T; off <<= 1) {
    int add = (t >= off) ? s[t - off] : 0;
    __syncthreads(); s[t] += add; __syncthreads();
  }
  if (i < n) rowptr[i + 1] = s[t];
  if (t == SCAN_T - 1) bsum[blockIdx.x] = s[t];
}
__global__ void scan2(const int* __restrict__ bsum, int* __restrict__ boff, int nb) {
  __shared__ int s[SCAN_T];
  int t = threadIdx.x;
  int v = (t < nb) ? bsum[t] : 0;
  s[t] = v; __syncthreads();
  for (int off = 1; off < SCAN_T; off <<= 1) {
    int add = (t >= off) ? s[t - off] : 0;
    __syncthreads(); s[t] += add; __syncthreads();
  }
  boff[t] = s[t] - v;
}
__global__ void scan3(int* __restrict__ rowptr, const int* __restrict__ boff, int n) {
  int i = blockIdx.x * 256 + threadIdx.x;
  if (i < n) rowptr[i + 1] += boff[i >> 8];
  if (i == 0) rowptr[0] = 0;
}
__global__ void scatter_k(const int* __restrict__ dst, const int* __restrict__ src,
                          const int* __restrict__ rowptr, int* __restrict__ cursor,
                          int* __restrict__ esrc, int* __restrict__ eidx) {
  int e = blockIdx.x * 256 + threadIdx.x;
  if (e < NE) {
    int d = dst[e];
    int pos = rowptr[d] + atomicAdd(&cursor[d], 1);
    esrc[pos] = src[e];
    eidx[pos] = e;
  }
}

// ---------------- weight fragment packing (all weights, one dispatch) ----------------
struct PackEnt { const float* src; bf16_t* dst; int K; int N; };
struct PackArgs { PackEnt e[16]; };
__global__ void pack_all(PackArgs pa) {
  PackEnt en = pa.e[blockIdx.y];
  int i = blockIdx.x * 256 + threadIdx.x;
  if (i >= en.K * en.N) return;
  int el = i & 511, f = i >> 9;
  int ntiles = en.N >> 4;
  int ks = f / ntiles, t = f - ks * ntiles;
  int lane = el >> 3, j = el & 7;
  int k = ks * 32 + (lane >> 4) * 8 + j;
  int n = t * 16 + (lane & 15);
  en.dst[i] = (bf16_t)en.src[(size_t)k * en.N + n];
}

// Wqe[d][j] = sum_h Wq[d][h]*We[j][h]; bqe[j] = sum_h bq[h]*We[j][h]
__global__ void wqe_k(const float* __restrict__ Wq, const float* __restrict__ We,
                      const float* __restrict__ bq, float* __restrict__ Wqe,
                      float* __restrict__ bqe, int din) {
  int idx = blockIdx.x * 256 + threadIdx.x;
  if (idx < din * 32) {
    int d = idx >> 5, j = idx & 31;
    float s = 0.f;
    for (int h = 0; h < DH; ++h) s += Wq[(size_t)d * DH + h] * We[(size_t)j * DH + h];
    Wqe[idx] = s;
  }
  if (idx < 32) {
    float s = 0.f;
    for (int h = 0; h < DH; ++h) s += bq[h] * We[(size_t)idx * DH + h];
    bqe[idx] = s;
  }
}

// ---------------- MFMA GEMM body, LDS-staged A (m97 structure) ----------------
// block = 256 thr = 4 waves; tile = 128 rows x (NT*16) cols; BK=32.
// A-tile staged to LDS via async global_load_lds (16B/lane), row-major [128][32].
// B pre-packed fragments from global (identical addrs across waves -> L1-hot).
template<int NT>
__device__ __forceinline__ void gemm_body(
    const bf16_t* __restrict__ Ab, const bf16_t* __restrict__ Wp,
    const float* __restrict__ bias, float* __restrict__ Cf, bf16_t* __restrict__ Cb,
    int M, int K, int relu, int bx)
{
  __shared__ bf16_t Atile[128 * 32];   // 8 KB
  const int Ncols = NT * 16;
  int tid = threadIdx.x;
  int lane = tid & 63, wv = tid >> 6;
  int base = bx * 128;

  f32x4 acc[2][NT];
#pragma unroll
  for (int rt = 0; rt < 2; ++rt)
#pragma unroll
    for (int t = 0; t < NT; ++t) acc[rt][t] = (f32x4){0.f, 0.f, 0.f, 0.f};

  // staging chunks: c = l*256+tid, row = c>>2, 16B sub-chunk q = c&3
  int c0 = tid, c1 = 256 + tid;
  int r0s = c0 >> 2, q0s = c0 & 3;
  int r1s = c1 >> 2, q1s = c1 & 3;
  const bf16_t* g0 = Ab + (size_t)(base + r0s) * K + q0s * 8;
  const bf16_t* g1 = Ab + (size_t)(base + r1s) * K + q1s * 8;
  bf16_t* l0 = &Atile[(size_t)c0 * 8];
  bf16_t* l1 = &Atile[(size_t)c1 * 8];

  int arow = wv * 32 + (lane & 15);
  int aq = (lane >> 4) * 8;
  int nk = K >> 5;
  for (int ks = 0; ks < nk; ++ks) {
    __syncthreads();                       // protect LDS reuse
    async_copy16(g0 + ks * 32, l0);
    async_copy16(g1 + ks * 32, l1);
    __syncthreads();                       // drains vmcnt -> tile ready
    bf16x8 a0 = *(const bf16x8*)&Atile[arow * 32 + aq];
    bf16x8 a1 = *(const bf16x8*)&Atile[(arow + 16) * 32 + aq];
    const bf16_t* wb = Wp + ((size_t)ks * NT) * 512 + lane * 8;
#pragma unroll
    for (int t = 0; t < NT; ++t) {
      bf16x8 b = *(const bf16x8*)(wb + t * 512);
      acc[0][t] = __builtin_amdgcn_mfma_f32_16x16x32_bf16(a0, b, acc[0][t], 0, 0, 0);
      acc[1][t] = __builtin_amdgcn_mfma_f32_16x16x32_bf16(a1, b, acc[1][t], 0, 0, 0);
    }
  }
  int col_l = lane & 15;
#pragma unroll
  for (int rt = 0; rt < 2; ++rt) {
    int rbase = base + wv * 32 + rt * 16 + (lane >> 4) * 4;
#pragma unroll
    for (int t = 0; t < NT; ++t) {
      int col = t * 16 + col_l;
      float bv = bias ? bias[col] : 0.f;
#pragma unroll
      for (int r = 0; r < 4; ++r) {
        int row = rbase + r;
        if (row >= M) continue;
        float vv = acc[rt][t][r] + bv;
        if (relu) vv = fmaxf(vv, 0.f);
        if (Cf) Cf[(size_t)row * Ncols + col] = vv;
        if (Cb) Cb[(size_t)row * Ncols + col] = (bf16_t)vv;
      }
    }
  }
}

template<int NT>
__global__ __launch_bounds__(256, 3) void gemm_mfma(
    const bf16_t* __restrict__ Ab, const bf16_t* __restrict__ Wp,
    const float* __restrict__ bias, float* __restrict__ Cf, bf16_t* __restrict__ Cb,
    int M, int K, int relu)
{
  gemm_body<NT>(Ab, Wp, bias, Cf, Cb, M, K, relu, blockIdx.x);
}

// 4 GEMMs sharing A (q,k,v,s) in one dispatch: grid.y selects the weight set
struct QkvsArgs { const bf16_t* w[4]; const float* bias[4]; bf16_t* outp[4]; };
__global__ __launch_bounds__(256, 3) void gemm_qkvs(
    const bf16_t* __restrict__ Ab, QkvsArgs qa, int M, int K)
{
  int which = blockIdx.y;
  gemm_body<16>(Ab, qa.w[which], qa.bias[which], nullptr, qa.outp[which], M, K, 0, blockIdx.x);
}

// ---------------- fused edge softmax-aggregate: half-wave per node, pipelined ----------------
__global__ __launch_bounds__(256) void conv_edge_fused(
    const int* __restrict__ rowptr, const int* __restrict__ esrc, const int* __restrict__ eidx,
    const bf16_t* __restrict__ qb, const bf16_t* __restrict__ kb, const bf16_t* __restrict__ vb,
    const bf16_t* __restrict__ eab, const float* __restrict__ QEf,
    bf16_t* __restrict__ AGGn, bf16_t* __restrict__ EAn)
{
  int half = threadIdx.x >> 5, l = threadIdx.x & 31;
  int n = blockIdx.x * 8 + half;
  if (n >= NN) return;
  size_t co = (size_t)n * DH + l * 8;
  float q[8];
  {
    bf16x8 t = *(const bf16x8*)&qb[co];
#pragma unroll
    for (int j = 0; j < 8; ++j) q[j] = (float)t[j];
  }
  float qe[8];
#pragma unroll
  for (int j = 0; j < 8; ++j) qe[j] = 0.f;
  if (l < 4) {
    const float* p = &QEf[(size_t)n * DED + l * 8];
#pragma unroll
    for (int j = 0; j < 8; ++j) qe[j] = p[j];
  }
  float m = -__builtin_huge_valf(), s = 0.f;
  float acc[8], eacc[8];
#pragma unroll
  for (int j = 0; j < 8; ++j) { acc[j] = 0.f; eacc[j] = 0.f; }
  int i0 = rowptr[n], i1 = rowptr[n + 1];
  int i = i0;
  bf16x8 kt, vt; float eav[8];
#pragma unroll
  for (int j = 0; j < 8; ++j) eav[j] = 0.f;
  if (i < i1) {
    int sN = esrc[i];
    kt = *(const bf16x8*)&kb[(size_t)sN * DH + l * 8];
    vt = *(const bf16x8*)&vb[(size_t)sN * DH + l * 8];
    if (l < 4) {
      int e = eidx[i];
      bf16x8 t = *(const bf16x8*)&eab[(size_t)e * DED + l * 8];
#pragma unroll
      for (int j = 0; j < 8; ++j) eav[j] = (float)t[j];
    }
  }
  while (i < i1) {
    bf16x8 kt2, vt2; float eav2[8];
#pragma unroll
    for (int j = 0; j < 8; ++j) eav2[j] = 0.f;
    if (i + 1 < i1) {
      int sN = esrc[i + 1];
      kt2 = *(const bf16x8*)&kb[(size_t)sN * DH + l * 8];
      vt2 = *(const bf16x8*)&vb[(size_t)sN * DH + l * 8];
      if (l < 4) {
        int e = eidx[i + 1];
        bf16x8 t = *(const bf16x8*)&eab[(size_t)e * DED + l * 8];
#pragma unroll
        for (int j = 0; j < 8; ++j) eav2[j] = (float)t[j];
      }
    } else {
      kt2 = kt; vt2 = vt;
    }
    float partial = 0.f;
#pragma unroll
    for (int j = 0; j < 8; ++j) partial = fmaf(q[j], (float)kt[j], partial);
#pragma unroll
    for (int j = 0; j < 8; ++j) partial = fmaf(qe[j], eav[j], partial);
#pragma unroll
    for (int off = 16; off > 0; off >>= 1) partial += __shfl_xor(partial, off, 64);
    float sc = partial * 0.0625f;  // 1/sqrt(256)
    float nm = fmaxf(m, sc);
    float sca = __expf(m - nm);
    float ex = __expf(sc - nm);
    s = s * sca + ex;
#pragma unroll
    for (int j = 0; j < 8; ++j) acc[j] = acc[j] * sca + ex * (float)vt[j];
#pragma unroll
    for (int j = 0; j < 8; ++j) eacc[j] = eacc[j] * sca + ex * eav[j];
    m = nm;
    kt = kt2; vt = vt2;
#pragma unroll
    for (int j = 0; j < 8; ++j) eav[j] = eav2[j];
    ++i;
  }
  float inv = 1.f / (s + 1e-16f);
  bf16x8 o;
#pragma unroll
  for (int j = 0; j < 8; ++j) o[j] = (bf16_t)(acc[j] * inv);
  *(bf16x8*)&AGGn[co] = o;
  if (l < 4) {
    bf16x8 eo;
#pragma unroll
    for (int j = 0; j < 8; ++j) eo[j] = (bf16_t)(eacc[j] * inv);
    *(bf16x8*)&EAn[(size_t)n * DED + l * 8] = eo;
  }
}

// out = LN( leaky_relu( AGGn + E2N + S ) ) * g + b
__global__ __launch_bounds__(256) void conv_epilogue(
    const bf16_t* __restrict__ AGGn, const bf16_t* __restrict__ E2N,
    const bf16_t* __restrict__ S, const float* __restrict__ g,
    const float* __restrict__ b, bf16_t* __restrict__ out)
{
  int wv = threadIdx.x >> 6, lane = threadIdx.x & 63;
  int n = blockIdx.x * 4 + wv;
  if (n >= NN) return;
  size_t base = (size_t)n * DH + lane * 4;
  bf16x4 a = *(const bf16x4*)&AGGn[base];
  bf16x4 e2 = *(const bf16x4*)&E2N[base];
  bf16x4 sv = *(const bf16x4*)&S[base];
  float v[4];
#pragma unroll
  for (int j = 0; j < 4; ++j) {
    float t = (float)a[j] + (float)e2[j] + (float)sv[j];
    v[j] = (t > 0.f) ? t : 0.01f * t;
  }
  float sum = v[0] + v[1] + v[2] + v[3];
  float sq = v[0]*v[0] + v[1]*v[1] + v[2]*v[2] + v[3]*v[3];
#pragma unroll
  for (int off = 32; off > 0; off >>= 1) {
    sum += __shfl_xor(sum, off, 64);
    sq  += __shfl_xor(sq, off, 64);
  }
  float mu = sum * (1.f / DH);
  float var = sq * (1.f / DH) - mu * mu;
  float rstd = rsqrtf(var + 1e-5f);
  bf16x4 o;
#pragma unroll
  for (int j = 0; j < 4; ++j)
    o[j] = (bf16_t)((v[j] - mu) * rstd * g[lane * 4 + j] + b[lane * 4 + j]);
  *(bf16x4*)&out[base] = o;
}

// ---------------- GIN gather: half-wave per node, pipelined ----------------
__global__ __launch_bounds__(256) void gin_gather(
    const int* __restrict__ rowptr, const int* __restrict__ esrc,
    const bf16_t* __restrict__ h, bf16_t* __restrict__ out)
{
  int half = threadIdx.x >> 5, l = threadIdx.x & 31;
  int n = blockIdx.x * 8 + half;
  if (n >= NN) return;
  size_t co = (size_t)n * DH + l * 8;
  float acc[8];
  {
    bf16x8 hv = *(const bf16x8*)&h[co];
#pragma unroll
    for (int j = 0; j < 8; ++j) acc[j] = (float)hv[j];
  }
  int i0 = rowptr[n], i1 = rowptr[n + 1];
  int i = i0;
  bf16x8 cur;
  if (i < i1) cur = *(const bf16x8*)&h[(size_t)esrc[i] * DH + l * 8];
  while (i < i1) {
    bf16x8 nxt = cur;
    if (i + 1 < i1) nxt = *(const bf16x8*)&h[(size_t)esrc[i + 1] * DH + l * 8];
#pragma unroll
    for (int j = 0; j < 8; ++j) acc[j] += (float)cur[j];
    cur = nxt;
    ++i;
  }
  bf16x8 o;
#pragma unroll
  for (int j = 0; j < 8; ++j) o[j] = (bf16_t)acc[j];
  *(bf16x8*)&out[co] = o;
}

// ---------------- BN (no atomics, no fills) ----------------
__global__ __launch_bounds__(256) void bn_partial_na(
    const float* __restrict__ y, float* __restrict__ psum, float* __restrict__ psq)
{
  int c = threadIdx.x, b = blockIdx.x;
  float s = 0.f, ss = 0.f;
  for (int r = b; r < NN; r += 256) {
    float v = y[(size_t)r * DH + c];
    s += v; ss += v * v;
  }
  psum[b * DH + c] = s; psq[b * DH + c] = ss;
}
__global__ void bn_final_na(const float* __restrict__ psum, const float* __restrict__ psq,
                            const float* __restrict__ bng, const float* __restrict__ bnb,
                            float* __restrict__ scale, float* __restrict__ shift) {
  int c = threadIdx.x;
  float s = 0.f, ss = 0.f;
  for (int b = 0; b < 256; ++b) { s += psum[b * DH + c]; ss += psq[b * DH + c]; }
  float mu = s * (1.f / NN);
  float var = ss * (1.f / NN) - mu * mu;
  float rstd = rsqrtf(var + 1e-5f);
  float sc = bng[c] * rstd;
  scale[c] = sc;
  shift[c] = bnb[c] - mu * sc;
}
__global__ void bn_apply_relu(const float* __restrict__ y, const float* __restrict__ scale,
                              const float* __restrict__ shift, bf16_t* __restrict__ o, int n) {
  int i = blockIdx.x * 256 + threadIdx.x;
  if (i < n) {
    int c = i & (DH - 1);
    o[i] = (bf16_t)fmaxf(y[i] * scale[c] + shift[c], 0.f);
  }
}

// ---------------- pooling over sorted batch ----------------
__global__ __launch_bounds__(256) void pool_sorted(
    const int* __restrict__ batch, const float* __restrict__ h, float* __restrict__ pooled)
{
  __shared__ int s0, s1;
  int g = blockIdx.x;
  if (threadIdx.x == 0) {
    int lo = 0, hi = NN;
    while (lo < hi) { int mid = (lo + hi) >> 1; if (batch[mid] < g) lo = mid + 1; else hi = mid; }
    s0 = lo;
  }
  if (threadIdx.x == 1) {
    int lo = 0, hi = NN;
    while (lo < hi) { int mid = (lo + hi) >> 1; if (batch[mid] < g + 1) lo = mid + 1; else hi = mid; }
    s1 = lo;
  }
  __syncthreads();
  int c = threadIdx.x;
  float acc = 0.f;
  for (int r = s0; r < s1; ++r) acc += h[(size_t)r * DH + c];
  pooled[(size_t)g * DH + c] = acc;
}

// ---------------- small fp32 GEMM (head only) ----------------
__global__ __launch_bounds__(256) void gemm_bias_act(
    const float* __restrict__ A, const float* __restrict__ Wm,
    const float* __restrict__ bias, float* __restrict__ C,
    int M, int K, int Ncol, int act)
{
  __shared__ __align__(16) float As[16][68];
  __shared__ __align__(16) float Bs[16][68];
  int tid = threadIdx.x;
  int tx = tid & 15, ty = tid >> 4;
  int row0 = blockIdx.y * 64 + ty * 4;
  int col0 = blockIdx.x * 64 + tx * 4;
  float acc[4][4] = {{0.f}};
  for (int k0 = 0; k0 < K; k0 += 16) {
#pragma unroll
    for (int l = 0; l < 4; ++l) {
      int e = tid + l * 256;
      int r = e >> 4, kk = e & 15;
      int gr = blockIdx.y * 64 + r;
      As[kk][r] = (gr < M) ? A[(size_t)gr * K + k0 + kk] : 0.f;
    }
#pragma unroll
    for (int l = 0; l < 4; ++l) {
      int e = tid + l * 256;
      int kk = e >> 6, c = e & 63;
      int gc = blockIdx.x * 64 + c;
      Bs[kk][c] = (gc < Ncol) ? Wm[(size_t)(k0 + kk) * Ncol + gc] : 0.f;
    }
    __syncthreads();
#pragma unroll
    for (int kk = 0; kk < 16; ++kk) {
      float4 a4 = *(const float4*)&As[kk][ty * 4];
      float4 b4 = *(const float4*)&Bs[kk][tx * 4];
      float a[4] = {a4.x, a4.y, a4.z, a4.w};
      float b[4] = {b4.x, b4.y, b4.z, b4.w};
#pragma unroll
      for (int i = 0; i < 4; ++i)
#pragma unroll
        for (int j = 0; j < 4; ++j)
          acc[i][j] = fmaf(a[i], b[j], acc[i][j]);
    }
    __syncthreads();
  }
#pragma unroll
  for (int i = 0; i < 4; ++i) {
    int r = row0 + i;
    if (r >= M) continue;
#pragma unroll
    for (int j = 0; j < 4; ++j) {
      int c = col0 + j;
      if (c >= Ncol) continue;
      float val = acc[i][j];
      if (bias) val += bias[c];
      if (act == 1) val = fmaxf(val, 0.f);
      C[(size_t)r * Ncol + c] = val;
    }
  }
}

// ---------------- host ----------------
static inline void launch_filli(hipStream_t st, int* p, int v, long n) {
  fill_i32<<<dim3((unsigned)((n + 255) / 256)), dim3(256), 0, st>>>(p, v, (int)n);
}
static inline void launch_cast(hipStream_t st, const float* in, bf16_t* o, long n) {
  cast_bf16_k<<<dim3((unsigned)((n + 255) / 256)), dim3(256), 0, st>>>(in, o, n);
}

extern "C" void kernel_launch(void* const* d_in, const int* in_sizes, int n_in,
                              void* d_out, int out_size, void* d_ws, size_t ws_size,
                              hipStream_t stream) {
  const float* x  = (const float*)d_in[0];
  const int* ei   = (const int*)d_in[1];
  const float* ea = (const float*)d_in[2];
  const int* batch = (const int*)d_in[3];
  const int* src = ei;
  const int* dst = ei + NE;

  const float* c1[9]; for (int i = 0; i < 9; ++i) c1[i] = (const float*)d_in[4 + i];
  const float* ln1g = (const float*)d_in[13]; const float* ln1b = (const float*)d_in[14];
  const float* c2[9]; for (int i = 0; i < 9; ++i) c2[i] = (const float*)d_in[15 + i];
  const float* ln2g = (const float*)d_in[24]; const float* ln2b = (const float*)d_in[25];
  const float* g1[6]; for (int i = 0; i < 6; ++i) g1[i] = (const float*)d_in[26 + i];
  const float* g2[6]; for (int i = 0; i < 6; ++i) g2[i] = (const float*)d_in[32 + i];
  const float* linW = (const float*)d_in[38]; const float* linb = (const float*)d_in[39];
  const float* clfW = (const float*)d_in[40]; const float* clfb = (const float*)d_in[41];
  float* out = (float*)d_out;

  // ---- bump allocator over d_ws (256B aligned) ----
  size_t off = 0;
  auto alloc = [&](size_t bytes) -> void* {
    void* r = (char*)d_ws + off;
    off += (bytes + 255) & ~(size_t)255;
    return r;
  };
  int* deg    = (int*)alloc(NN * 4);
  int* cursor = (int*)alloc(NN * 4);
  int* rowptr = (int*)alloc((NN + 1) * 4);
  int* esrc   = (int*)alloc((size_t)NE * 4);
  int* eidx   = (int*)alloc((size_t)NE * 4);
  int* bsum   = (int*)alloc(1024);
  int* boff   = (int*)alloc(1024);
  float* QEf   = (float*)alloc((size_t)NN * DED * 4);
  float* Yf    = (float*)alloc((size_t)NN * DH * 4);
  float* pooled = (float*)alloc((size_t)NG * DH * 4);
  float* zbuf   = (float*)alloc((size_t)NG * DH * 4);
  float* psum  = (float*)alloc(256 * DH * 4);
  float* psq   = (float*)alloc(256 * DH * 4);
  float* bnscale = (float*)alloc(DH * 4);
  float* bnshift = (float*)alloc(DH * 4);
  float* wqe_tmp1 = (float*)alloc((size_t)DIN * DED * 4);
  float* wqe_tmp2 = (float*)alloc((size_t)DH * DED * 4);
  float* bqe1 = (float*)alloc(DED * 4);
  float* bqe2 = (float*)alloc(DED * 4);
  bf16_t* qb = (bf16_t*)alloc((size_t)NN * DH * 2);
  bf16_t* kb = (bf16_t*)alloc((size_t)NN * DH * 2);
  bf16_t* vb = (bf16_t*)alloc((size_t)NN * DH * 2);
  bf16_t* sb = (bf16_t*)alloc((size_t)NN * DH * 2);
  bf16_t* h_b = (bf16_t*)alloc((size_t)NN * DH * 2);
  bf16_t* g_b = (bf16_t*)alloc((size_t)NN * DH * 2);
  bf16_t* E2Nb = (bf16_t*)alloc((size_t)NN * DH * 2);
  bf16_t* AGGb = (bf16_t*)alloc((size_t)NN * DH * 2);
  bf16_t* EAn = (bf16_t*)alloc((size_t)NN * DED * 2);
  bf16_t* xb  = (bf16_t*)alloc((size_t)NN * DIN * 2);
  bf16_t* eab = (bf16_t*)alloc((size_t)NE * DED * 2);
  float* Hout = (float*)qb;  // qb+kb region (fp32 [N,DH]) free during GIN phase
  bf16_t* pk1q = (bf16_t*)alloc(DIN * DH * 2);
  bf16_t* pk1k = (bf16_t*)alloc(DIN * DH * 2);
  bf16_t* pk1v = (bf16_t*)alloc(DIN * DH * 2);
  bf16_t* pk1s = (bf16_t*)alloc(DIN * DH * 2);
  bf16_t* pk1qe = (bf16_t*)alloc(DIN * DED * 2);
  bf16_t* pk1we = (bf16_t*)alloc(DED * DH * 2);
  bf16_t* pk2q = (bf16_t*)alloc(DH * DH * 2);
  bf16_t* pk2k = (bf16_t*)alloc(DH * DH * 2);
  bf16_t* pk2v = (bf16_t*)alloc(DH * DH * 2);
  bf16_t* pk2s = (bf16_t*)alloc(DH * DH * 2);
  bf16_t* pk2qe = (bf16_t*)alloc(DH * DED * 2);
  bf16_t* pk2we = (bf16_t*)alloc(DED * DH * 2);
  bf16_t* pkg1a = (bf16_t*)alloc(DH * DH * 2);
  bf16_t* pkg1b = (bf16_t*)alloc(DH * DH * 2);
  bf16_t* pkg2a = (bf16_t*)alloc(DH * DH * 2);
  bf16_t* pkg2b = (bf16_t*)alloc(DH * DH * 2);
  if (ws_size < off) return;

  const int GRID_M = (NN + 127) / 128;

  launch_cast(stream, x, xb, (long)NN * DIN);
  launch_cast(stream, ea, eab, (long)NE * DED);
  wqe_k<<<dim3((DIN * 32 + 255) / 256), dim3(256), 0, stream>>>(c1[0], c1[6], c1[1], wqe_tmp1, bqe1, DIN);
  wqe_k<<<dim3((DH * 32 + 255) / 256), dim3(256), 0, stream>>>(c2[0], c2[6], c2[1], wqe_tmp2, bqe2, DH);
  PackArgs pa;
  pa.e[0]  = {c1[0], pk1q, DIN, DH};
  pa.e[1]  = {c1[2], pk1k, DIN, DH};
  pa.e[2]  = {c1[4], pk1v, DIN, DH};
  pa.e[3]  = {c1[7], pk1s, DIN, DH};
  pa.e[4]  = {c1[6], pk1we, DED, DH};
  pa.e[5]  = {wqe_tmp1, pk1qe, DIN, DED};
  pa.e[6]  = {c2[0], pk2q, DH, DH};
  pa.e[7]  = {c2[2], pk2k, DH, DH};
  pa.e[8]  = {c2[4], pk2v, DH, DH};
  pa.e[9]  = {c2[7], pk2s, DH, DH};
  pa.e[10] = {c2[6], pk2we, DED, DH};
  pa.e[11] = {wqe_tmp2, pk2qe, DH, DED};
  pa.e[12] = {g1[0], pkg1a, DH, DH};
  pa.e[13] = {g1[4], pkg1b, DH, DH};
  pa.e[14] = {g2[0], pkg2a, DH, DH};
  pa.e[15] = {g2[4], pkg2b, DH, DH};
  pack_all<<<dim3(256, 16), dim3(256), 0, stream>>>(pa);

  const int nb1 = (NN + SCAN_T - 1) / SCAN_T;
  launch_filli(stream, deg, 0, NN);
  launch_filli(stream, cursor, 0, NN);
  count_k<<<dim3((NE + 255) / 256), dim3(256), 0, stream>>>(dst, deg);
  scan1<<<dim3(nb1), dim3(SCAN_T), 0, stream>>>(deg, rowptr, bsum, NN);
  scan2<<<dim3(1), dim3(SCAN_T), 0, stream>>>(bsum, boff, nb1);
  scan3<<<dim3(nb1), dim3(SCAN_T), 0, stream>>>(rowptr, boff, NN);
  scatter_k<<<dim3((NE + 255) / 256), dim3(256), 0, stream>>>(dst, src, rowptr, cursor, esrc, eidx);

  auto conv = [&](const bf16_t* Ain, int K,
                  const bf16_t* pq, const bf16_t* pk, const bf16_t* pv, const bf16_t* ps,
                  const bf16_t* pqe, const bf16_t* pwe,
                  const float* const* P, const float* bqe,
                  const float* lng, const float* lnb, bf16_t* outb) {
    QkvsArgs qa;
    qa.w[0] = pq; qa.w[1] = pk; qa.w[2] = pv; qa.w[3] = ps;
    qa.bias[0] = P[1]; qa.bias[1] = P[3]; qa.bias[2] = P[5]; qa.bias[3] = P[8];
    qa.outp[0] = qb; qa.outp[1] = kb; qa.outp[2] = vb; qa.outp[3] = sb;
    gemm_qkvs<<<dim3(GRID_M, 4), dim3(256), 0, stream>>>(Ain, qa, NN, K);
    gemm_mfma<2><<<dim3(GRID_M), dim3(256), 0, stream>>>(Ain, pqe, bqe, QEf, nullptr, NN, K, 0);
    conv_edge_fused<<<dim3((NN + 7) / 8), dim3(256), 0, stream>>>(
        rowptr, esrc, eidx, qb, kb, vb, eab, QEf, AGGb, EAn);
    gemm_mfma<16><<<dim3(GRID_M), dim3(256), 0, stream>>>(EAn, pwe, nullptr, nullptr, E2Nb, NN, DED, 0);
    conv_epilogue<<<dim3((NN + 3) / 4), dim3(256), 0, stream>>>(AGGb, E2Nb, sb, lng, lnb, outb);
  };

  auto gin = [&](const bf16_t* hin, const bf16_t* pw1, const bf16_t* pw2,
                 const float* const* P, int relu_out, float* Cf, bf16_t* Cb) {
    gin_gather<<<dim3((NN + 7) / 8), dim3(256), 0, stream>>>(rowptr, esrc, hin, g_b);
    gemm_mfma<16><<<dim3(GRID_M), dim3(256), 0, stream>>>(g_b, pw1, P[1], Yf, nullptr, NN, DH, 0);
    bn_partial_na<<<dim3(256), dim3(256), 0, stream>>>(Yf, psum, psq);
    bn_final_na<<<dim3(1), dim3(256), 0, stream>>>(psum, psq, P[2], P[3], bnscale, bnshift);
    bn_apply_relu<<<dim3((NN * DH + 255) / 256), dim3(256), 0, stream>>>(
        Yf, bnscale, bnshift, g_b, NN * DH);
    gemm_mfma<16><<<dim3(GRID_M), dim3(256), 0, stream>>>(g_b, pw2, P[5], Cf, Cb, NN, DH, relu_out);
  };

  conv(xb, DIN, pk1q, pk1k, pk1v, pk1s, pk1qe, pk1we, c1, bqe1, ln1g, ln1b, h_b);
  conv(h_b, DH, pk2q, pk2k, pk2v, pk2s, pk2qe, pk2we, c2, bqe2, ln2g, ln2b, h_b);
  gin(h_b, pkg1a, pkg1b, g1, 1, nullptr, h_b);
  gin(h_b, pkg2a, pkg2b, g2, 0, Hout, nullptr);

  pool_sorted<<<dim3(NG), dim3(256), 0, stream>>>(batch, Hout, pooled);
  gemm_bias_act<<<dim3(4, 8), dim3(256), 0, stream>>>(pooled, linW, linb, zbuf, NG, DH, DH, 1);
  gemm_bias_act<<<dim3(1, 8), dim3(256), 0, stream>>>(zbuf, clfW, clfb, out, NG, DH, DOUT, 0);
}

// Round 6
// 1659.595 us; speedup vs baseline: 6.0463x; 1.0203x over previous
//
#include <hip/hip_runtime.h>
#include <math.h>

#define NN 50000
#define NE 800000
#define DIN 128
#define DH 256
#define DED 32
#define NG 500
#define DOUT 16
#define SCAN_T 256

typedef __bf16 bf16_t;
typedef __bf16 bf16x4 __attribute__((ext_vector_type(4)));
typedef __bf16 bf16x8 __attribute__((ext_vector_type(8)));
typedef float f32x4 __attribute__((ext_vector_type(4)));

// async global->LDS, 16B per lane (global_load_lds_dwordx4)
__device__ __forceinline__ void async_copy16(const bf16_t* g, bf16_t* l) {
  __builtin_amdgcn_global_load_lds(
      (const __attribute__((address_space(1))) void*)g,
      (__attribute__((address_space(3))) void*)l, 16, 0, 0);
}

// ---------------- utility ----------------
__global__ void fill_i32(int* __restrict__ p, int v, int n) {
  int i = blockIdx.x * 256 + threadIdx.x;
  if (i < n) p[i] = v;
}
__global__ void cast_bf16_k(const float* __restrict__ in, bf16_t* __restrict__ o, long n) {
  long i = (long)blockIdx.x * 256 + threadIdx.x;
  if (i < n) o[i] = (bf16_t)in[i];
}

// ---------------- CSR build (by dst) ----------------
__global__ void count_k(const int* __restrict__ dst, int* __restrict__ deg) {
  int e = blockIdx.x * 256 + threadIdx.x;
  if (e < NE) atomicAdd(&deg[dst[e]], 1);
}
__global__ void scan1(const int* __restrict__ deg, int* __restrict__ rowptr,
                      int* __restrict__ bsum, int n) {
  __shared__ int s[SCAN_T];
  int t = threadIdx.x, i = blockIdx.x * SCAN_T + t;
  int v = (i < n) ? deg[i] : 0;
  s[t] = v; __syncthreads();
  for (int off = 1; off < SCAN_T; off <<= 1) {
    int add = (t >= off) ? s[t - off] : 0;
    __syncthreads(); s[t] += add; __syncthreads();
  }
  if (i < n) rowptr[i + 1] = s[t];
  if (t == SCAN_T - 1) bsum[blockIdx.x] = s[t];
}
__global__ void scan2(const int* __restrict__ bsum, int* __restrict__ boff, int nb) {
  __shared__ int s[SCAN_T];
  int t = threadIdx.x;
  int v = (t < nb) ? bsum[t] : 0;
  s[t] = v; __syncthreads();
  for (int off = 1; off < SCAN_T; off <<= 1) {
    int add = (t >= off) ? s[t - off] : 0;
    __syncthreads(); s[t] += add; __syncthreads();
  }
  boff[t] = s[t] - v;
}
__global__ void scan3(int* __restrict__ rowptr, const int* __restrict__ boff, int n) {
  int i = blockIdx.x * 256 + threadIdx.x;
  if (i < n) rowptr[i + 1] += boff[i >> 8];
  if (i == 0) rowptr[0] = 0;
}
__global__ void scatter_k(const int* __restrict__ dst, const int* __restrict__ src,
                          const int* __restrict__ rowptr, int* __restrict__ cursor,
                          int* __restrict__ esrc, int* __restrict__ eidx) {
  int e = blockIdx.x * 256 + threadIdx.x;
  if (e < NE) {
    int d = dst[e];
    int pos = rowptr[d] + atomicAdd(&cursor[d], 1);
    esrc[pos] = src[e];
    eidx[pos] = e;
  }
}
// cast + permute edge_attr into CSR order (sequential reads in edge loop)
__global__ void permute_ea(const int* __restrict__ eidx, const float* __restrict__ ea,
                           bf16_t* __restrict__ eac) {
  long t = (long)blockIdx.x * 256 + threadIdx.x;
  if (t >= (long)NE * 4) return;
  int pos = (int)(t >> 2), c8 = ((int)t & 3) * 8;
  int e = eidx[pos];
  const float* sp = &ea[(size_t)e * DED + c8];
  bf16x8 o;
#pragma unroll
  for (int j = 0; j < 8; ++j) o[j] = (bf16_t)sp[j];
  *(bf16x8*)&eac[(size_t)pos * DED + c8] = o;
}

// ---------------- weight fragment packing (all weights, one dispatch) ----------------
struct PackEnt { const float* src; bf16_t* dst; int K; int N; };
struct PackArgs { PackEnt e[16]; };
__global__ void pack_all(PackArgs pa) {
  PackEnt en = pa.e[blockIdx.y];
  int i = blockIdx.x * 256 + threadIdx.x;
  if (i >= en.K * en.N) return;
  int el = i & 511, f = i >> 9;
  int ntiles = en.N >> 4;
  int ks = f / ntiles, t = f - ks * ntiles;
  int lane = el >> 3, j = el & 7;
  int k = ks * 32 + (lane >> 4) * 8 + j;
  int n = t * 16 + (lane & 15);
  en.dst[i] = (bf16_t)en.src[(size_t)k * en.N + n];
}

// Wqe[d][j] = sum_h Wq[d][h]*We[j][h]; bqe[j] = sum_h bq[h]*We[j][h]
__global__ void wqe_k(const float* __restrict__ Wq, const float* __restrict__ We,
                      const float* __restrict__ bq, float* __restrict__ Wqe,
                      float* __restrict__ bqe, int din) {
  int idx = blockIdx.x * 256 + threadIdx.x;
  if (idx < din * 32) {
    int d = idx >> 5, j = idx & 31;
    float s = 0.f;
    for (int h = 0; h < DH; ++h) s += Wq[(size_t)d * DH + h] * We[(size_t)j * DH + h];
    Wqe[idx] = s;
  }
  if (idx < 32) {
    float s = 0.f;
    for (int h = 0; h < DH; ++h) s += bq[h] * We[(size_t)idx * DH + h];
    bqe[idx] = s;
  }
}

// ---------------- small-K MFMA GEMM (per-kstep staging; used for E2N/QE) ----------------
template<int NT>
__device__ __forceinline__ void gemm_body(
    const bf16_t* __restrict__ Ab, const bf16_t* __restrict__ Wp,
    const float* __restrict__ bias, float* __restrict__ Cf, bf16_t* __restrict__ Cb,
    int M, int K, int relu, int bx)
{
  __shared__ bf16_t Atile[128 * 32];
  const int Ncols = NT * 16;
  int tid = threadIdx.x;
  int lane = tid & 63, wv = tid >> 6;
  int base = bx * 128;
  f32x4 acc[2][NT];
#pragma unroll
  for (int rt = 0; rt < 2; ++rt)
#pragma unroll
    for (int t = 0; t < NT; ++t) acc[rt][t] = (f32x4){0.f, 0.f, 0.f, 0.f};
  int c0 = tid, c1 = 256 + tid;
  const bf16_t* g0 = Ab + (size_t)(base + (c0 >> 2)) * K + (c0 & 3) * 8;
  const bf16_t* g1 = Ab + (size_t)(base + (c1 >> 2)) * K + (c1 & 3) * 8;
  bf16_t* l0 = &Atile[(size_t)c0 * 8];
  bf16_t* l1 = &Atile[(size_t)c1 * 8];
  int arow = wv * 32 + (lane & 15);
  int aq = (lane >> 4) * 8;
  int nk = K >> 5;
  for (int ks = 0; ks < nk; ++ks) {
    __syncthreads();
    async_copy16(g0 + ks * 32, l0);
    async_copy16(g1 + ks * 32, l1);
    __syncthreads();
    bf16x8 a0 = *(const bf16x8*)&Atile[arow * 32 + aq];
    bf16x8 a1 = *(const bf16x8*)&Atile[(arow + 16) * 32 + aq];
    const bf16_t* wb = Wp + ((size_t)ks * NT) * 512 + lane * 8;
#pragma unroll
    for (int t = 0; t < NT; ++t) {
      bf16x8 b = *(const bf16x8*)(wb + t * 512);
      acc[0][t] = __builtin_amdgcn_mfma_f32_16x16x32_bf16(a0, b, acc[0][t], 0, 0, 0);
      acc[1][t] = __builtin_amdgcn_mfma_f32_16x16x32_bf16(a1, b, acc[1][t], 0, 0, 0);
    }
  }
  int col_l = lane & 15;
#pragma unroll
  for (int rt = 0; rt < 2; ++rt) {
    int rbase = base + wv * 32 + rt * 16 + (lane >> 4) * 4;
#pragma unroll
    for (int t = 0; t < NT; ++t) {
      int col = t * 16 + col_l;
      float bv = bias ? bias[col] : 0.f;
#pragma unroll
      for (int r = 0; r < 4; ++r) {
        int row = rbase + r;
        if (row >= M) continue;
        float vv = acc[rt][t][r] + bv;
        if (relu) vv = fmaxf(vv, 0.f);
        if (Cf) Cf[(size_t)row * Ncols + col] = vv;
        if (Cb) Cb[(size_t)row * Ncols + col] = (bf16_t)vv;
      }
    }
  }
}

template<int NT>
__global__ __launch_bounds__(256, 3) void gemm_mfma(
    const bf16_t* __restrict__ Ab, const bf16_t* __restrict__ Wp,
    const float* __restrict__ bias, float* __restrict__ Cf, bf16_t* __restrict__ Cb,
    int M, int K, int relu)
{
  gemm_body<NT>(Ab, Wp, bias, Cf, Cb, M, K, relu, blockIdx.x);
}

// ---------------- sharedA MFMA GEMM: stage whole 128xK A-tile once, barrier-free K-loop ----
// A staged in MFMA-fragment order: Atile[ks][rb][lane][8] -> lane-contiguous ds_read_b128.
struct SetA { const bf16_t* w; const float* bias; float* outf; bf16_t* outb; int relu; };
struct SharedAArgs { SetA st[4]; int nsets; int rstride; };

__global__ __launch_bounds__(256, 2) void gemm_sharedA(
    const bf16_t* __restrict__ Ab, SharedAArgs sa, int M, int K)
{
  __shared__ bf16_t Atile[32768];   // 64 KB (K up to 256)
  int tid = threadIdx.x;
  int lane = tid & 63, wv = tid >> 6;
  int base = blockIdx.x * 128;
  int nk = K >> 5;
  int nch = nk * 512;               // 16B chunks
  for (int c = tid; c < nch; c += 256) {
    int ks = c >> 9;
    int rem = c & 511;
    int rb = rem >> 6;
    int lc = rem & 63;
    int row = rb * 16 + (lc & 15);
    int kcol = ks * 32 + (lc >> 4) * 8;
    async_copy16(Ab + (size_t)(base + row) * K + kcol, &Atile[(size_t)c * 8]);
  }
  __syncthreads();
  int col_l = lane & 15;
  for (int w = 0; w < sa.nsets; ++w) {
    SetA s = sa.st[w];
    f32x4 acc[2][16];
#pragma unroll
    for (int rt = 0; rt < 2; ++rt)
#pragma unroll
      for (int t = 0; t < 16; ++t) acc[rt][t] = (f32x4){0.f, 0.f, 0.f, 0.f};
    for (int ks = 0; ks < nk; ++ks) {
      bf16x8 a0 = *(const bf16x8*)&Atile[(size_t)((ks * 8 + wv * 2) * 64 + lane) * 8];
      bf16x8 a1 = *(const bf16x8*)&Atile[(size_t)((ks * 8 + wv * 2 + 1) * 64 + lane) * 8];
      const bf16_t* wb = s.w + (size_t)ks * 16 * 512 + lane * 8;
#pragma unroll
      for (int t = 0; t < 16; ++t) {
        bf16x8 b = *(const bf16x8*)(wb + t * 512);
        acc[0][t] = __builtin_amdgcn_mfma_f32_16x16x32_bf16(a0, b, acc[0][t], 0, 0, 0);
        acc[1][t] = __builtin_amdgcn_mfma_f32_16x16x32_bf16(a1, b, acc[1][t], 0, 0, 0);
      }
    }
#pragma unroll
    for (int rt = 0; rt < 2; ++rt) {
      int rbase = base + wv * 32 + rt * 16 + (lane >> 4) * 4;
#pragma unroll
      for (int t = 0; t < 16; ++t) {
        int col = t * 16 + col_l;
        float bv = s.bias ? s.bias[col] : 0.f;
#pragma unroll
        for (int r = 0; r < 4; ++r) {
          int row = rbase + r;
          if (row >= M) continue;
          float vv = acc[rt][t][r] + bv;
          if (s.relu) vv = fmaxf(vv, 0.f);
          if (s.outf) s.outf[(size_t)row * sa.rstride + col] = vv;
          if (s.outb) s.outb[(size_t)row * sa.rstride + col] = (bf16_t)vv;
        }
      }
    }
  }
}

// ---------------- fused edge softmax-aggregate: half-wave/node, 2-edge unroll, m=0 ------
// qkvs layout: [NN][1024] = q|k|v|s. eac: edge_attr bf16 in CSR order.
__global__ __launch_bounds__(256) void conv_edge_fused(
    const int* __restrict__ rowptr, const int* __restrict__ esrc,
    const bf16_t* __restrict__ qkvs, const bf16_t* __restrict__ eac,
    const float* __restrict__ QEf,
    bf16_t* __restrict__ AGGn, bf16_t* __restrict__ EAn)
{
  int half = threadIdx.x >> 5, l = threadIdx.x & 31;
  int n = blockIdx.x * 8 + half;
  if (n >= NN) return;
  float q[8];
  {
    bf16x8 t = *(const bf16x8*)&qkvs[(size_t)n * 1024 + l * 8];
#pragma unroll
    for (int j = 0; j < 8; ++j) q[j] = (float)t[j];
  }
  float qe[8];
#pragma unroll
  for (int j = 0; j < 8; ++j) qe[j] = 0.f;
  if (l < 4) {
    const float* p = &QEf[(size_t)n * DED + l * 8];
#pragma unroll
    for (int j = 0; j < 8; ++j) qe[j] = p[j];
  }
  float s = 0.f;
  float acc[8], eacc[8];
#pragma unroll
  for (int j = 0; j < 8; ++j) { acc[j] = 0.f; eacc[j] = 0.f; }
  int i0 = rowptr[n], i1 = rowptr[n + 1];
  int i = i0;
  for (; i + 1 < i1; i += 2) {
    int s1 = esrc[i], s2 = esrc[i + 1];
    const bf16_t* b1 = &qkvs[(size_t)s1 * 1024 + 256 + l * 8];
    const bf16_t* b2 = &qkvs[(size_t)s2 * 1024 + 256 + l * 8];
    bf16x8 k1 = *(const bf16x8*)b1;
    bf16x8 v1 = *(const bf16x8*)(b1 + 256);
    bf16x8 k2 = *(const bf16x8*)b2;
    bf16x8 v2 = *(const bf16x8*)(b2 + 256);
    float ea1[8], ea2[8];
#pragma unroll
    for (int j = 0; j < 8; ++j) { ea1[j] = 0.f; ea2[j] = 0.f; }
    if (l < 4) {
      bf16x8 t1 = *(const bf16x8*)&eac[(size_t)i * DED + l * 8];
      bf16x8 t2 = *(const bf16x8*)&eac[(size_t)(i + 1) * DED + l * 8];
#pragma unroll
      for (int j = 0; j < 8; ++j) { ea1[j] = (float)t1[j]; ea2[j] = (float)t2[j]; }
    }
    float p1 = 0.f, p2 = 0.f;
#pragma unroll
    for (int j = 0; j < 8; ++j) {
      p1 = fmaf(q[j], (float)k1[j], p1);
      p2 = fmaf(q[j], (float)k2[j], p2);
    }
#pragma unroll
    for (int j = 0; j < 8; ++j) {
      p1 = fmaf(qe[j], ea1[j], p1);
      p2 = fmaf(qe[j], ea2[j], p2);
    }
#pragma unroll
    for (int off = 16; off > 0; off >>= 1) {
      p1 += __shfl_xor(p1, off, 64);
      p2 += __shfl_xor(p2, off, 64);
    }
    float ex1 = __expf(p1 * 0.0625f);   // scores are O(1); exp without max-shift is safe
    float ex2 = __expf(p2 * 0.0625f);
    s += ex1 + ex2;
#pragma unroll
    for (int j = 0; j < 8; ++j) {
      acc[j] = fmaf(ex1, (float)v1[j], acc[j]);
      acc[j] = fmaf(ex2, (float)v2[j], acc[j]);
    }
#pragma unroll
    for (int j = 0; j < 8; ++j) {
      eacc[j] = fmaf(ex1, ea1[j], eacc[j]);
      eacc[j] = fmaf(ex2, ea2[j], eacc[j]);
    }
  }
  if (i < i1) {
    int s1 = esrc[i];
    const bf16_t* b1 = &qkvs[(size_t)s1 * 1024 + 256 + l * 8];
    bf16x8 k1 = *(const bf16x8*)b1;
    bf16x8 v1 = *(const bf16x8*)(b1 + 256);
    float ea1[8];
#pragma unroll
    for (int j = 0; j < 8; ++j) ea1[j] = 0.f;
    if (l < 4) {
      bf16x8 t1 = *(const bf16x8*)&eac[(size_t)i * DED + l * 8];
#pragma unroll
      for (int j = 0; j < 8; ++j) ea1[j] = (float)t1[j];
    }
    float p1 = 0.f;
#pragma unroll
    for (int j = 0; j < 8; ++j) p1 = fmaf(q[j], (float)k1[j], p1);
#pragma unroll
    for (int j = 0; j < 8; ++j) p1 = fmaf(qe[j], ea1[j], p1);
#pragma unroll
    for (int off = 16; off > 0; off >>= 1) p1 += __shfl_xor(p1, off, 64);
    float ex1 = __expf(p1 * 0.0625f);
    s += ex1;
#pragma unroll
    for (int j = 0; j < 8; ++j) acc[j] = fmaf(ex1, (float)v1[j], acc[j]);
#pragma unroll
    for (int j = 0; j < 8; ++j) eacc[j] = fmaf(ex1, ea1[j], eacc[j]);
  }
  float inv = 1.f / (s + 1e-16f);
  bf16x8 o;
#pragma unroll
  for (int j = 0; j < 8; ++j) o[j] = (bf16_t)(acc[j] * inv);
  *(bf16x8*)&AGGn[(size_t)n * DH + l * 8] = o;
  if (l < 4) {
    bf16x8 eo;
#pragma unroll
    for (int j = 0; j < 8; ++j) eo[j] = (bf16_t)(eacc[j] * inv);
    *(bf16x8*)&EAn[(size_t)n * DED + l * 8] = eo;
  }
}

// out = LN( leaky_relu( AGGn + E2N + S ) ) * g + b ; S = qkvs[:,768:1024]
__global__ __launch_bounds__(256) void conv_epilogue(
    const bf16_t* __restrict__ AGGn, const bf16_t* __restrict__ E2N,
    const bf16_t* __restrict__ qkvs, const float* __restrict__ g,
    const float* __restrict__ b, bf16_t* __restrict__ out)
{
  int wv = threadIdx.x >> 6, lane = threadIdx.x & 63;
  int n = blockIdx.x * 4 + wv;
  if (n >= NN) return;
  size_t base = (size_t)n * DH + lane * 4;
  bf16x4 a = *(const bf16x4*)&AGGn[base];
  bf16x4 e2 = *(const bf16x4*)&E2N[base];
  bf16x4 sv = *(const bf16x4*)&qkvs[(size_t)n * 1024 + 768 + lane * 4];
  float v[4];
#pragma unroll
  for (int j = 0; j < 4; ++j) {
    float t = (float)a[j] + (float)e2[j] + (float)sv[j];
    v[j] = (t > 0.f) ? t : 0.01f * t;
  }
  float sum = v[0] + v[1] + v[2] + v[3];
  float sq = v[0]*v[0] + v[1]*v[1] + v[2]*v[2] + v[3]*v[3];
#pragma unroll
  for (int off = 32; off > 0; off >>= 1) {
    sum += __shfl_xor(sum, off, 64);
    sq  += __shfl_xor(sq, off, 64);
  }
  float mu = sum * (1.f / DH);
  float var = sq * (1.f / DH) - mu * mu;
  float rstd = rsqrtf(var + 1e-5f);
  bf16x4 o;
#pragma unroll
  for (int j = 0; j < 4; ++j)
    o[j] = (bf16_t)((v[j] - mu) * rstd * g[lane * 4 + j] + b[lane * 4 + j]);
  *(bf16x4*)&out[base] = o;
}

// ---------------- GIN gather: half-wave per node, 2-edge unroll ----------------
__global__ __launch_bounds__(256) void gin_gather(
    const int* __restrict__ rowptr, const int* __restrict__ esrc,
    const bf16_t* __restrict__ h, bf16_t* __restrict__ out)
{
  int half = threadIdx.x >> 5, l = threadIdx.x & 31;
  int n = blockIdx.x * 8 + half;
  if (n >= NN) return;
  size_t co = (size_t)n * DH + l * 8;
  float acc[8];
  {
    bf16x8 hv = *(const bf16x8*)&h[co];
#pragma unroll
    for (int j = 0; j < 8; ++j) acc[j] = (float)hv[j];
  }
  int i0 = rowptr[n], i1 = rowptr[n + 1];
  int i = i0;
  for (; i + 1 < i1; i += 2) {
    bf16x8 t1 = *(const bf16x8*)&h[(size_t)esrc[i] * DH + l * 8];
    bf16x8 t2 = *(const bf16x8*)&h[(size_t)esrc[i + 1] * DH + l * 8];
#pragma unroll
    for (int j = 0; j < 8; ++j) acc[j] += (float)t1[j] + (float)t2[j];
  }
  if (i < i1) {
    bf16x8 t1 = *(const bf16x8*)&h[(size_t)esrc[i] * DH + l * 8];
#pragma unroll
    for (int j = 0; j < 8; ++j) acc[j] += (float)t1[j];
  }
  bf16x8 o;
#pragma unroll
  for (int j = 0; j < 8; ++j) o[j] = (bf16_t)acc[j];
  *(bf16x8*)&out[co] = o;
}

// ---------------- BN ----------------
__global__ __launch_bounds__(256) void bn_partial_na(
    const float* __restrict__ y, float* __restrict__ psum, float* __restrict__ psq)
{
  int c = threadIdx.x, b = blockIdx.x;
  float s = 0.f, ss = 0.f;
  for (int r = b; r < NN; r += 256) {
    float v = y[(size_t)r * DH + c];
    s += v; ss += v * v;
  }
  psum[b * DH + c] = s; psq[b * DH + c] = ss;
}
__global__ void bn_final_na(const float* __restrict__ psum, const float* __restrict__ psq,
                            const float* __restrict__ bng, const float* __restrict__ bnb,
                            float* __restrict__ scale, float* __restrict__ shift) {
  int c = threadIdx.x;
  float s = 0.f, ss = 0.f;
  for (int b = 0; b < 256; ++b) { s += psum[b * DH + c]; ss += psq[b * DH + c]; }
  float mu = s * (1.f / NN);
  float var = ss * (1.f / NN) - mu * mu;
  float rstd = rsqrtf(var + 1e-5f);
  float sc = bng[c] * rstd;
  scale[c] = sc;
  shift[c] = bnb[c] - mu * sc;
}
__global__ void bn_apply_relu(const float* __restrict__ y, const float* __restrict__ scale,
                              const float* __restrict__ shift, bf16_t* __restrict__ o, int n) {
  int i = blockIdx.x * 256 + threadIdx.x;
  if (i < n) {
    int c = i & (DH - 1);
    o[i] = (bf16_t)fmaxf(y[i] * scale[c] + shift[c], 0.f);
  }
}

// ---------------- pooling over sorted batch ----------------
__global__ __launch_bounds__(256) void pool_sorted(
    const int* __restrict__ batch, const float* __restrict__ h, float* __restrict__ pooled)
{
  __shared__ int s0, s1;
  int g = blockIdx.x;
  if (threadIdx.x == 0) {
    int lo = 0, hi = NN;
    while (lo < hi) { int mid = (lo + hi) >> 1; if (batch[mid] < g) lo = mid + 1; else hi = mid; }
    s0 = lo;
  }
  if (threadIdx.x == 1) {
    int lo = 0, hi = NN;
    while (lo < hi) { int mid = (lo + hi) >> 1; if (batch[mid] < g + 1) lo = mid + 1; else hi = mid; }
    s1 = lo;
  }
  __syncthreads();
  int c = threadIdx.x;
  float acc = 0.f;
  for (int r = s0; r < s1; ++r) acc += h[(size_t)r * DH + c];
  pooled[(size_t)g * DH + c] = acc;
}

// ---------------- small fp32 GEMM (head only) ----------------
__global__ __launch_bounds__(256) void gemm_bias_act(
    const float* __restrict__ A, const float* __restrict__ Wm,
    const float* __restrict__ bias, float* __restrict__ C,
    int M, int K, int Ncol, int act)
{
  __shared__ __align__(16) float As[16][68];
  __shared__ __align__(16) float Bs[16][68];
  int tid = threadIdx.x;
  int tx = tid & 15, ty = tid >> 4;
  int row0 = blockIdx.y * 64 + ty * 4;
  int col0 = blockIdx.x * 64 + tx * 4;
  float acc[4][4] = {{0.f}};
  for (int k0 = 0; k0 < K; k0 += 16) {
#pragma unroll
    for (int l = 0; l < 4; ++l) {
      int e = tid + l * 256;
      int r = e >> 4, kk = e & 15;
      int gr = blockIdx.y * 64 + r;
      As[kk][r] = (gr < M) ? A[(size_t)gr * K + k0 + kk] : 0.f;
    }
#pragma unroll
    for (int l = 0; l < 4; ++l) {
      int e = tid + l * 256;
      int kk = e >> 6, c = e & 63;
      int gc = blockIdx.x * 64 + c;
      Bs[kk][c] = (gc < Ncol) ? Wm[(size_t)(k0 + kk) * Ncol + gc] : 0.f;
    }
    __syncthreads();
#pragma unroll
    for (int kk = 0; kk < 16; ++kk) {
      float4 a4 = *(const float4*)&As[kk][ty * 4];
      float4 b4 = *(const float4*)&Bs[kk][tx * 4];
      float a[4] = {a4.x, a4.y, a4.z, a4.w};
      float b[4] = {b4.x, b4.y, b4.z, b4.w};
#pragma unroll
      for (int i = 0; i < 4; ++i)
#pragma unroll
        for (int j = 0; j < 4; ++j)
          acc[i][j] = fmaf(a[i], b[j], acc[i][j]);
    }
    __syncthreads();
  }
#pragma unroll
  for (int i = 0; i < 4; ++i) {
    int r = row0 + i;
    if (r >= M) continue;
#pragma unroll
    for (int j = 0; j < 4; ++j) {
      int c = col0 + j;
      if (c >= Ncol) continue;
      float val = acc[i][j];
      if (bias) val += bias[c];
      if (act == 1) val = fmaxf(val, 0.f);
      C[(size_t)r * Ncol + c] = val;
    }
  }
}

// ---------------- host ----------------
static inline void launch_filli(hipStream_t st, int* p, int v, long n) {
  fill_i32<<<dim3((unsigned)((n + 255) / 256)), dim3(256), 0, st>>>(p, v, (int)n);
}
static inline void launch_cast(hipStream_t st, const float* in, bf16_t* o, long n) {
  cast_bf16_k<<<dim3((unsigned)((n + 255) / 256)), dim3(256), 0, st>>>(in, o, n);
}

extern "C" void kernel_launch(void* const* d_in, const int* in_sizes, int n_in,
                              void* d_out, int out_size, void* d_ws, size_t ws_size,
                              hipStream_t stream) {
  const float* x  = (const float*)d_in[0];
  const int* ei   = (const int*)d_in[1];
  const float* ea = (const float*)d_in[2];
  const int* batch = (const int*)d_in[3];
  const int* src = ei;
  const int* dst = ei + NE;

  const float* c1[9]; for (int i = 0; i < 9; ++i) c1[i] = (const float*)d_in[4 + i];
  const float* ln1g = (const float*)d_in[13]; const float* ln1b = (const float*)d_in[14];
  const float* c2[9]; for (int i = 0; i < 9; ++i) c2[i] = (const float*)d_in[15 + i];
  const float* ln2g = (const float*)d_in[24]; const float* ln2b = (const float*)d_in[25];
  const float* g1[6]; for (int i = 0; i < 6; ++i) g1[i] = (const float*)d_in[26 + i];
  const float* g2[6]; for (int i = 0; i < 6; ++i) g2[i] = (const float*)d_in[32 + i];
  const float* linW = (const float*)d_in[38]; const float* linb = (const float*)d_in[39];
  const float* clfW = (const float*)d_in[40]; const float* clfb = (const float*)d_in[41];
  float* out = (float*)d_out;

  // ---- bump allocator over d_ws (256B aligned) ----
  size_t off = 0;
  auto alloc = [&](size_t bytes) -> void* {
    void* r = (char*)d_ws + off;
    off += (bytes + 255) & ~(size_t)255;
    return r;
  };
  int* deg    = (int*)alloc(NN * 4);
  int* cursor = (int*)alloc(NN * 4);
  int* rowptr = (int*)alloc((NN + 1) * 4);
  int* esrc   = (int*)alloc((size_t)NE * 4);
  int* eidx   = (int*)alloc((size_t)NE * 4);
  int* bsum   = (int*)alloc(1024);
  int* boff   = (int*)alloc(1024);
  float* QEf   = (float*)alloc((size_t)NN * DED * 4);
  float* Yf    = (float*)alloc((size_t)NN * DH * 4);
  float* pooled = (float*)alloc((size_t)NG * DH * 4);
  float* zbuf   = (float*)alloc((size_t)NG * DH * 4);
  float* psum  = (float*)alloc(256 * DH * 4);
  float* psq   = (float*)alloc(256 * DH * 4);
  float* bnscale = (float*)alloc(DH * 4);
  float* bnshift = (float*)alloc(DH * 4);
  float* wqe_tmp1 = (float*)alloc((size_t)DIN * DED * 4);
  float* wqe_tmp2 = (float*)alloc((size_t)DH * DED * 4);
  float* bqe1 = (float*)alloc(DED * 4);
  float* bqe2 = (float*)alloc(DED * 4);
  bf16_t* qkvsb = (bf16_t*)alloc((size_t)NN * 1024 * 2);  // q|k|v|s interleaved
  bf16_t* h_b = (bf16_t*)alloc((size_t)NN * DH * 2);
  bf16_t* g_b = (bf16_t*)alloc((size_t)NN * DH * 2);
  bf16_t* E2Nb = (bf16_t*)alloc((size_t)NN * DH * 2);
  bf16_t* AGGb = (bf16_t*)alloc((size_t)NN * DH * 2);
  bf16_t* EAn = (bf16_t*)alloc((size_t)NN * DED * 2);
  bf16_t* xb  = (bf16_t*)alloc((size_t)NN * DIN * 2);
  bf16_t* eac = (bf16_t*)alloc((size_t)NE * DED * 2);     // edge_attr, CSR order
  float* Hout = (float*)qkvsb;  // fp32 [NN][256] aliases qkvs region (free in GIN phase)
  bf16_t* pk1q = (bf16_t*)alloc(DIN * DH * 2);
  bf16_t* pk1k = (bf16_t*)alloc(DIN * DH * 2);
  bf16_t* pk1v = (bf16_t*)alloc(DIN * DH * 2);
  bf16_t* pk1s = (bf16_t*)alloc(DIN * DH * 2);
  bf16_t* pk1qe = (bf16_t*)alloc(DIN * DED * 2);
  bf16_t* pk1we = (bf16_t*)alloc(DED * DH * 2);
  bf16_t* pk2q = (bf16_t*)alloc(DH * DH * 2);
  bf16_t* pk2k = (bf16_t*)alloc(DH * DH * 2);
  bf16_t* pk2v = (bf16_t*)alloc(DH * DH * 2);
  bf16_t* pk2s = (bf16_t*)alloc(DH * DH * 2);
  bf16_t* pk2qe = (bf16_t*)alloc(DH * DED * 2);
  bf16_t* pk2we = (bf16_t*)alloc(DED * DH * 2);
  bf16_t* pkg1a = (bf16_t*)alloc(DH * DH * 2);
  bf16_t* pkg1b = (bf16_t*)alloc(DH * DH * 2);
  bf16_t* pkg2a = (bf16_t*)alloc(DH * DH * 2);
  bf16_t* pkg2b = (bf16_t*)alloc(DH * DH * 2);
  if (ws_size < off) return;

  const int GRID_M = (NN + 127) / 128;

  launch_cast(stream, x, xb, (long)NN * DIN);
  wqe_k<<<dim3((DIN * 32 + 255) / 256), dim3(256), 0, stream>>>(c1[0], c1[6], c1[1], wqe_tmp1, bqe1, DIN);
  wqe_k<<<dim3((DH * 32 + 255) / 256), dim3(256), 0, stream>>>(c2[0], c2[6], c2[1], wqe_tmp2, bqe2, DH);
  PackArgs pa;
  pa.e[0]  = {c1[0], pk1q, DIN, DH};
  pa.e[1]  = {c1[2], pk1k, DIN, DH};
  pa.e[2]  = {c1[4], pk1v, DIN, DH};
  pa.e[3]  = {c1[7], pk1s, DIN, DH};
  pa.e[4]  = {c1[6], pk1we, DED, DH};
  pa.e[5]  = {wqe_tmp1, pk1qe, DIN, DED};
  pa.e[6]  = {c2[0], pk2q, DH, DH};
  pa.e[7]  = {c2[2], pk2k, DH, DH};
  pa.e[8]  = {c2[4], pk2v, DH, DH};
  pa.e[9]  = {c2[7], pk2s, DH, DH};
  pa.e[10] = {c2[6], pk2we, DED, DH};
  pa.e[11] = {wqe_tmp2, pk2qe, DH, DED};
  pa.e[12] = {g1[0], pkg1a, DH, DH};
  pa.e[13] = {g1[4], pkg1b, DH, DH};
  pa.e[14] = {g2[0], pkg2a, DH, DH};
  pa.e[15] = {g2[4], pkg2b, DH, DH};
  pack_all<<<dim3(256, 16), dim3(256), 0, stream>>>(pa);

  const int nb1 = (NN + SCAN_T - 1) / SCAN_T;
  launch_filli(stream, deg, 0, NN);
  launch_filli(stream, cursor, 0, NN);
  count_k<<<dim3((NE + 255) / 256), dim3(256), 0, stream>>>(dst, deg);
  scan1<<<dim3(nb1), dim3(SCAN_T), 0, stream>>>(deg, rowptr, bsum, NN);
  scan2<<<dim3(1), dim3(SCAN_T), 0, stream>>>(bsum, boff, nb1);
  scan3<<<dim3(nb1), dim3(SCAN_T), 0, stream>>>(rowptr, boff, NN);
  scatter_k<<<dim3((NE + 255) / 256), dim3(256), 0, stream>>>(dst, src, rowptr, cursor, esrc, eidx);
  permute_ea<<<dim3((unsigned)(((long)NE * 4 + 255) / 256)), dim3(256), 0, stream>>>(eidx, ea, eac);

  auto conv = [&](const bf16_t* Ain, int K,
                  const bf16_t* pq, const bf16_t* pk, const bf16_t* pv, const bf16_t* ps,
                  const bf16_t* pqe, const bf16_t* pwe,
                  const float* const* P, const float* bqe,
                  const float* lng, const float* lnb, bf16_t* outb) {
    SharedAArgs qa;
    qa.nsets = 4; qa.rstride = 1024;
    qa.st[0] = {pq, P[1], nullptr, qkvsb + 0,   0};
    qa.st[1] = {pk, P[3], nullptr, qkvsb + 256, 0};
    qa.st[2] = {pv, P[5], nullptr, qkvsb + 512, 0};
    qa.st[3] = {ps, P[8], nullptr, qkvsb + 768, 0};
    gemm_sharedA<<<dim3(GRID_M), dim3(256), 0, stream>>>(Ain, qa, NN, K);
    gemm_mfma<2><<<dim3(GRID_M), dim3(256), 0, stream>>>(Ain, pqe, bqe, QEf, nullptr, NN, K, 0);
    conv_edge_fused<<<dim3((NN + 7) / 8), dim3(256), 0, stream>>>(
        rowptr, esrc, qkvsb, eac, QEf, AGGb, EAn);
    gemm_mfma<16><<<dim3(GRID_M), dim3(256), 0, stream>>>(EAn, pwe, nullptr, nullptr, E2Nb, NN, DED, 0);
    conv_epilogue<<<dim3((NN + 3) / 4), dim3(256), 0, stream>>>(AGGb, E2Nb, qkvsb, lng, lnb, outb);
  };

  auto gin = [&](const bf16_t* hin, const bf16_t* pw1, const bf16_t* pw2,
                 const float* const* P, int relu_out, float* Cf, bf16_t* Cb) {
    gin_gather<<<dim3((NN + 7) / 8), dim3(256), 0, stream>>>(rowptr, esrc, hin, g_b);
    SharedAArgs a1;
    a1.nsets = 1; a1.rstride = DH;
    a1.st[0] = {pw1, P[1], Yf, nullptr, 0};
    gemm_sharedA<<<dim3(GRID_M), dim3(256), 0, stream>>>(g_b, a1, NN, DH);
    bn_partial_na<<<dim3(256), dim3(256), 0, stream>>>(Yf, psum, psq);
    bn_final_na<<<dim3(1), dim3(256), 0, stream>>>(psum, psq, P[2], P[3], bnscale, bnshift);
    bn_apply_relu<<<dim3((NN * DH + 255) / 256), dim3(256), 0, stream>>>(
        Yf, bnscale, bnshift, g_b, NN * DH);
    SharedAArgs a2;
    a2.nsets = 1; a2.rstride = DH;
    a2.st[0] = {pw2, P[5], Cf, Cb, relu_out};
    gemm_sharedA<<<dim3(GRID_M), dim3(256), 0, stream>>>(g_b, a2, NN, DH);
  };

  conv(xb, DIN, pk1q, pk1k, pk1v, pk1s, pk1qe, pk1we, c1, bqe1, ln1g, ln1b, h_b);
  conv(h_b, DH, pk2q, pk2k, pk2v, pk2s, pk2qe, pk2we, c2, bqe2, ln2g, ln2b, h_b);
  gin(h_b, pkg1a, pkg1b, g1, 1, nullptr, h_b);
  gin(h_b, pkg2a, pkg2b, g2, 0, Hout, nullptr);

  pool_sorted<<<dim3(NG), dim3(256), 0, stream>>>(batch, Hout, pooled);
  gemm_bias_act<<<dim3(4, 8), dim3(256), 0, stream>>>(pooled, linW, linb, zbuf, NG, DH, DH, 1);
  gemm_bias_act<<<dim3(1, 8), dim3(256), 0, stream>>>(zbuf, clfW, clfb, out, NG, DH, DOUT, 0);
}

// Round 7
// 1436.331 us; speedup vs baseline: 6.9861x; 1.1554x over previous
//
#include <hip/hip_runtime.h>
#include <math.h>

#define NN 50000
#define NE 800000
#define DIN 128
#define DH 256
#define DED 32
#define NG 500
#define DOUT 16
#define SCAN_T 256

typedef __bf16 bf16_t;
typedef __bf16 bf16x4 __attribute__((ext_vector_type(4)));
typedef __bf16 bf16x8 __attribute__((ext_vector_type(8)));
typedef float f32x4 __attribute__((ext_vector_type(4)));

// async global->LDS, 16B per lane (global_load_lds_dwordx4)
__device__ __forceinline__ void async_copy16(const bf16_t* g, bf16_t* l) {
  __builtin_amdgcn_global_load_lds(
      (const __attribute__((address_space(1))) void*)g,
      (__attribute__((address_space(3))) void*)l, 16, 0, 0);
}

// ---------------- utility ----------------
__global__ void fill_i32(int* __restrict__ p, int v, int n) {
  int i = blockIdx.x * 256 + threadIdx.x;
  if (i < n) p[i] = v;
}
__global__ void cast_bf16_k(const float* __restrict__ in, bf16_t* __restrict__ o, long n) {
  long i = (long)blockIdx.x * 256 + threadIdx.x;
  if (i < n) o[i] = (bf16_t)in[i];
}

// ---------------- CSR build (by dst) ----------------
__global__ void count_k(const int* __restrict__ dst, int* __restrict__ deg) {
  int e = blockIdx.x * 256 + threadIdx.x;
  if (e < NE) atomicAdd(&deg[dst[e]], 1);
}
__global__ void scan1(const int* __restrict__ deg, int* __restrict__ rowptr,
                      int* __restrict__ bsum, int n) {
  __shared__ int s[SCAN_T];
  int t = threadIdx.x, i = blockIdx.x * SCAN_T + t;
  int v = (i < n) ? deg[i] : 0;
  s[t] = v; __syncthreads();
  for (int off = 1; off < SCAN_T; off <<= 1) {
    int add = (t >= off) ? s[t - off] : 0;
    __syncthreads(); s[t] += add; __syncthreads();
  }
  if (i < n) rowptr[i + 1] = s[t];
  if (t == SCAN_T - 1) bsum[blockIdx.x] = s[t];
}
__global__ void scan2(const int* __restrict__ bsum, int* __restrict__ boff, int nb) {
  __shared__ int s[SCAN_T];
  int t = threadIdx.x;
  int v = (t < nb) ? bsum[t] : 0;
  s[t] = v; __syncthreads();
  for (int off = 1; off < SCAN_T; off <<= 1) {
    int add = (t >= off) ? s[t - off] : 0;
    __syncthreads(); s[t] += add; __syncthreads();
  }
  boff[t] = s[t] - v;
}
__global__ void scan3(int* __restrict__ rowptr, const int* __restrict__ boff, int n) {
  int i = blockIdx.x * 256 + threadIdx.x;
  if (i < n) rowptr[i + 1] += boff[i >> 8];
  if (i == 0) rowptr[0] = 0;
}
__global__ void scatter_k(const int* __restrict__ dst, const int* __restrict__ src,
                          const int* __restrict__ rowptr, int* __restrict__ cursor,
                          int* __restrict__ esrc, int* __restrict__ eidx) {
  int e = blockIdx.x * 256 + threadIdx.x;
  if (e < NE) {
    int d = dst[e];
    int pos = rowptr[d] + atomicAdd(&cursor[d], 1);
    esrc[pos] = src[e];
    eidx[pos] = e;
  }
}
// cast + permute edge_attr into CSR order (sequential reads in edge loop)
__global__ void permute_ea(const int* __restrict__ eidx, const float* __restrict__ ea,
                           bf16_t* __restrict__ eac) {
  long t = (long)blockIdx.x * 256 + threadIdx.x;
  if (t >= (long)NE * 4) return;
  int pos = (int)(t >> 2), c8 = ((int)t & 3) * 8;
  int e = eidx[pos];
  const float* sp = &ea[(size_t)e * DED + c8];
  bf16x8 o;
#pragma unroll
  for (int j = 0; j < 8; ++j) o[j] = (bf16_t)sp[j];
  *(bf16x8*)&eac[(size_t)pos * DED + c8] = o;
}

// ---------------- weight fragment packing (all weights, one dispatch) ----------------
struct PackEnt { const float* src; bf16_t* dst; int K; int N; };
struct PackArgs { PackEnt e[16]; };
__global__ void pack_all(PackArgs pa) {
  PackEnt en = pa.e[blockIdx.y];
  int i = blockIdx.x * 256 + threadIdx.x;
  if (i >= en.K * en.N) return;
  int el = i & 511, f = i >> 9;
  int ntiles = en.N >> 4;
  int ks = f / ntiles, t = f - ks * ntiles;
  int lane = el >> 3, j = el & 7;
  int k = ks * 32 + (lane >> 4) * 8 + j;
  int n = t * 16 + (lane & 15);
  en.dst[i] = (bf16_t)en.src[(size_t)k * en.N + n];
}

// Wqe[d][j] = sum_h Wq[d][h]*We[j][h]; bqe[j] = sum_h bq[h]*We[j][h]
__global__ void wqe_k(const float* __restrict__ Wq, const float* __restrict__ We,
                      const float* __restrict__ bq, float* __restrict__ Wqe,
                      float* __restrict__ bqe, int din) {
  int idx = blockIdx.x * 256 + threadIdx.x;
  if (idx < din * 32) {
    int d = idx >> 5, j = idx & 31;
    float s = 0.f;
    for (int h = 0; h < DH; ++h) s += Wq[(size_t)d * DH + h] * We[(size_t)j * DH + h];
    Wqe[idx] = s;
  }
  if (idx < 32) {
    float s = 0.f;
    for (int h = 0; h < DH; ++h) s += bq[h] * We[(size_t)idx * DH + h];
    bqe[idx] = s;
  }
}

// ---------------- MFMA GEMM: per-kstep LDS staging of BOTH A and B (m97 shape) --------
// block = 4 waves; tile = 128 rows x NT*16 cols; BK=32.
// A-tile 8KB row-major [128][32]; B-tile NT KB in fragment order (linear copy).
// A/B chunk regions are wave-aligned (multiples of 64 chunks) so each
// global_load_lds wave has a lane-contiguous LDS destination.
template<int NT>
__device__ __forceinline__ void gemm_body(
    const bf16_t* __restrict__ Ab, const bf16_t* __restrict__ Wp,
    const float* __restrict__ bias, float* __restrict__ Cf, bf16_t* __restrict__ Cb,
    int M, int K, int relu, int rstride, int bx)
{
  __shared__ bf16_t Atile[4096];       // 8 KB
  __shared__ bf16_t Btile[NT * 512];   // NT KB
  int tid = threadIdx.x;
  int lane = tid & 63, wv = tid >> 6;
  int base = bx * 128;
  f32x4 acc[2][NT];
#pragma unroll
  for (int rt = 0; rt < 2; ++rt)
#pragma unroll
    for (int t = 0; t < NT; ++t) acc[rt][t] = (f32x4){0.f, 0.f, 0.f, 0.f};
  int arow = wv * 32 + (lane & 15);
  int aq = (lane >> 4) * 8;
  int nk = K >> 5;
  const int NCH = 512 + NT * 64;       // 16B chunks per kstep (both multiples of 64)
  for (int ks = 0; ks < nk; ++ks) {
    __syncthreads();                   // protect LDS from previous iteration's readers
    for (int c = tid; c < NCH; c += 256) {
      if (c < 512) {                   // A: row = c>>2, 16B sub-chunk q = c&3
        int r = c >> 2, q = c & 3;
        async_copy16(Ab + (size_t)(base + r) * K + ks * 32 + q * 8, &Atile[c * 8]);
      } else {                         // B: linear 16B chunks of the kstep's frag block
        int cb = c - 512;
        async_copy16(Wp + (size_t)ks * NT * 512 + cb * 8, &Btile[cb * 8]);
      }
    }
    __syncthreads();                   // drains vmcnt -> tiles ready
    bf16x8 a0 = *(const bf16x8*)&Atile[arow * 32 + aq];
    bf16x8 a1 = *(const bf16x8*)&Atile[(arow + 16) * 32 + aq];
#pragma unroll
    for (int t = 0; t < NT; ++t) {
      bf16x8 b = *(const bf16x8*)&Btile[t * 512 + lane * 8];
      acc[0][t] = __builtin_amdgcn_mfma_f32_16x16x32_bf16(a0, b, acc[0][t], 0, 0, 0);
      acc[1][t] = __builtin_amdgcn_mfma_f32_16x16x32_bf16(a1, b, acc[1][t], 0, 0, 0);
    }
  }
  int col_l = lane & 15;
#pragma unroll
  for (int rt = 0; rt < 2; ++rt) {
    int rbase = base + wv * 32 + rt * 16 + (lane >> 4) * 4;
#pragma unroll
    for (int t = 0; t < NT; ++t) {
      int col = t * 16 + col_l;
      float bv = bias ? bias[col] : 0.f;
#pragma unroll
      for (int r = 0; r < 4; ++r) {
        int row = rbase + r;
        if (row >= M) continue;
        float vv = acc[rt][t][r] + bv;
        if (relu) vv = fmaxf(vv, 0.f);
        if (Cf) Cf[(size_t)row * rstride + col] = vv;
        if (Cb) Cb[(size_t)row * rstride + col] = (bf16_t)vv;
      }
    }
  }
}

template<int NT>
__global__ __launch_bounds__(256, 3) void gemm_mfma(
    const bf16_t* __restrict__ Ab, const bf16_t* __restrict__ Wp,
    const float* __restrict__ bias, float* __restrict__ Cf, bf16_t* __restrict__ Cb,
    int M, int K, int relu, int rstride)
{
  gemm_body<NT>(Ab, Wp, bias, Cf, Cb, M, K, relu, rstride, blockIdx.x);
}

// 4 GEMMs sharing A (q,k,v,s) in one dispatch: grid.y selects the weight set;
// outputs interleave into qkvs[N][1024].
struct QkvsArgs { const bf16_t* w[4]; const float* bias[4]; bf16_t* outp[4]; };
__global__ __launch_bounds__(256, 3) void gemm_qkvs(
    const bf16_t* __restrict__ Ab, QkvsArgs qa, int M, int K)
{
  int which = blockIdx.y;
  gemm_body<16>(Ab, qa.w[which], qa.bias[which], nullptr, qa.outp[which], M, K, 0, 1024,
                blockIdx.x);
}

// ---------------- fused edge softmax-aggregate: half-wave/node, 2-edge unroll ----------
// qkvs layout: [NN][1024] = q|k|v|s. eac: edge_attr bf16 in CSR order.
__global__ __launch_bounds__(256) void conv_edge_fused(
    const int* __restrict__ rowptr, const int* __restrict__ esrc,
    const bf16_t* __restrict__ qkvs, const bf16_t* __restrict__ eac,
    const float* __restrict__ QEf,
    bf16_t* __restrict__ AGGn, bf16_t* __restrict__ EAn)
{
  int half = threadIdx.x >> 5, l = threadIdx.x & 31;
  int n = blockIdx.x * 8 + half;
  if (n >= NN) return;
  float q[8];
  {
    bf16x8 t = *(const bf16x8*)&qkvs[(size_t)n * 1024 + l * 8];
#pragma unroll
    for (int j = 0; j < 8; ++j) q[j] = (float)t[j];
  }
  float qe[8];
#pragma unroll
  for (int j = 0; j < 8; ++j) qe[j] = 0.f;
  if (l < 4) {
    const float* p = &QEf[(size_t)n * DED + l * 8];
#pragma unroll
    for (int j = 0; j < 8; ++j) qe[j] = p[j];
  }
  float s = 0.f;
  float acc[8], eacc[8];
#pragma unroll
  for (int j = 0; j < 8; ++j) { acc[j] = 0.f; eacc[j] = 0.f; }
  int i0 = rowptr[n], i1 = rowptr[n + 1];
  int i = i0;
  for (; i + 1 < i1; i += 2) {
    int s1 = esrc[i], s2 = esrc[i + 1];
    const bf16_t* b1 = &qkvs[(size_t)s1 * 1024 + 256 + l * 8];
    const bf16_t* b2 = &qkvs[(size_t)s2 * 1024 + 256 + l * 8];
    bf16x8 k1 = *(const bf16x8*)b1;
    bf16x8 v1 = *(const bf16x8*)(b1 + 256);
    bf16x8 k2 = *(const bf16x8*)b2;
    bf16x8 v2 = *(const bf16x8*)(b2 + 256);
    float ea1[8], ea2[8];
#pragma unroll
    for (int j = 0; j < 8; ++j) { ea1[j] = 0.f; ea2[j] = 0.f; }
    if (l < 4) {
      bf16x8 t1 = *(const bf16x8*)&eac[(size_t)i * DED + l * 8];
      bf16x8 t2 = *(const bf16x8*)&eac[(size_t)(i + 1) * DED + l * 8];
#pragma unroll
      for (int j = 0; j < 8; ++j) { ea1[j] = (float)t1[j]; ea2[j] = (float)t2[j]; }
    }
    float p1 = 0.f, p2 = 0.f;
#pragma unroll
    for (int j = 0; j < 8; ++j) {
      p1 = fmaf(q[j], (float)k1[j], p1);
      p2 = fmaf(q[j], (float)k2[j], p2);
    }
#pragma unroll
    for (int j = 0; j < 8; ++j) {
      p1 = fmaf(qe[j], ea1[j], p1);
      p2 = fmaf(qe[j], ea2[j], p2);
    }
#pragma unroll
    for (int off = 16; off > 0; off >>= 1) {
      p1 += __shfl_xor(p1, off, 64);
      p2 += __shfl_xor(p2, off, 64);
    }
    float ex1 = __expf(p1 * 0.0625f);   // scores O(1); exp without max-shift is safe
    float ex2 = __expf(p2 * 0.0625f);
    s += ex1 + ex2;
#pragma unroll
    for (int j = 0; j < 8; ++j) {
      acc[j] = fmaf(ex1, (float)v1[j], acc[j]);
      acc[j] = fmaf(ex2, (float)v2[j], acc[j]);
    }
#pragma unroll
    for (int j = 0; j < 8; ++j) {
      eacc[j] = fmaf(ex1, ea1[j], eacc[j]);
      eacc[j] = fmaf(ex2, ea2[j], eacc[j]);
    }
  }
  if (i < i1) {
    int s1 = esrc[i];
    const bf16_t* b1 = &qkvs[(size_t)s1 * 1024 + 256 + l * 8];
    bf16x8 k1 = *(const bf16x8*)b1;
    bf16x8 v1 = *(const bf16x8*)(b1 + 256);
    float ea1[8];
#pragma unroll
    for (int j = 0; j < 8; ++j) ea1[j] = 0.f;
    if (l < 4) {
      bf16x8 t1 = *(const bf16x8*)&eac[(size_t)i * DED + l * 8];
#pragma unroll
      for (int j = 0; j < 8; ++j) ea1[j] = (float)t1[j];
    }
    float p1 = 0.f;
#pragma unroll
    for (int j = 0; j < 8; ++j) p1 = fmaf(q[j], (float)k1[j], p1);
#pragma unroll
    for (int j = 0; j < 8; ++j) p1 = fmaf(qe[j], ea1[j], p1);
#pragma unroll
    for (int off = 16; off > 0; off >>= 1) p1 += __shfl_xor(p1, off, 64);
    float ex1 = __expf(p1 * 0.0625f);
    s += ex1;
#pragma unroll
    for (int j = 0; j < 8; ++j) acc[j] = fmaf(ex1, (float)v1[j], acc[j]);
#pragma unroll
    for (int j = 0; j < 8; ++j) eacc[j] = fmaf(ex1, ea1[j], eacc[j]);
  }
  float inv = 1.f / (s + 1e-16f);
  bf16x8 o;
#pragma unroll
  for (int j = 0; j < 8; ++j) o[j] = (bf16_t)(acc[j] * inv);
  *(bf16x8*)&AGGn[(size_t)n * DH + l * 8] = o;
  if (l < 4) {
    bf16x8 eo;
#pragma unroll
    for (int j = 0; j < 8; ++j) eo[j] = (bf16_t)(eacc[j] * inv);
    *(bf16x8*)&EAn[(size_t)n * DED + l * 8] = eo;
  }
}

// out = LN( leaky_relu( AGGn + E2N + S ) ) * g + b ; S = qkvs[:,768:1024]
__global__ __launch_bounds__(256) void conv_epilogue(
    const bf16_t* __restrict__ AGGn, const bf16_t* __restrict__ E2N,
    const bf16_t* __restrict__ qkvs, const float* __restrict__ g,
    const float* __restrict__ b, bf16_t* __restrict__ out)
{
  int wv = threadIdx.x >> 6, lane = threadIdx.x & 63;
  int n = blockIdx.x * 4 + wv;
  if (n >= NN) return;
  size_t base = (size_t)n * DH + lane * 4;
  bf16x4 a = *(const bf16x4*)&AGGn[base];
  bf16x4 e2 = *(const bf16x4*)&E2N[base];
  bf16x4 sv = *(const bf16x4*)&qkvs[(size_t)n * 1024 + 768 + lane * 4];
  float v[4];
#pragma unroll
  for (int j = 0; j < 4; ++j) {
    float t = (float)a[j] + (float)e2[j] + (float)sv[j];
    v[j] = (t > 0.f) ? t : 0.01f * t;
  }
  float sum = v[0] + v[1] + v[2] + v[3];
  float sq = v[0]*v[0] + v[1]*v[1] + v[2]*v[2] + v[3]*v[3];
#pragma unroll
  for (int off = 32; off > 0; off >>= 1) {
    sum += __shfl_xor(sum, off, 64);
    sq  += __shfl_xor(sq, off, 64);
  }
  float mu = sum * (1.f / DH);
  float var = sq * (1.f / DH) - mu * mu;
  float rstd = rsqrtf(var + 1e-5f);
  bf16x4 o;
#pragma unroll
  for (int j = 0; j < 4; ++j)
    o[j] = (bf16_t)((v[j] - mu) * rstd * g[lane * 4 + j] + b[lane * 4 + j]);
  *(bf16x4*)&out[base] = o;
}

// ---------------- GIN gather: half-wave per node, 2-edge unroll ----------------
__global__ __launch_bounds__(256) void gin_gather(
    const int* __restrict__ rowptr, const int* __restrict__ esrc,
    const bf16_t* __restrict__ h, bf16_t* __restrict__ out)
{
  int half = threadIdx.x >> 5, l = threadIdx.x & 31;
  int n = blockIdx.x * 8 + half;
  if (n >= NN) return;
  size_t co = (size_t)n * DH + l * 8;
  float acc[8];
  {
    bf16x8 hv = *(const bf16x8*)&h[co];
#pragma unroll
    for (int j = 0; j < 8; ++j) acc[j] = (float)hv[j];
  }
  int i0 = rowptr[n], i1 = rowptr[n + 1];
  int i = i0;
  for (; i + 1 < i1; i += 2) {
    bf16x8 t1 = *(const bf16x8*)&h[(size_t)esrc[i] * DH + l * 8];
    bf16x8 t2 = *(const bf16x8*)&h[(size_t)esrc[i + 1] * DH + l * 8];
#pragma unroll
    for (int j = 0; j < 8; ++j) acc[j] += (float)t1[j] + (float)t2[j];
  }
  if (i < i1) {
    bf16x8 t1 = *(const bf16x8*)&h[(size_t)esrc[i] * DH + l * 8];
#pragma unroll
    for (int j = 0; j < 8; ++j) acc[j] += (float)t1[j];
  }
  bf16x8 o;
#pragma unroll
  for (int j = 0; j < 8; ++j) o[j] = (bf16_t)acc[j];
  *(bf16x8*)&out[co] = o;
}

// ---------------- BN ----------------
__global__ __launch_bounds__(256) void bn_partial_na(
    const float* __restrict__ y, float* __restrict__ psum, float* __restrict__ psq)
{
  int c = threadIdx.x, b = blockIdx.x;
  float s = 0.f, ss = 0.f;
  for (int r = b; r < NN; r += 256) {
    float v = y[(size_t)r * DH + c];
    s += v; ss += v * v;
  }
  psum[b * DH + c] = s; psq[b * DH + c] = ss;
}
__global__ void bn_final_na(const float* __restrict__ psum, const float* __restrict__ psq,
                            const float* __restrict__ bng, const float* __restrict__ bnb,
                            float* __restrict__ scale, float* __restrict__ shift) {
  int c = threadIdx.x;
  float s = 0.f, ss = 0.f;
  for (int b = 0; b < 256; ++b) { s += psum[b * DH + c]; ss += psq[b * DH + c]; }
  float mu = s * (1.f / NN);
  float var = ss * (1.f / NN) - mu * mu;
  float rstd = rsqrtf(var + 1e-5f);
  float sc = bng[c] * rstd;
  scale[c] = sc;
  shift[c] = bnb[c] - mu * sc;
}
__global__ void bn_apply_relu(const float* __restrict__ y, const float* __restrict__ scale,
                              const float* __restrict__ shift, bf16_t* __restrict__ o, int n) {
  int i = blockIdx.x * 256 + threadIdx.x;
  if (i < n) {
    int c = i & (DH - 1);
    o[i] = (bf16_t)fmaxf(y[i] * scale[c] + shift[c], 0.f);
  }
}

// ---------------- pooling over sorted batch ----------------
__global__ __launch_bounds__(256) void pool_sorted(
    const int* __restrict__ batch, const float* __restrict__ h, float* __restrict__ pooled)
{
  __shared__ int s0, s1;
  int g = blockIdx.x;
  if (threadIdx.x == 0) {
    int lo = 0, hi = NN;
    while (lo < hi) { int mid = (lo + hi) >> 1; if (batch[mid] < g) lo = mid + 1; else hi = mid; }
    s0 = lo;
  }
  if (threadIdx.x == 1) {
    int lo = 0, hi = NN;
    while (lo < hi) { int mid = (lo + hi) >> 1; if (batch[mid] < g + 1) lo = mid + 1; else hi = mid; }
    s1 = lo;
  }
  __syncthreads();
  int c = threadIdx.x;
  float acc = 0.f;
  for (int r = s0; r < s1; ++r) acc += h[(size_t)r * DH + c];
  pooled[(size_t)g * DH + c] = acc;
}

// ---------------- small fp32 GEMM (head only) ----------------
__global__ __launch_bounds__(256) void gemm_bias_act(
    const float* __restrict__ A, const float* __restrict__ Wm,
    const float* __restrict__ bias, float* __restrict__ C,
    int M, int K, int Ncol, int act)
{
  __shared__ __align__(16) float As[16][68];
  __shared__ __align__(16) float Bs[16][68];
  int tid = threadIdx.x;
  int tx = tid & 15, ty = tid >> 4;
  int row0 = blockIdx.y * 64 + ty * 4;
  int col0 = blockIdx.x * 64 + tx * 4;
  float acc[4][4] = {{0.f}};
  for (int k0 = 0; k0 < K; k0 += 16) {
#pragma unroll
    for (int l = 0; l < 4; ++l) {
      int e = tid + l * 256;
      int r = e >> 4, kk = e & 15;
      int gr = blockIdx.y * 64 + r;
      As[kk][r] = (gr < M) ? A[(size_t)gr * K + k0 + kk] : 0.f;
    }
#pragma unroll
    for (int l = 0; l < 4; ++l) {
      int e = tid + l * 256;
      int kk = e >> 6, c = e & 63;
      int gc = blockIdx.x * 64 + c;
      Bs[kk][c] = (gc < Ncol) ? Wm[(size_t)(k0 + kk) * Ncol + gc] : 0.f;
    }
    __syncthreads();
#pragma unroll
    for (int kk = 0; kk < 16; ++kk) {
      float4 a4 = *(const float4*)&As[kk][ty * 4];
      float4 b4 = *(const float4*)&Bs[kk][tx * 4];
      float a[4] = {a4.x, a4.y, a4.z, a4.w};
      float b[4] = {b4.x, b4.y, b4.z, b4.w};
#pragma unroll
      for (int i = 0; i < 4; ++i)
#pragma unroll
        for (int j = 0; j < 4; ++j)
          acc[i][j] = fmaf(a[i], b[j], acc[i][j]);
    }
    __syncthreads();
  }
#pragma unroll
  for (int i = 0; i < 4; ++i) {
    int r = row0 + i;
    if (r >= M) continue;
#pragma unroll
    for (int j = 0; j < 4; ++j) {
      int c = col0 + j;
      if (c >= Ncol) continue;
      float val = acc[i][j];
      if (bias) val += bias[c];
      if (act == 1) val = fmaxf(val, 0.f);
      C[(size_t)r * Ncol + c] = val;
    }
  }
}

// ---------------- host ----------------
static inline void launch_filli(hipStream_t st, int* p, int v, long n) {
  fill_i32<<<dim3((unsigned)((n + 255) / 256)), dim3(256), 0, st>>>(p, v, (int)n);
}
static inline void launch_cast(hipStream_t st, const float* in, bf16_t* o, long n) {
  cast_bf16_k<<<dim3((unsigned)((n + 255) / 256)), dim3(256), 0, st>>>(in, o, n);
}

extern "C" void kernel_launch(void* const* d_in, const int* in_sizes, int n_in,
                              void* d_out, int out_size, void* d_ws, size_t ws_size,
                              hipStream_t stream) {
  const float* x  = (const float*)d_in[0];
  const int* ei   = (const int*)d_in[1];
  const float* ea = (const float*)d_in[2];
  const int* batch = (const int*)d_in[3];
  const int* src = ei;
  const int* dst = ei + NE;

  const float* c1[9]; for (int i = 0; i < 9; ++i) c1[i] = (const float*)d_in[4 + i];
  const float* ln1g = (const float*)d_in[13]; const float* ln1b = (const float*)d_in[14];
  const float* c2[9]; for (int i = 0; i < 9; ++i) c2[i] = (const float*)d_in[15 + i];
  const float* ln2g = (const float*)d_in[24]; const float* ln2b = (const float*)d_in[25];
  const float* g1[6]; for (int i = 0; i < 6; ++i) g1[i] = (const float*)d_in[26 + i];
  const float* g2[6]; for (int i = 0; i < 6; ++i) g2[i] = (const float*)d_in[32 + i];
  const float* linW = (const float*)d_in[38]; const float* linb = (const float*)d_in[39];
  const float* clfW = (const float*)d_in[40]; const float* clfb = (const float*)d_in[41];
  float* out = (float*)d_out;

  // ---- bump allocator over d_ws (256B aligned) ----
  size_t off = 0;
  auto alloc = [&](size_t bytes) -> void* {
    void* r = (char*)d_ws + off;
    off += (bytes + 255) & ~(size_t)255;
    return r;
  };
  int* deg    = (int*)alloc(NN * 4);
  int* cursor = (int*)alloc(NN * 4);
  int* rowptr = (int*)alloc((NN + 1) * 4);
  int* esrc   = (int*)alloc((size_t)NE * 4);
  int* eidx   = (int*)alloc((size_t)NE * 4);
  int* bsum   = (int*)alloc(1024);
  int* boff   = (int*)alloc(1024);
  float* QEf   = (float*)alloc((size_t)NN * DED * 4);
  float* Yf    = (float*)alloc((size_t)NN * DH * 4);
  float* pooled = (float*)alloc((size_t)NG * DH * 4);
  float* zbuf   = (float*)alloc((size_t)NG * DH * 4);
  float* psum  = (float*)alloc(256 * DH * 4);
  float* psq   = (float*)alloc(256 * DH * 4);
  float* bnscale = (float*)alloc(DH * 4);
  float* bnshift = (float*)alloc(DH * 4);
  float* wqe_tmp1 = (float*)alloc((size_t)DIN * DED * 4);
  float* wqe_tmp2 = (float*)alloc((size_t)DH * DED * 4);
  float* bqe1 = (float*)alloc(DED * 4);
  float* bqe2 = (float*)alloc(DED * 4);
  bf16_t* qkvsb = (bf16_t*)alloc((size_t)NN * 1024 * 2);  // q|k|v|s interleaved
  bf16_t* h_b = (bf16_t*)alloc((size_t)NN * DH * 2);
  bf16_t* g_b = (bf16_t*)alloc((size_t)NN * DH * 2);
  bf16_t* E2Nb = (bf16_t*)alloc((size_t)NN * DH * 2);
  bf16_t* AGGb = (bf16_t*)alloc((size_t)NN * DH * 2);
  bf16_t* EAn = (bf16_t*)alloc((size_t)NN * DED * 2);
  bf16_t* xb  = (bf16_t*)alloc((size_t)NN * DIN * 2);
  bf16_t* eac = (bf16_t*)alloc((size_t)NE * DED * 2);     // edge_attr, CSR order
  float* Hout = (float*)qkvsb;  // fp32 [NN][256] aliases qkvs region (free in GIN phase)
  bf16_t* pk1q = (bf16_t*)alloc(DIN * DH * 2);
  bf16_t* pk1k = (bf16_t*)alloc(DIN * DH * 2);
  bf16_t* pk1v = (bf16_t*)alloc(DIN * DH * 2);
  bf16_t* pk1s = (bf16_t*)alloc(DIN * DH * 2);
  bf16_t* pk1qe = (bf16_t*)alloc(DIN * DED * 2);
  bf16_t* pk1we = (bf16_t*)alloc(DED * DH * 2);
  bf16_t* pk2q = (bf16_t*)alloc(DH * DH * 2);
  bf16_t* pk2k = (bf16_t*)alloc(DH * DH * 2);
  bf16_t* pk2v = (bf16_t*)alloc(DH * DH * 2);
  bf16_t* pk2s = (bf16_t*)alloc(DH * DH * 2);
  bf16_t* pk2qe = (bf16_t*)alloc(DH * DED * 2);
  bf16_t* pk2we = (bf16_t*)alloc(DED * DH * 2);
  bf16_t* pkg1a = (bf16_t*)alloc(DH * DH * 2);
  bf16_t* pkg1b = (bf16_t*)alloc(DH * DH * 2);
  bf16_t* pkg2a = (bf16_t*)alloc(DH * DH * 2);
  bf16_t* pkg2b = (bf16_t*)alloc(DH * DH * 2);
  if (ws_size < off) return;

  const int GRID_M = (NN + 127) / 128;

  launch_cast(stream, x, xb, (long)NN * DIN);
  wqe_k<<<dim3((DIN * 32 + 255) / 256), dim3(256), 0, stream>>>(c1[0], c1[6], c1[1], wqe_tmp1, bqe1, DIN);
  wqe_k<<<dim3((DH * 32 + 255) / 256), dim3(256), 0, stream>>>(c2[0], c2[6], c2[1], wqe_tmp2, bqe2, DH);
  PackArgs pa;
  pa.e[0]  = {c1[0], pk1q, DIN, DH};
  pa.e[1]  = {c1[2], pk1k, DIN, DH};
  pa.e[2]  = {c1[4], pk1v, DIN, DH};
  pa.e[3]  = {c1[7], pk1s, DIN, DH};
  pa.e[4]  = {c1[6], pk1we, DED, DH};
  pa.e[5]  = {wqe_tmp1, pk1qe, DIN, DED};
  pa.e[6]  = {c2[0], pk2q, DH, DH};
  pa.e[7]  = {c2[2], pk2k, DH, DH};
  pa.e[8]  = {c2[4], pk2v, DH, DH};
  pa.e[9]  = {c2[7], pk2s, DH, DH};
  pa.e[10] = {c2[6], pk2we, DED, DH};
  pa.e[11] = {wqe_tmp2, pk2qe, DH, DED};
  pa.e[12] = {g1[0], pkg1a, DH, DH};
  pa.e[13] = {g1[4], pkg1b, DH, DH};
  pa.e[14] = {g2[0], pkg2a, DH, DH};
  pa.e[15] = {g2[4], pkg2b, DH, DH};
  pack_all<<<dim3(256, 16), dim3(256), 0, stream>>>(pa);

  const int nb1 = (NN + SCAN_T - 1) / SCAN_T;
  launch_filli(stream, deg, 0, NN);
  launch_filli(stream, cursor, 0, NN);
  count_k<<<dim3((NE + 255) / 256), dim3(256), 0, stream>>>(dst, deg);
  scan1<<<dim3(nb1), dim3(SCAN_T), 0, stream>>>(deg, rowptr, bsum, NN);
  scan2<<<dim3(1), dim3(SCAN_T), 0, stream>>>(bsum, boff, nb1);
  scan3<<<dim3(nb1), dim3(SCAN_T), 0, stream>>>(rowptr, boff, NN);
  scatter_k<<<dim3((NE + 255) / 256), dim3(256), 0, stream>>>(dst, src, rowptr, cursor, esrc, eidx);
  permute_ea<<<dim3((unsigned)(((long)NE * 4 + 255) / 256)), dim3(256), 0, stream>>>(eidx, ea, eac);

  auto conv = [&](const bf16_t* Ain, int K,
                  const bf16_t* pq, const bf16_t* pk, const bf16_t* pv, const bf16_t* ps,
                  const bf16_t* pqe, const bf16_t* pwe,
                  const float* const* P, const float* bqe,
                  const float* lng, const float* lnb, bf16_t* outb) {
    QkvsArgs qa;
    qa.w[0] = pq; qa.w[1] = pk; qa.w[2] = pv; qa.w[3] = ps;
    qa.bias[0] = P[1]; qa.bias[1] = P[3]; qa.bias[2] = P[5]; qa.bias[3] = P[8];
    qa.outp[0] = qkvsb + 0; qa.outp[1] = qkvsb + 256;
    qa.outp[2] = qkvsb + 512; qa.outp[3] = qkvsb + 768;
    gemm_qkvs<<<dim3(GRID_M, 4), dim3(256), 0, stream>>>(Ain, qa, NN, K);
    gemm_mfma<2><<<dim3(GRID_M), dim3(256), 0, stream>>>(Ain, pqe, bqe, QEf, nullptr, NN, K, 0, 32);
    conv_edge_fused<<<dim3((NN + 7) / 8), dim3(256), 0, stream>>>(
        rowptr, esrc, qkvsb, eac, QEf, AGGb, EAn);
    gemm_mfma<16><<<dim3(GRID_M), dim3(256), 0, stream>>>(EAn, pwe, nullptr, nullptr, E2Nb, NN, DED, 0, 256);
    conv_epilogue<<<dim3((NN + 3) / 4), dim3(256), 0, stream>>>(AGGb, E2Nb, qkvsb, lng, lnb, outb);
  };

  auto gin = [&](const bf16_t* hin, const bf16_t* pw1, const bf16_t* pw2,
                 const float* const* P, int relu_out, float* Cf, bf16_t* Cb) {
    gin_gather<<<dim3((NN + 7) / 8), dim3(256), 0, stream>>>(rowptr, esrc, hin, g_b);
    gemm_mfma<16><<<dim3(GRID_M), dim3(256), 0, stream>>>(g_b, pw1, P[1], Yf, nullptr, NN, DH, 0, 256);
    bn_partial_na<<<dim3(256), dim3(256), 0, stream>>>(Yf, psum, psq);
    bn_final_na<<<dim3(1), dim3(256), 0, stream>>>(psum, psq, P[2], P[3], bnscale, bnshift);
    bn_apply_relu<<<dim3((NN * DH + 255) / 256), dim3(256), 0, stream>>>(
        Yf, bnscale, bnshift, g_b, NN * DH);
    gemm_mfma<16><<<dim3(GRID_M), dim3(256), 0, stream>>>(g_b, pw2, P[5], Cf, Cb, NN, DH, relu_out, 256);
  };

  conv(xb, DIN, pk1q, pk1k, pk1v, pk1s, pk1qe, pk1we, c1, bqe1, ln1g, ln1b, h_b);
  conv(h_b, DH, pk2q, pk2k, pk2v, pk2s, pk2qe, pk2we, c2, bqe2, ln2g, ln2b, h_b);
  gin(h_b, pkg1a, pkg1b, g1, 1, nullptr, h_b);
  gin(h_b, pkg2a, pkg2b, g2, 0, Hout, nullptr);

  pool_sorted<<<dim3(NG), dim3(256), 0, stream>>>(batch, Hout, pooled);
  gemm_bias_act<<<dim3(4, 8), dim3(256), 0, stream>>>(pooled, linW, linb, zbuf, NG, DH, DH, 1);
  gemm_bias_act<<<dim3(1, 8), dim3(256), 0, stream>>>(zbuf, clfW, clfb, out, NG, DH, DOUT, 0);
}